// Round 1
// baseline (5833.916 us; speedup 1.0000x reference)
//
#include <hip/hip_runtime.h>
#include <math.h>

#define HW 4096          // 64*64 pixels
#define IMG 64

// ---------------------------------------------------------------------------
// block reduction helpers (256 threads = 4 waves)
// ---------------------------------------------------------------------------
__device__ __forceinline__ float blockReduceMax(float v, float* sd) {
#pragma unroll
    for (int o = 32; o > 0; o >>= 1) v = fmaxf(v, __shfl_down(v, o));
    if ((threadIdx.x & 63) == 0) sd[threadIdx.x >> 6] = v;
    __syncthreads();
    float r = fmaxf(fmaxf(sd[0], sd[1]), fmaxf(sd[2], sd[3]));
    __syncthreads();
    return r;
}
__device__ __forceinline__ float blockReduceSum(float v, float* sd) {
#pragma unroll
    for (int o = 32; o > 0; o >>= 1) v += __shfl_down(v, o);
    if ((threadIdx.x & 63) == 0) sd[threadIdx.x >> 6] = v;
    __syncthreads();
    float r = sd[0] + sd[1] + sd[2] + sd[3];
    __syncthreads();
    return r;
}

// ---------------------------------------------------------------------------
// Generic fp32 3x3 SAME conv (cross-correlation, matches lax.conv).
// Input = concat(src0[B,C0,64,64], src1[B,C1,64,64]) along channels.
// weights [OC, C0+C1, 3, 3], bias [OC].
// dst[b*dstBatch + oc*HW + p], optional per-oc mask [B, OC, 64, 64].
// Block: 256 threads = 16x16 spatial tile, OCT output channels per block.
// ---------------------------------------------------------------------------
template <int OCT>
__global__ void conv3x3_kernel(const float* __restrict__ src0, int C0,
                               const float* __restrict__ src1, int C1,
                               const float* __restrict__ wgt,
                               const float* __restrict__ bias,
                               float* __restrict__ dst, int dstBatch,
                               const float* __restrict__ mask, int OC) {
    int b = blockIdx.z;
    int ocBase = blockIdx.y * OCT;
    int tile = blockIdx.x;              // 0..15
    int ty0 = (tile >> 2) * 16;
    int tx0 = (tile & 3) * 16;
    int t = threadIdx.x;
    int ty = t >> 4, tx = t & 15;
    int py = ty0 + ty, px = tx0 + tx;

    __shared__ float sIn[18 * 18];

    float acc[OCT];
#pragma unroll
    for (int j = 0; j < OCT; ++j) acc[j] = 0.f;
    int jmax = OC - ocBase;
    if (jmax > OCT) jmax = OCT;

    int Ctot = C0 + C1;
    const float* s0 = src0 + (size_t)b * C0 * HW;
    const float* s1 = (C1 > 0) ? (src1 + (size_t)b * C1 * HW) : (const float*)0;

    for (int ic = 0; ic < Ctot; ++ic) {
        const float* sp = (ic < C0) ? (s0 + (size_t)ic * HW)
                                    : (s1 + (size_t)(ic - C0) * HW);
        __syncthreads();
        for (int i = t; i < 18 * 18; i += 256) {
            int iy = i / 18, ix = i - iy * 18;
            int gy = ty0 + iy - 1, gx = tx0 + ix - 1;
            float v = 0.f;
            if (gy >= 0 && gy < IMG && gx >= 0 && gx < IMG) v = sp[gy * IMG + gx];
            sIn[i] = v;
        }
        __syncthreads();
        float in0 = sIn[(ty + 0) * 18 + tx + 0];
        float in1 = sIn[(ty + 0) * 18 + tx + 1];
        float in2 = sIn[(ty + 0) * 18 + tx + 2];
        float in3 = sIn[(ty + 1) * 18 + tx + 0];
        float in4 = sIn[(ty + 1) * 18 + tx + 1];
        float in5 = sIn[(ty + 1) * 18 + tx + 2];
        float in6 = sIn[(ty + 2) * 18 + tx + 0];
        float in7 = sIn[(ty + 2) * 18 + tx + 1];
        float in8 = sIn[(ty + 2) * 18 + tx + 2];
        const float* wrow = wgt + ((size_t)ocBase * Ctot + ic) * 9;
        if (jmax == OCT) {
#pragma unroll
            for (int j = 0; j < OCT; ++j) {
                const float* w = wrow + (size_t)j * Ctot * 9;
                float a = acc[j];
                a = fmaf(w[0], in0, a); a = fmaf(w[1], in1, a); a = fmaf(w[2], in2, a);
                a = fmaf(w[3], in3, a); a = fmaf(w[4], in4, a); a = fmaf(w[5], in5, a);
                a = fmaf(w[6], in6, a); a = fmaf(w[7], in7, a); a = fmaf(w[8], in8, a);
                acc[j] = a;
            }
        } else {
            for (int j = 0; j < jmax; ++j) {
                const float* w = wrow + (size_t)j * Ctot * 9;
                float a = acc[j];
                a = fmaf(w[0], in0, a); a = fmaf(w[1], in1, a); a = fmaf(w[2], in2, a);
                a = fmaf(w[3], in3, a); a = fmaf(w[4], in4, a); a = fmaf(w[5], in5, a);
                a = fmaf(w[6], in6, a); a = fmaf(w[7], in7, a); a = fmaf(w[8], in8, a);
                acc[j] = a;
            }
        }
    }
    for (int j = 0; j < jmax; ++j) {
        int oc = ocBase + j;
        float v = acc[j] + bias[oc];
        if (mask) v *= mask[((size_t)b * OC + oc) * HW + py * IMG + px];
        dst[(size_t)b * dstBatch + (size_t)oc * HW + py * IMG + px] = v;
    }
}

// ---------------------------------------------------------------------------
// copy x into inp channels [0,256)
// ---------------------------------------------------------------------------
__global__ void copy_x_kernel(const float4* __restrict__ x, float* __restrict__ inp) {
    int idx = blockIdx.x * 256 + threadIdx.x;      // over 524288 float4
    float4 v = x[idx];
    size_t e = (size_t)idx * 4;
    int b = (int)(e >> 20);
    size_t rem = e & ((1u << 20) - 1);
    *(float4*)(inp + (size_t)b * 294 * HW + rem) = v;
}

// ---------------------------------------------------------------------------
// SE layer
// ---------------------------------------------------------------------------
__global__ void se_reduce_kernel(const float* __restrict__ cat, float* __restrict__ y) {
    __shared__ float sd[4];
    int c = blockIdx.x, b = blockIdx.y;
    const float* p = cat + ((size_t)b * 768 + c) * HW;
    float s = 0.f;
    for (int i = threadIdx.x; i < HW; i += 256) s += p[i];
    s = blockReduceSum(s, sd);
    if (threadIdx.x == 0) y[b * 256 + c] = s * (1.f / 4096.f);
}

__global__ void se_mlp_kernel(const float* __restrict__ y, const float* __restrict__ w1,
                              const float* __restrict__ w2, float* __restrict__ sc) {
    int b = blockIdx.x, t = threadIdx.x;
    __shared__ float sy[256], sh[32];
    sy[t] = y[b * 256 + t];
    __syncthreads();
    if (t < 32) {
        float s = 0.f;
        for (int c = 0; c < 256; ++c) s = fmaf(w1[t * 256 + c], sy[c], s);
        sh[t] = fmaxf(s, 0.f);
    }
    __syncthreads();
    float s = 0.f;
#pragma unroll
    for (int h = 0; h < 32; ++h) s = fmaf(w2[t * 32 + h], sh[h], s);
    sc[b * 256 + t] = 1.f / (1.f + __expf(-s));
}

__global__ void se_scale_kernel(float* __restrict__ cat, const float* __restrict__ sc) {
    int idx = blockIdx.x * 256 + threadIdx.x;      // over 524288 float4
    size_t e = (size_t)idx * 4;
    int b = (int)(e >> 20);
    size_t rem = e & ((1u << 20) - 1);
    int c = (int)(rem >> 12);
    float4* p = (float4*)(cat + (size_t)b * 768 * HW + rem);
    float4 v = *p;
    float s = sc[b * 256 + c];
    v.x *= s; v.y *= s; v.z *= s; v.w *= s;
    *p = v;
}

// ---------------------------------------------------------------------------
// E[n,m] = sum_d q[d,n] * k[d,m]   (per batch; q,k are [32,4096])
// ---------------------------------------------------------------------------
__global__ void energy_kernel(const float* __restrict__ q, const float* __restrict__ k,
                              float* __restrict__ E) {
    __shared__ float sQ[32][64];
    __shared__ float sK[32][64];
    int t = threadIdx.x;
    int m0 = blockIdx.x * 64, n0 = blockIdx.y * 64;
    for (int i = t; i < 2048; i += 256) {
        int d = i >> 6, c = i & 63;
        sQ[d][c] = q[(size_t)d * HW + n0 + c];
        sK[d][c] = k[(size_t)d * HW + m0 + c];
    }
    __syncthreads();
    int tn = (t >> 4) * 4, tm = (t & 15) * 4;
    float acc[4][4] = {};
#pragma unroll 8
    for (int d = 0; d < 32; ++d) {
        float4 qv = *(const float4*)&sQ[d][tn];
        float4 kv = *(const float4*)&sK[d][tm];
        float qa[4] = {qv.x, qv.y, qv.z, qv.w};
        float ka[4] = {kv.x, kv.y, kv.z, kv.w};
#pragma unroll
        for (int i = 0; i < 4; ++i)
#pragma unroll
            for (int j = 0; j < 4; ++j) acc[i][j] = fmaf(qa[i], ka[j], acc[i][j]);
    }
#pragma unroll
    for (int i = 0; i < 4; ++i) {
        float4 o = make_float4(acc[i][0], acc[i][1], acc[i][2], acc[i][3]);
        *(float4*)&E[(size_t)(n0 + tn + i) * HW + m0 + tm] = o;
    }
}

// ---------------------------------------------------------------------------
// row softmax stats: rmax[n], rinv[n] = 1/sum_m exp(E[n,m]-rmax[n])
// ---------------------------------------------------------------------------
__global__ void rowstats_kernel(const float* __restrict__ E, float* __restrict__ rmax,
                                float* __restrict__ rinv) {
    __shared__ float sd[4];
    int n = blockIdx.x;
    const float* row = E + (size_t)n * HW;
    float vals[16];
    float mx = -3.4e38f;
#pragma unroll
    for (int r = 0; r < 16; ++r) {
        vals[r] = row[threadIdx.x + 256 * r];
        mx = fmaxf(mx, vals[r]);
    }
    mx = blockReduceMax(mx, sd);
    float s = 0.f;
#pragma unroll
    for (int r = 0; r < 16; ++r) s += __expf(vals[r] - mx);
    s = blockReduceSum(s, sd);
    if (threadIdx.x == 0) { rmax[n] = mx; rinv[n] = 1.f / s; }
}

// column softmax stats (two-step): partial over 128-row chunks, then combine
__global__ void colstats_partial_kernel(const float* __restrict__ E,
                                        float* __restrict__ pmax, float* __restrict__ psum) {
    int m = blockIdx.x * 256 + threadIdx.x;
    int n0 = blockIdx.y * 128;
    float mx = -3.4e38f;
    for (int n = n0; n < n0 + 128; ++n) mx = fmaxf(mx, E[(size_t)n * HW + m]);
    float s = 0.f;
    for (int n = n0; n < n0 + 128; ++n) s += __expf(E[(size_t)n * HW + m] - mx);
    pmax[blockIdx.y * HW + m] = mx;
    psum[blockIdx.y * HW + m] = s;
}

__global__ void colstats_combine_kernel(const float* __restrict__ pmax,
                                        const float* __restrict__ psum,
                                        float* __restrict__ cmax, float* __restrict__ cinv) {
    int m = blockIdx.x * 256 + threadIdx.x;
    float mx = -3.4e38f;
    for (int c = 0; c < 32; ++c) mx = fmaxf(mx, pmax[c * HW + m]);
    float s = 0.f;
    for (int c = 0; c < 32; ++c) s += psum[c * HW + m] * __expf(pmax[c * HW + m] - mx);
    cmax[m] = mx;
    cinv[m] = 1.f / s;
}

// ---------------------------------------------------------------------------
// out[c,p] = sum_j v[c,j] * P[j,p]
//   mode 0 (out_b): P[j,p] = exp(E[p,j]-rmax[p])*rinv[p]
//   mode 1 (out_c): P[j,p] = exp(E[j,p]-cmax[p])*cinv[p]
// dst layout: dst + mode*256*HW + c*HW + p   (channels 256.. / 512.. of cat)
// ---------------------------------------------------------------------------
__global__ void attn_gemm_kernel(const float* __restrict__ vmat, const float* __restrict__ E,
                                 const float* __restrict__ rmax, const float* __restrict__ rinv,
                                 const float* __restrict__ cmax, const float* __restrict__ cinv,
                                 float* __restrict__ dst) {
    int mode = blockIdx.z;
    int p0 = blockIdx.x * 64;
    int c0 = blockIdx.y * 64;
    const float* mx = mode ? cmax : rmax;
    const float* iv = mode ? cinv : rinv;
    float* out = dst + (size_t)mode * 256 * HW;

    __shared__ float sV[32][68];   // sV[j][c]
    __shared__ float sB[32][68];   // sB[j][p]
    __shared__ float sMx[64], sInv[64];
    int t = threadIdx.x;
    if (t < 64) { sMx[t] = mx[p0 + t]; sInv[t] = iv[p0 + t]; }

    float acc[4][4] = {};
    int tc = (t >> 4) * 4, tp = (t & 15) * 4;

    for (int j0 = 0; j0 < HW; j0 += 32) {
        __syncthreads();
        for (int i = t; i < 2048; i += 256) {
            int jj = i & 31, cc = i >> 5;
            sV[jj][cc] = vmat[(size_t)(c0 + cc) * HW + j0 + jj];
        }
        if (mode == 0) {
            for (int i = t; i < 2048; i += 256) {
                int jj = i & 31, pp = i >> 5;
                float e = E[(size_t)(p0 + pp) * HW + j0 + jj];
                sB[jj][pp] = __expf(e - sMx[pp]) * sInv[pp];
            }
        } else {
            for (int i = t; i < 2048; i += 256) {
                int pp = i & 63, jj = i >> 6;
                float e = E[(size_t)(j0 + jj) * HW + p0 + pp];
                sB[jj][pp] = __expf(e - sMx[pp]) * sInv[pp];
            }
        }
        __syncthreads();
#pragma unroll 8
        for (int jj = 0; jj < 32; ++jj) {
            float4 vv = *(const float4*)&sV[jj][tc];
            float4 bb = *(const float4*)&sB[jj][tp];
            float va[4] = {vv.x, vv.y, vv.z, vv.w};
            float ba[4] = {bb.x, bb.y, bb.z, bb.w};
#pragma unroll
            for (int i = 0; i < 4; ++i)
#pragma unroll
                for (int j = 0; j < 4; ++j) acc[i][j] = fmaf(va[i], ba[j], acc[i][j]);
        }
    }
#pragma unroll
    for (int i = 0; i < 4; ++i) {
        float4 o = make_float4(acc[i][0], acc[i][1], acc[i][2], acc[i][3]);
        *(float4*)&out[(size_t)(c0 + tc + i) * HW + p0 + tp] = o;
    }
}

// ---------------------------------------------------------------------------
extern "C" void kernel_launch(void* const* d_in, const int* in_sizes, int n_in,
                              void* d_out, int out_size, void* d_ws, size_t ws_size,
                              hipStream_t stream) {
    const float* x      = (const float*)d_in[0];
    const float* mmask  = (const float*)d_in[1];
    const float* amask  = (const float*)d_in[2];
    const float* w_mp   = (const float*)d_in[3];
    const float* b_mp   = (const float*)d_in[4];
    const float* w_ap   = (const float*)d_in[5];
    const float* b_ap   = (const float*)d_in[6];
    const float* w_q    = (const float*)d_in[7];
    const float* b_q    = (const float*)d_in[8];
    const float* w_k    = (const float*)d_in[9];
    const float* b_k    = (const float*)d_in[10];
    const float* w_v    = (const float*)d_in[11];
    const float* b_v    = (const float*)d_in[12];
    const float* w_comp = (const float*)d_in[13];
    const float* b_comp = (const float*)d_in[14];
    const float* w_out  = (const float*)d_in[15];
    const float* b_out  = (const float*)d_in[16];
    const float* w_se1  = (const float*)d_in[17];
    const float* w_se2  = (const float*)d_in[18];

    float* ws = (float*)d_ws;
    size_t o = 0;
    float* inp  = ws + o; o += (size_t)2 * 294 * HW;   // [B,294,64,64]
    float* cat  = ws + o; o += (size_t)2 * 768 * HW;   // [B,768,64,64]
    float* qb   = ws + o; o += (size_t)2 * 32 * HW;
    float* kb   = ws + o; o += (size_t)2 * 32 * HW;
    float* vb   = ws + o; o += (size_t)2 * 256 * HW;
    float* E    = ws + o; o += (size_t)HW * HW;        // per-batch reuse
    float* rmax = ws + o; o += HW;
    float* rinv = ws + o; o += HW;
    float* cmax = ws + o; o += HW;
    float* cinv = ws + o; o += HW;
    float* pmax = ws + o; o += (size_t)32 * HW;
    float* psum = ws + o; o += (size_t)32 * HW;
    float* ybuf = ws + o; o += 512;
    float* sbuf = ws + o; o += 512;
    if (ws_size < o * sizeof(float)) return;  // workspace too small

    float* outp = (float*)d_out;

    // 1. inp[:, 0:256] = x
    copy_x_kernel<<<2048, 256, 0, stream>>>((const float4*)x, inp);
    // 2/3. modal_x / amodal_x (conv + mask) into inp at ch 256 / 275
    conv3x3_kernel<4><<<dim3(16, 5, 2), 256, 0, stream>>>(
        x, 256, (const float*)0, 0, w_mp, b_mp, inp + (size_t)256 * HW, 294 * HW, mmask, 19);
    conv3x3_kernel<4><<<dim3(16, 5, 2), 256, 0, stream>>>(
        x, 256, (const float*)0, 0, w_ap, b_ap, inp + (size_t)275 * HW, 294 * HW, amask, 19);
    // 4. comp conv -> cat[:, 0:256]
    conv3x3_kernel<16><<<dim3(16, 16, 2), 256, 0, stream>>>(
        inp, 294, (const float*)0, 0, w_comp, b_comp, cat, 768 * HW, (const float*)0, 256);
    // q/k/v convs
    conv3x3_kernel<4><<<dim3(16, 8, 2), 256, 0, stream>>>(
        x, 256, mmask, 19, w_q, b_q, qb, 32 * HW, (const float*)0, 32);
    conv3x3_kernel<4><<<dim3(16, 8, 2), 256, 0, stream>>>(
        x, 256, amask, 19, w_k, b_k, kb, 32 * HW, (const float*)0, 32);
    conv3x3_kernel<16><<<dim3(16, 16, 2), 256, 0, stream>>>(
        x, 256, (const float*)0, 0, w_v, b_v, vb, 256 * HW, (const float*)0, 256);
    // SE
    se_reduce_kernel<<<dim3(256, 2), 256, 0, stream>>>(cat, ybuf);
    se_mlp_kernel<<<2, 256, 0, stream>>>(ybuf, w_se1, w_se2, sbuf);
    se_scale_kernel<<<2048, 256, 0, stream>>>(cat, sbuf);
    // attention, per batch
    for (int bb = 0; bb < 2; ++bb) {
        energy_kernel<<<dim3(64, 64), 256, 0, stream>>>(
            qb + (size_t)bb * 32 * HW, kb + (size_t)bb * 32 * HW, E);
        rowstats_kernel<<<4096, 256, 0, stream>>>(E, rmax, rinv);
        colstats_partial_kernel<<<dim3(16, 32), 256, 0, stream>>>(E, pmax, psum);
        colstats_combine_kernel<<<16, 256, 0, stream>>>(pmax, psum, cmax, cinv);
        attn_gemm_kernel<<<dim3(64, 4, 2), 256, 0, stream>>>(
            vb + (size_t)bb * 256 * HW, E, rmax, rinv, cmax, cinv,
            cat + (size_t)bb * 768 * HW + (size_t)256 * HW);
    }
    // final conv over cat (768 ch) -> d_out
    conv3x3_kernel<16><<<dim3(16, 16, 2), 256, 0, stream>>>(
        cat, 768, (const float*)0, 0, w_out, b_out, outp, 256 * HW, (const float*)0, 256);
}

// Round 2
// 1634.154 us; speedup vs baseline: 3.5700x; 3.5700x over previous
//
#include <hip/hip_runtime.h>
#include <math.h>

#define HW 4096
#define IMG 64
#define PIX66 (66 * 66)

typedef short short8 __attribute__((ext_vector_type(8)));
typedef float f32x4 __attribute__((ext_vector_type(4)));

__device__ __forceinline__ unsigned short f2bf(float f) {
    unsigned int u = __float_as_uint(f);
    u += 0x7fff + ((u >> 16) & 1);
    return (unsigned short)(u >> 16);
}
__device__ __forceinline__ float bf2f(unsigned short h) {
    return __uint_as_float(((unsigned int)h) << 16);
}

// ---------------------------------------------------------------------------
// weight transform: w fp32 [OC][C0+C1][9] -> wT bf16 [9][OCpad][Ktot]
// seg0: k in [0,C0) -> ic=k ; seg1: k in [K0pad, K0pad+C1) -> ic=C0+k-K0pad
// ---------------------------------------------------------------------------
__global__ __launch_bounds__(256) void k_wt(const float* __restrict__ w,
                                            unsigned short* __restrict__ dh,
                                            unsigned short* __restrict__ dl,
                                            int OC, int OCpad, int C0, int K0pad,
                                            int C1, int Ktot) {
    int idx = blockIdx.x * 256 + threadIdx.x;
    int n = 9 * OCpad * Ktot;
    if (idx >= n) return;
    int k = idx % Ktot;
    int rest = idx / Ktot;
    int oc = rest % OCpad;
    // int tap = rest / OCpad;  (implicit in idx layout)
    float v = 0.f;
    if (oc < OC) {
        int ic = -1;
        if (k < C0) ic = k;
        else if (k >= K0pad && (k - K0pad) < C1) ic = C0 + (k - K0pad);
        if (ic >= 0) {
            int tap = rest / OCpad;
            v = w[((size_t)oc * (C0 + C1) + ic) * 9 + tap];
        }
    }
    unsigned short hi = f2bf(v);
    dh[idx] = hi;
    if (dl) dl[idx] = f2bf(v - bf2f(hi));
}

// ---------------------------------------------------------------------------
// build NHWC-padded bf16 x (hi+lo) and ipad channels 0..255
// ---------------------------------------------------------------------------
__global__ __launch_bounds__(256) void k_build_x(const float* __restrict__ x,
                                                 unsigned short* __restrict__ xh,
                                                 unsigned short* __restrict__ xl,
                                                 unsigned short* __restrict__ ipad) {
    int b = blockIdx.z, c0 = blockIdx.y * 64, p0 = blockIdx.x * 64;
    __shared__ float s[64][65];
    int t = threadIdx.x;
    for (int i = t; i < 4096; i += 256) {
        int c = i >> 6, p = i & 63;
        s[p][c] = x[((size_t)b * 256 + c0 + c) * HW + p0 + p];
    }
    __syncthreads();
    for (int i = t; i < 4096; i += 256) {
        int c = i & 63, p = i >> 6;
        float f = s[p][c];
        unsigned short hi = f2bf(f);
        unsigned short lo = f2bf(f - bf2f(hi));
        int pp = p0 + p;
        int y = pp >> 6, xx = pp & 63;
        size_t pix = (size_t)((y + 1) * 66 + xx + 1);
        xh[(size_t)b * (PIX66 * 256) + pix * 256 + c0 + c] = hi;
        xl[(size_t)b * (PIX66 * 256) + pix * 256 + c0 + c] = lo;
        ipad[(size_t)b * (PIX66 * 320) + pix * 320 + c0 + c] = hi;
    }
}

// masks -> NHWC bf16 hi/lo, 32-channel padded
__global__ __launch_bounds__(256) void k_build_mask(const float* __restrict__ m,
                                                    unsigned short* __restrict__ dh,
                                                    unsigned short* __restrict__ dl) {
    int idx = blockIdx.x * 256 + threadIdx.x;   // 2*4096*32
    int c = idx & 31;
    int p = (idx >> 5) & 4095;
    int b = idx >> 17;
    float f = (c < 19) ? m[((size_t)b * 19 + c) * HW + p] : 0.f;
    unsigned short hi = f2bf(f);
    int y = p >> 6, xx = p & 63;
    size_t pix = (size_t)((y + 1) * 66 + xx + 1);
    dh[(size_t)b * (PIX66 * 32) + pix * 32 + c] = hi;
    dl[(size_t)b * (PIX66 * 32) + pix * 32 + c] = f2bf(f - bf2f(hi));
}

// ---------------------------------------------------------------------------
// MFMA implicit-GEMM conv. Wave tile 32px x 32oc (2x2 16x16 MFMA tiles).
// Block: WPP waves along pixels, WPO along oc.
// MODE 0: fp32 NCHW + bias        (out conv -> d_out)
// MODE 1: (acc+bias)*mask -> bf16 NHWC at chBase (mp/ap -> ipad)
// MODE 2: split bf16 pixel-major [p][32] hi+lo   (q/k)
// MODE 3: bf16 CHW [oc][4096]                    (v)
// MODE 4: bf16 NHWC + atomic channel-mean accum  (comp -> catN + ybuf)
// SPLIT: 3 passes (hi*Whi, hi*Wlo, lo*Whi)
// ---------------------------------------------------------------------------
template <int WPP, int WPO, int MODE, int SPLIT>
__global__ __launch_bounds__(256) void conv_mfma(
    const unsigned short* __restrict__ s0h, const unsigned short* __restrict__ s0l, int C0,
    const unsigned short* __restrict__ s1h, const unsigned short* __restrict__ s1l, int C1,
    const unsigned short* __restrict__ wth, const unsigned short* __restrict__ wtl, int OCpad,
    const float* __restrict__ bias,
    float* __restrict__ dstf, size_t batF,
    unsigned short* __restrict__ dstb, unsigned short* __restrict__ dstb2, size_t batB,
    int strideC, int chBase,
    const float* __restrict__ mask, int OCreal,
    float* __restrict__ ybuf) {
    int b = blockIdx.z;
    int t = threadIdx.x, w = t >> 6, l = t & 63, quad = l >> 4, ln = l & 15;
    int wP = w % WPP, wO = w / WPP;
    int pBase = blockIdx.x * (WPP * 32) + wP * 32;
    int ocBase = blockIdx.y * (WPO * 32) + wO * 32;
    int Ktot = C0 + C1;

    long nb0[2], nb1[2];
#pragma unroll
    for (int tn = 0; tn < 2; ++tn) {
        int p = pBase + tn * 16 + ln;
        int y = p >> 6, x = p & 63;
        nb0[tn] = (long)((y + 1) * 66 + (x + 1)) * C0 + quad * 8;
        nb1[tn] = C1 ? (long)((y + 1) * 66 + (x + 1)) * C1 + quad * 8 : 0;
    }
    size_t aoff[2];
#pragma unroll
    for (int tm = 0; tm < 2; ++tm)
        aoff[tm] = (size_t)(ocBase + tm * 16 + ln) * Ktot + quad * 8;

    f32x4 acc[2][2];
#pragma unroll
    for (int i = 0; i < 2; ++i)
#pragma unroll
        for (int j = 0; j < 2; ++j) acc[i][j] = (f32x4){0.f, 0.f, 0.f, 0.f};

    const int npass = SPLIT ? 3 : 1;
    for (int ps = 0; ps < npass; ++ps) {
        const unsigned short* S0 =
            ((SPLIT && ps == 2) ? s0l : s0h) + (size_t)b * PIX66 * C0;
        const unsigned short* S1 =
            C1 ? (((SPLIT && ps == 2) ? s1l : s1h) + (size_t)b * PIX66 * C1) : (const unsigned short*)0;
        const unsigned short* WT = (SPLIT && ps == 1) ? wtl : wth;
        for (int tap = 0; tap < 9; ++tap) {
            int dy = tap / 3 - 1, dx = tap % 3 - 1;
            long o0 = (long)(dy * 66 + dx) * C0;
            long o1 = (long)(dy * 66 + dx) * C1;
            const unsigned short* WTt = WT + (size_t)tap * OCpad * Ktot;
            for (int kb = 0; kb < Ktot; kb += 32) {
                short8 bfr[2], afr[2];
                if (kb < C0) {
#pragma unroll
                    for (int tn = 0; tn < 2; ++tn)
                        bfr[tn] = *(const short8*)(S0 + nb0[tn] + o0 + kb);
                } else {
#pragma unroll
                    for (int tn = 0; tn < 2; ++tn)
                        bfr[tn] = *(const short8*)(S1 + nb1[tn] + o1 + (kb - C0));
                }
#pragma unroll
                for (int tm = 0; tm < 2; ++tm)
                    afr[tm] = *(const short8*)(WTt + aoff[tm] + kb);
#pragma unroll
                for (int tm = 0; tm < 2; ++tm)
#pragma unroll
                    for (int tn = 0; tn < 2; ++tn)
                        acc[tm][tn] = __builtin_amdgcn_mfma_f32_16x16x32_bf16(
                            afr[tm], bfr[tn], acc[tm][tn], 0, 0, 0);
            }
        }
    }

#pragma unroll
    for (int tm = 0; tm < 2; ++tm) {
#pragma unroll
        for (int r = 0; r < 4; ++r) {
            int oc = ocBase + tm * 16 + quad * 4 + r;
            float bi;
            if (MODE == 1) bi = (oc < OCreal) ? bias[oc] : 0.f;
            else bi = bias[oc];
            float msum = 0.f;
#pragma unroll
            for (int tn = 0; tn < 2; ++tn) {
                int p = pBase + tn * 16 + ln;
                float v = acc[tm][tn][r] + bi;
                if (MODE == 0) {
                    dstf[(size_t)b * batF + (size_t)oc * HW + p] = v;
                } else if (MODE == 1) {
                    if (oc < OCreal) {
                        v *= mask[((size_t)b * OCreal + oc) * HW + p];
                        int y = p >> 6, x = p & 63;
                        dstb[(size_t)b * batB + (size_t)((y + 1) * 66 + x + 1) * strideC +
                             chBase + oc] = f2bf(v);
                    }
                } else if (MODE == 2) {
                    unsigned short hi = f2bf(v);
                    dstb[(size_t)b * batB + (size_t)p * 32 + oc] = hi;
                    dstb2[(size_t)b * batB + (size_t)p * 32 + oc] = f2bf(v - bf2f(hi));
                } else if (MODE == 3) {
                    dstb[(size_t)b * batB + (size_t)oc * HW + p] = f2bf(v);
                } else {  // MODE 4
                    int y = p >> 6, x = p & 63;
                    dstb[(size_t)b * batB + (size_t)((y + 1) * 66 + x + 1) * strideC +
                         chBase + oc] = f2bf(v);
                    msum += v;
                }
            }
            if (MODE == 4) {
#pragma unroll
                for (int off = 8; off; off >>= 1) msum += __shfl_down(msum, off, 16);
                if (ln == 0) atomicAdd(&ybuf[b * 256 + oc], msum);
            }
        }
    }
}

// ---------------------------------------------------------------------------
// E[n][m] = q[n]·k[m], split hi/lo bf16 (4 MFMA terms), K=32 in one step
// ---------------------------------------------------------------------------
__global__ __launch_bounds__(256) void energy_mfma(const unsigned short* __restrict__ qh,
                                                   const unsigned short* __restrict__ ql,
                                                   const unsigned short* __restrict__ kh,
                                                   const unsigned short* __restrict__ kl,
                                                   float* __restrict__ E) {
    int t = threadIdx.x, w = t >> 6, l = t & 63, quad = l >> 4, ln = l & 15;
    int nBase = blockIdx.y * 64 + (w >> 1) * 32;
    int mBase = blockIdx.x * 64 + (w & 1) * 32;
    size_t ao[2], bo[2];
#pragma unroll
    for (int i = 0; i < 2; ++i) {
        ao[i] = (size_t)(nBase + i * 16 + ln) * 32 + quad * 8;
        bo[i] = (size_t)(mBase + i * 16 + ln) * 32 + quad * 8;
    }
    short8 ah[2], al[2], bh[2], bl[2];
#pragma unroll
    for (int i = 0; i < 2; ++i) {
        ah[i] = *(const short8*)(qh + ao[i]);
        al[i] = *(const short8*)(ql + ao[i]);
        bh[i] = *(const short8*)(kh + bo[i]);
        bl[i] = *(const short8*)(kl + bo[i]);
    }
    f32x4 acc[2][2];
#pragma unroll
    for (int i = 0; i < 2; ++i)
#pragma unroll
        for (int j = 0; j < 2; ++j) acc[i][j] = (f32x4){0.f, 0.f, 0.f, 0.f};
#pragma unroll
    for (int i = 0; i < 2; ++i)
#pragma unroll
        for (int j = 0; j < 2; ++j) {
            acc[i][j] = __builtin_amdgcn_mfma_f32_16x16x32_bf16(ah[i], bh[j], acc[i][j], 0, 0, 0);
            acc[i][j] = __builtin_amdgcn_mfma_f32_16x16x32_bf16(ah[i], bl[j], acc[i][j], 0, 0, 0);
            acc[i][j] = __builtin_amdgcn_mfma_f32_16x16x32_bf16(al[i], bh[j], acc[i][j], 0, 0, 0);
            acc[i][j] = __builtin_amdgcn_mfma_f32_16x16x32_bf16(al[i], bl[j], acc[i][j], 0, 0, 0);
        }
#pragma unroll
    for (int i = 0; i < 2; ++i)
#pragma unroll
        for (int j = 0; j < 2; ++j)
#pragma unroll
            for (int r = 0; r < 4; ++r)
                E[(size_t)(nBase + i * 16 + quad * 4 + r) * HW + mBase + j * 16 + ln] =
                    acc[i][j][r];
}

// ---------------------------------------------------------------------------
// softmax stats (unchanged fp32)
// ---------------------------------------------------------------------------
__device__ __forceinline__ float blockReduceMax(float v, float* sd) {
#pragma unroll
    for (int o = 32; o > 0; o >>= 1) v = fmaxf(v, __shfl_down(v, o));
    if ((threadIdx.x & 63) == 0) sd[threadIdx.x >> 6] = v;
    __syncthreads();
    float r = fmaxf(fmaxf(sd[0], sd[1]), fmaxf(sd[2], sd[3]));
    __syncthreads();
    return r;
}
__device__ __forceinline__ float blockReduceSum(float v, float* sd) {
#pragma unroll
    for (int o = 32; o > 0; o >>= 1) v += __shfl_down(v, o);
    if ((threadIdx.x & 63) == 0) sd[threadIdx.x >> 6] = v;
    __syncthreads();
    float r = sd[0] + sd[1] + sd[2] + sd[3];
    __syncthreads();
    return r;
}

__global__ __launch_bounds__(256) void rowstats_kernel(const float* __restrict__ E,
                                                       float* __restrict__ rmax,
                                                       float* __restrict__ rinv) {
    __shared__ float sd[4];
    int n = blockIdx.x;
    const float* row = E + (size_t)n * HW;
    float vals[16];
    float mx = -3.4e38f;
#pragma unroll
    for (int r = 0; r < 16; ++r) {
        vals[r] = row[threadIdx.x + 256 * r];
        mx = fmaxf(mx, vals[r]);
    }
    mx = blockReduceMax(mx, sd);
    float s = 0.f;
#pragma unroll
    for (int r = 0; r < 16; ++r) s += __expf(vals[r] - mx);
    s = blockReduceSum(s, sd);
    if (threadIdx.x == 0) { rmax[n] = mx; rinv[n] = 1.f / s; }
}

__global__ __launch_bounds__(256) void colstats_partial_kernel(const float* __restrict__ E,
                                                               float* __restrict__ pmax,
                                                               float* __restrict__ psum) {
    int m = blockIdx.x * 256 + threadIdx.x;
    int n0 = blockIdx.y * 128;
    float mx = -3.4e38f;
    for (int n = n0; n < n0 + 128; ++n) mx = fmaxf(mx, E[(size_t)n * HW + m]);
    float s = 0.f;
    for (int n = n0; n < n0 + 128; ++n) s += __expf(E[(size_t)n * HW + m] - mx);
    pmax[blockIdx.y * HW + m] = mx;
    psum[blockIdx.y * HW + m] = s;
}

__global__ __launch_bounds__(256) void colstats_combine_kernel(const float* __restrict__ pmax,
                                                               const float* __restrict__ psum,
                                                               float* __restrict__ cmax,
                                                               float* __restrict__ cinv) {
    int m = blockIdx.x * 256 + threadIdx.x;
    float mx = -3.4e38f;
    for (int c = 0; c < 32; ++c) mx = fmaxf(mx, pmax[c * HW + m]);
    float s = 0.f;
    for (int c = 0; c < 32; ++c) s += psum[c * HW + m] * __expf(pmax[c * HW + m] - mx);
    cmax[m] = mx;
    cinv[m] = 1.f / s;
}

// ---------------------------------------------------------------------------
// attention GEMM: out[c,p] = sum_j v[c,j] * P[j,p], P staged per 32-j tile in
// LDS as bf16 with exp applied. Block tile 128c x 64p, wave 64c x 32p.
// mode 0: P[j,p]=exp(E[p,j]-rmax[p])*rinv[p]; mode 1: exp(E[j,p]-cmax[p])*cinv[p]
// ---------------------------------------------------------------------------
__global__ __launch_bounds__(256) void attn_mfma(const unsigned short* __restrict__ vbf,
                                                 const float* __restrict__ E,
                                                 const float* __restrict__ rmax,
                                                 const float* __restrict__ rinv,
                                                 const float* __restrict__ cmax,
                                                 const float* __restrict__ cinv,
                                                 unsigned short* __restrict__ catW) {
    int mode = blockIdx.z;
    const float* mxp = mode ? cmax : rmax;
    const float* ivp = mode ? cinv : rinv;
    int t = threadIdx.x, w = t >> 6, l = t & 63, quad = l >> 4, ln = l & 15;
    int p0 = blockIdx.x * 64;
    int cBase = blockIdx.y * 128 + (w >> 1) * 64;
    int pw = (w & 1) * 32;

    __shared__ unsigned short sP[64 * 40];
    __shared__ float sMx[64], sInv[64];
    if (t < 64) { sMx[t] = mxp[p0 + t]; sInv[t] = ivp[p0 + t]; }

    f32x4 acc[4][2];
#pragma unroll
    for (int i = 0; i < 4; ++i)
#pragma unroll
        for (int j = 0; j < 2; ++j) acc[i][j] = (f32x4){0.f, 0.f, 0.f, 0.f};
    size_t aoff[4];
#pragma unroll
    for (int tm = 0; tm < 4; ++tm)
        aoff[tm] = (size_t)(cBase + tm * 16 + ln) * HW + quad * 8;

    for (int jb = 0; jb < HW; jb += 32) {
        __syncthreads();
        if (mode == 0) {
            for (int i = t; i < 2048; i += 256) {
                int p = i >> 5, j = i & 31;
                float e = E[(size_t)(p0 + p) * HW + jb + j];
                sP[p * 40 + j] = f2bf(__expf(e - sMx[p]) * sInv[p]);
            }
        } else {
            for (int i = t; i < 2048; i += 256) {
                int j = i >> 6, p = i & 63;
                float e = E[(size_t)(jb + j) * HW + p0 + p];
                sP[p * 40 + j] = f2bf(__expf(e - sMx[p]) * sInv[p]);
            }
        }
        __syncthreads();
        short8 bfr[2], afr[4];
#pragma unroll
        for (int tn = 0; tn < 2; ++tn)
            bfr[tn] = *(const short8*)&sP[(pw + tn * 16 + ln) * 40 + quad * 8];
#pragma unroll
        for (int tm = 0; tm < 4; ++tm)
            afr[tm] = *(const short8*)(vbf + aoff[tm] + jb);
#pragma unroll
        for (int tm = 0; tm < 4; ++tm)
#pragma unroll
            for (int tn = 0; tn < 2; ++tn)
                acc[tm][tn] = __builtin_amdgcn_mfma_f32_16x16x32_bf16(
                    afr[tm], bfr[tn], acc[tm][tn], 0, 0, 0);
    }
#pragma unroll
    for (int tm = 0; tm < 4; ++tm)
#pragma unroll
        for (int tn = 0; tn < 2; ++tn)
#pragma unroll
            for (int r = 0; r < 4; ++r) {
                int c = cBase + tm * 16 + quad * 4 + r;
                int p = p0 + pw + tn * 16 + ln;
                int y = p >> 6, x = p & 63;
                catW[(size_t)((y + 1) * 66 + x + 1) * 768 + 256 + mode * 256 + c] =
                    f2bf(acc[tm][tn][r]);
            }
}

// ---------------------------------------------------------------------------
// SE mlp (reads channel sums, /4096) and in-place scale of catN ch 0..255
// ---------------------------------------------------------------------------
__global__ __launch_bounds__(256) void se_mlp_kernel(const float* __restrict__ y,
                                                     const float* __restrict__ w1,
                                                     const float* __restrict__ w2,
                                                     float* __restrict__ sc) {
    int b = blockIdx.x, t = threadIdx.x;
    __shared__ float sy[256], sh[32];
    sy[t] = y[b * 256 + t] * (1.f / 4096.f);
    __syncthreads();
    if (t < 32) {
        float s = 0.f;
        for (int c = 0; c < 256; ++c) s = fmaf(w1[t * 256 + c], sy[c], s);
        sh[t] = fmaxf(s, 0.f);
    }
    __syncthreads();
    float s = 0.f;
#pragma unroll
    for (int h = 0; h < 32; ++h) s = fmaf(w2[t * 32 + h], sh[h], s);
    sc[b * 256 + t] = 1.f / (1.f + __expf(-s));
}

__global__ __launch_bounds__(256) void se_scale_cat(unsigned short* __restrict__ catN,
                                                    const float* __restrict__ sc) {
    int idx = blockIdx.x * 256 + threadIdx.x;   // 2*4096*256
    int c = idx & 255;
    int p = (idx >> 8) & 4095;
    int b = idx >> 20;
    int y = p >> 6, x = p & 63;
    size_t pix = (size_t)((y + 1) * 66 + x + 1);
    unsigned short* q = catN + (size_t)b * (PIX66 * 768) + pix * 768 + c;
    *q = f2bf(bf2f(*q) * sc[b * 256 + c]);
}

// ---------------------------------------------------------------------------
extern "C" void kernel_launch(void* const* d_in, const int* in_sizes, int n_in,
                              void* d_out, int out_size, void* d_ws, size_t ws_size,
                              hipStream_t stream) {
    const float* x      = (const float*)d_in[0];
    const float* mmask  = (const float*)d_in[1];
    const float* amask  = (const float*)d_in[2];
    const float* w_mp   = (const float*)d_in[3];
    const float* b_mp   = (const float*)d_in[4];
    const float* w_ap   = (const float*)d_in[5];
    const float* b_ap   = (const float*)d_in[6];
    const float* w_q    = (const float*)d_in[7];
    const float* b_q    = (const float*)d_in[8];
    const float* w_k    = (const float*)d_in[9];
    const float* b_k    = (const float*)d_in[10];
    const float* w_v    = (const float*)d_in[11];
    const float* b_v    = (const float*)d_in[12];
    const float* w_comp = (const float*)d_in[13];
    const float* b_comp = (const float*)d_in[14];
    const float* w_out  = (const float*)d_in[15];
    const float* b_out  = (const float*)d_in[16];
    const float* w_se1  = (const float*)d_in[17];
    const float* w_se2  = (const float*)d_in[18];

    unsigned short* us = (unsigned short*)d_ws;
    size_t o = 0;
    // ---- zeroed bf16 region ----
    unsigned short* xpad_hi = us + o; o += (size_t)2 * PIX66 * 256;
    unsigned short* xpad_lo = us + o; o += (size_t)2 * PIX66 * 256;
    unsigned short* mq_hi   = us + o; o += (size_t)2 * PIX66 * 32;
    unsigned short* mq_lo   = us + o; o += (size_t)2 * PIX66 * 32;
    unsigned short* ma_hi   = us + o; o += (size_t)2 * PIX66 * 32;
    unsigned short* ma_lo   = us + o; o += (size_t)2 * PIX66 * 32;
    unsigned short* ipad    = us + o; o += (size_t)2 * PIX66 * 320;
    unsigned short* catN    = us + o; o += (size_t)2 * PIX66 * 768;
    size_t zeroBytes = o * sizeof(unsigned short);
    // ---- fully-written bf16 region ----
    unsigned short* wt_mp = us + o; o += (size_t)9 * 32 * 256;
    unsigned short* wt_ap = us + o; o += (size_t)9 * 32 * 256;
    unsigned short* wt_qh = us + o; o += (size_t)9 * 32 * 288;
    unsigned short* wt_ql = us + o; o += (size_t)9 * 32 * 288;
    unsigned short* wt_kh = us + o; o += (size_t)9 * 32 * 288;
    unsigned short* wt_kl = us + o; o += (size_t)9 * 32 * 288;
    unsigned short* wt_v  = us + o; o += (size_t)9 * 256 * 256;
    unsigned short* wt_cp = us + o; o += (size_t)9 * 256 * 320;
    unsigned short* wt_ot = us + o; o += (size_t)9 * 256 * 768;
    unsigned short* qt_h  = us + o; o += (size_t)2 * HW * 32;
    unsigned short* qt_l  = us + o; o += (size_t)2 * HW * 32;
    unsigned short* kt_h  = us + o; o += (size_t)2 * HW * 32;
    unsigned short* kt_l  = us + o; o += (size_t)2 * HW * 32;
    unsigned short* vbf   = us + o; o += (size_t)2 * 256 * HW;
    // ---- fp32 region ----
    float* fp = (float*)(us + o);
    size_t fo = 0;
    float* E    = fp + fo; fo += (size_t)HW * HW;
    float* rmax = fp + fo; fo += HW;
    float* rinv = fp + fo; fo += HW;
    float* cmax = fp + fo; fo += HW;
    float* cinv = fp + fo; fo += HW;
    float* pmax = fp + fo; fo += (size_t)32 * HW;
    float* psum = fp + fo; fo += (size_t)32 * HW;
    float* ybuf = fp + fo; fo += 512;
    float* sbuf = fp + fo; fo += 512;
    size_t need = o * sizeof(unsigned short) + fo * sizeof(float);
    if (ws_size < need) return;

    float* outp = (float*)d_out;

    // zero the padded NHWC buffers + ybuf
    hipMemsetAsync(us, 0, zeroBytes, stream);
    hipMemsetAsync(ybuf, 0, 512 * sizeof(float), stream);

    // weight transforms
    auto wtlaunch = [&](const float* w, unsigned short* dh, unsigned short* dl, int OC,
                        int OCpad, int C0, int K0pad, int C1, int Ktot) {
        int n = 9 * OCpad * Ktot;
        k_wt<<<(n + 255) / 256, 256, 0, stream>>>(w, dh, dl, OC, OCpad, C0, K0pad, C1, Ktot);
    };
    wtlaunch(w_mp, wt_mp, (unsigned short*)0, 19, 32, 256, 256, 0, 256);
    wtlaunch(w_ap, wt_ap, (unsigned short*)0, 19, 32, 256, 256, 0, 256);
    wtlaunch(w_q,  wt_qh, wt_ql, 32, 32, 256, 256, 19, 288);
    wtlaunch(w_k,  wt_kh, wt_kl, 32, 32, 256, 256, 19, 288);
    wtlaunch(w_v,  wt_v,  (unsigned short*)0, 256, 256, 256, 256, 0, 256);
    wtlaunch(w_comp, wt_cp, (unsigned short*)0, 256, 256, 294, 320, 0, 320);
    wtlaunch(w_out,  wt_ot, (unsigned short*)0, 256, 256, 768, 768, 0, 768);

    // inputs -> NHWC bf16
    k_build_x<<<dim3(64, 4, 2), 256, 0, stream>>>(x, xpad_hi, xpad_lo, ipad);
    k_build_mask<<<1024, 256, 0, stream>>>(mmask, mq_hi, mq_lo);
    k_build_mask<<<1024, 256, 0, stream>>>(amask, ma_hi, ma_lo);

    const unsigned short* NUS = (const unsigned short*)0;
    float* NF = (float*)0;
    unsigned short* NUSo = (unsigned short*)0;

    // mp/ap convs -> ipad ch 256 / 275  (mask-multiplied)
    conv_mfma<4, 1, 1, 0><<<dim3(32, 1, 2), 256, 0, stream>>>(
        xpad_hi, NUS, 256, NUS, NUS, 0, wt_mp, NUS, 32, b_mp,
        NF, 0, ipad, NUSo, (size_t)PIX66 * 320, 320, 256, mmask, 19, NF);
    conv_mfma<4, 1, 1, 0><<<dim3(32, 1, 2), 256, 0, stream>>>(
        xpad_hi, NUS, 256, NUS, NUS, 0, wt_ap, NUS, 32, b_ap,
        NF, 0, ipad, NUSo, (size_t)PIX66 * 320, 320, 275, amask, 19, NF);
    // q/k convs (split precision) -> qt/kt hi+lo
    conv_mfma<4, 1, 2, 1><<<dim3(32, 1, 2), 256, 0, stream>>>(
        xpad_hi, xpad_lo, 256, mq_hi, mq_lo, 32, wt_qh, wt_ql, 32, b_q,
        NF, 0, qt_h, qt_l, (size_t)HW * 32, 0, 0, NF, 32, NF);
    conv_mfma<4, 1, 2, 1><<<dim3(32, 1, 2), 256, 0, stream>>>(
        xpad_hi, xpad_lo, 256, ma_hi, ma_lo, 32, wt_kh, wt_kl, 32, b_k,
        NF, 0, kt_h, kt_l, (size_t)HW * 32, 0, 0, NF, 32, NF);
    // v conv -> vbf [c][4096] bf16
    conv_mfma<2, 2, 3, 0><<<dim3(64, 4, 2), 256, 0, stream>>>(
        xpad_hi, NUS, 256, NUS, NUS, 0, wt_v, NUS, 256, b_v,
        NF, 0, vbf, NUSo, (size_t)256 * HW, 0, 0, NF, 256, NF);
    // comp conv -> catN ch 0..255 + channel sums into ybuf
    conv_mfma<2, 2, 4, 0><<<dim3(64, 4, 2), 256, 0, stream>>>(
        ipad, NUS, 320, NUS, NUS, 0, wt_cp, NUS, 256, b_comp,
        NF, 0, catN, NUSo, (size_t)PIX66 * 768, 768, 0, NF, 256, ybuf);
    // SE
    se_mlp_kernel<<<2, 256, 0, stream>>>(ybuf, w_se1, w_se2, sbuf);
    se_scale_cat<<<8192, 256, 0, stream>>>(catN, sbuf);
    // attention per batch
    for (int bb = 0; bb < 2; ++bb) {
        energy_mfma<<<dim3(64, 64), 256, 0, stream>>>(
            qt_h + (size_t)bb * HW * 32, qt_l + (size_t)bb * HW * 32,
            kt_h + (size_t)bb * HW * 32, kt_l + (size_t)bb * HW * 32, E);
        rowstats_kernel<<<4096, 256, 0, stream>>>(E, rmax, rinv);
        colstats_partial_kernel<<<dim3(16, 32), 256, 0, stream>>>(E, pmax, psum);
        colstats_combine_kernel<<<16, 256, 0, stream>>>(pmax, psum, cmax, cinv);
        attn_mfma<<<dim3(64, 2, 2), 256, 0, stream>>>(
            vbf + (size_t)bb * 256 * HW, E, rmax, rinv, cmax, cinv,
            catN + (size_t)bb * PIX66 * 768);
    }
    // final conv -> d_out (fp32 NCHW)
    conv_mfma<2, 2, 0, 0><<<dim3(64, 4, 2), 256, 0, stream>>>(
        catN, NUS, 768, NUS, NUS, 0, wt_ot, NUS, 256, b_out,
        outp, (size_t)256 * HW, NUSo, NUSo, 0, 0, 0, NF, 256, NF);
}

// Round 3
// 911.762 us; speedup vs baseline: 6.3985x; 1.7923x over previous
//
#include <hip/hip_runtime.h>
#include <math.h>

#define HW 4096
#define IMG 64
#define PIX66 (66 * 66)

typedef short short8 __attribute__((ext_vector_type(8)));
typedef float f32x4 __attribute__((ext_vector_type(4)));
typedef unsigned short us4 __attribute__((ext_vector_type(4)));

__device__ __forceinline__ unsigned short f2bf(float f) {
    unsigned int u = __float_as_uint(f);
    u += 0x7fff + ((u >> 16) & 1);
    return (unsigned short)(u >> 16);
}
__device__ __forceinline__ float bf2f(unsigned short h) {
    return __uint_as_float(((unsigned int)h) << 16);
}

// ---------------------------------------------------------------------------
// weight transform: w fp32 [OC][C0+C1][9] -> wT bf16 [9][OCpad][Ktot]
// ---------------------------------------------------------------------------
__global__ __launch_bounds__(256) void k_wt(const float* __restrict__ w,
                                            unsigned short* __restrict__ dh,
                                            unsigned short* __restrict__ dl,
                                            int OC, int OCpad, int C0, int K0pad,
                                            int C1, int Ktot) {
    int idx = blockIdx.x * 256 + threadIdx.x;
    int n = 9 * OCpad * Ktot;
    if (idx >= n) return;
    int k = idx % Ktot;
    int rest = idx / Ktot;
    int oc = rest % OCpad;
    float v = 0.f;
    if (oc < OC) {
        int ic = -1;
        if (k < C0) ic = k;
        else if (k >= K0pad && (k - K0pad) < C1) ic = C0 + (k - K0pad);
        if (ic >= 0) {
            int tap = rest / OCpad;
            v = w[((size_t)oc * (C0 + C1) + ic) * 9 + tap];
        }
    }
    unsigned short hi = f2bf(v);
    dh[idx] = hi;
    if (dl) dl[idx] = f2bf(v - bf2f(hi));
}

// ---------------------------------------------------------------------------
// build NHWC-padded bf16 x (hi+lo) and ipad channels 0..255
// ---------------------------------------------------------------------------
__global__ __launch_bounds__(256) void k_build_x(const float* __restrict__ x,
                                                 unsigned short* __restrict__ xh,
                                                 unsigned short* __restrict__ xl,
                                                 unsigned short* __restrict__ ipad) {
    int b = blockIdx.z, c0 = blockIdx.y * 64, p0 = blockIdx.x * 64;
    __shared__ float s[64][65];
    int t = threadIdx.x;
    for (int i = t; i < 4096; i += 256) {
        int c = i >> 6, p = i & 63;
        s[p][c] = x[((size_t)b * 256 + c0 + c) * HW + p0 + p];
    }
    __syncthreads();
    for (int i = t; i < 4096; i += 256) {
        int c = i & 63, p = i >> 6;
        float f = s[p][c];
        unsigned short hi = f2bf(f);
        unsigned short lo = f2bf(f - bf2f(hi));
        int pp = p0 + p;
        int y = pp >> 6, xx = pp & 63;
        size_t pix = (size_t)((y + 1) * 66 + xx + 1);
        xh[(size_t)b * (PIX66 * 256) + pix * 256 + c0 + c] = hi;
        xl[(size_t)b * (PIX66 * 256) + pix * 256 + c0 + c] = lo;
        ipad[(size_t)b * (PIX66 * 320) + pix * 320 + c0 + c] = hi;
    }
}

__global__ __launch_bounds__(256) void k_build_mask(const float* __restrict__ m,
                                                    unsigned short* __restrict__ dh,
                                                    unsigned short* __restrict__ dl) {
    int idx = blockIdx.x * 256 + threadIdx.x;   // 2*4096*32
    int c = idx & 31;
    int p = (idx >> 5) & 4095;
    int b = idx >> 17;
    float f = (c < 19) ? m[((size_t)b * 19 + c) * HW + p] : 0.f;
    unsigned short hi = f2bf(f);
    int y = p >> 6, xx = p & 63;
    size_t pix = (size_t)((y + 1) * 66 + xx + 1);
    dh[(size_t)b * (PIX66 * 32) + pix * 32 + c] = hi;
    dl[(size_t)b * (PIX66 * 32) + pix * 32 + c] = f2bf(f - bf2f(hi));
}

// ---------------------------------------------------------------------------
// MFMA implicit-GEMM conv (unchanged from round 2)
// ---------------------------------------------------------------------------
template <int WPP, int WPO, int MODE, int SPLIT>
__global__ __launch_bounds__(256) void conv_mfma(
    const unsigned short* __restrict__ s0h, const unsigned short* __restrict__ s0l, int C0,
    const unsigned short* __restrict__ s1h, const unsigned short* __restrict__ s1l, int C1,
    const unsigned short* __restrict__ wth, const unsigned short* __restrict__ wtl, int OCpad,
    const float* __restrict__ bias,
    float* __restrict__ dstf, size_t batF,
    unsigned short* __restrict__ dstb, unsigned short* __restrict__ dstb2, size_t batB,
    int strideC, int chBase,
    const float* __restrict__ mask, int OCreal,
    float* __restrict__ ybuf) {
    int b = blockIdx.z;
    int t = threadIdx.x, w = t >> 6, l = t & 63, quad = l >> 4, ln = l & 15;
    int wP = w % WPP, wO = w / WPP;
    int pBase = blockIdx.x * (WPP * 32) + wP * 32;
    int ocBase = blockIdx.y * (WPO * 32) + wO * 32;
    int Ktot = C0 + C1;

    long nb0[2], nb1[2];
#pragma unroll
    for (int tn = 0; tn < 2; ++tn) {
        int p = pBase + tn * 16 + ln;
        int y = p >> 6, x = p & 63;
        nb0[tn] = (long)((y + 1) * 66 + (x + 1)) * C0 + quad * 8;
        nb1[tn] = C1 ? (long)((y + 1) * 66 + (x + 1)) * C1 + quad * 8 : 0;
    }
    size_t aoff[2];
#pragma unroll
    for (int tm = 0; tm < 2; ++tm)
        aoff[tm] = (size_t)(ocBase + tm * 16 + ln) * Ktot + quad * 8;

    f32x4 acc[2][2];
#pragma unroll
    for (int i = 0; i < 2; ++i)
#pragma unroll
        for (int j = 0; j < 2; ++j) acc[i][j] = (f32x4){0.f, 0.f, 0.f, 0.f};

    const int npass = SPLIT ? 3 : 1;
    for (int ps = 0; ps < npass; ++ps) {
        const unsigned short* S0 =
            ((SPLIT && ps == 2) ? s0l : s0h) + (size_t)b * PIX66 * C0;
        const unsigned short* S1 =
            C1 ? (((SPLIT && ps == 2) ? s1l : s1h) + (size_t)b * PIX66 * C1) : (const unsigned short*)0;
        const unsigned short* WT = (SPLIT && ps == 1) ? wtl : wth;
        for (int tap = 0; tap < 9; ++tap) {
            int dy = tap / 3 - 1, dx = tap % 3 - 1;
            long o0 = (long)(dy * 66 + dx) * C0;
            long o1 = (long)(dy * 66 + dx) * C1;
            const unsigned short* WTt = WT + (size_t)tap * OCpad * Ktot;
            for (int kb = 0; kb < Ktot; kb += 32) {
                short8 bfr[2], afr[2];
                if (kb < C0) {
#pragma unroll
                    for (int tn = 0; tn < 2; ++tn)
                        bfr[tn] = *(const short8*)(S0 + nb0[tn] + o0 + kb);
                } else {
#pragma unroll
                    for (int tn = 0; tn < 2; ++tn)
                        bfr[tn] = *(const short8*)(S1 + nb1[tn] + o1 + (kb - C0));
                }
#pragma unroll
                for (int tm = 0; tm < 2; ++tm)
                    afr[tm] = *(const short8*)(WTt + aoff[tm] + kb);
#pragma unroll
                for (int tm = 0; tm < 2; ++tm)
#pragma unroll
                    for (int tn = 0; tn < 2; ++tn)
                        acc[tm][tn] = __builtin_amdgcn_mfma_f32_16x16x32_bf16(
                            afr[tm], bfr[tn], acc[tm][tn], 0, 0, 0);
            }
        }
    }

#pragma unroll
    for (int tm = 0; tm < 2; ++tm) {
#pragma unroll
        for (int r = 0; r < 4; ++r) {
            int oc = ocBase + tm * 16 + quad * 4 + r;
            float bi;
            if (MODE == 1) bi = (oc < OCreal) ? bias[oc] : 0.f;
            else bi = bias[oc];
            float msum = 0.f;
#pragma unroll
            for (int tn = 0; tn < 2; ++tn) {
                int p = pBase + tn * 16 + ln;
                float v = acc[tm][tn][r] + bi;
                if (MODE == 0) {
                    dstf[(size_t)b * batF + (size_t)oc * HW + p] = v;
                } else if (MODE == 1) {
                    if (oc < OCreal) {
                        v *= mask[((size_t)b * OCreal + oc) * HW + p];
                        int y = p >> 6, x = p & 63;
                        dstb[(size_t)b * batB + (size_t)((y + 1) * 66 + x + 1) * strideC +
                             chBase + oc] = f2bf(v);
                    }
                } else if (MODE == 2) {
                    unsigned short hi = f2bf(v);
                    dstb[(size_t)b * batB + (size_t)p * 32 + oc] = hi;
                    dstb2[(size_t)b * batB + (size_t)p * 32 + oc] = f2bf(v - bf2f(hi));
                } else if (MODE == 3) {
                    dstb[(size_t)b * batB + (size_t)oc * HW + p] = f2bf(v);
                } else {  // MODE 4
                    int y = p >> 6, x = p & 63;
                    dstb[(size_t)b * batB + (size_t)((y + 1) * 66 + x + 1) * strideC +
                         chBase + oc] = f2bf(v);
                    msum += v;
                }
            }
            if (MODE == 4) {
#pragma unroll
                for (int off = 8; off; off >>= 1) msum += __shfl_down(msum, off, 16);
                if (ln == 0) atomicAdd(&ybuf[b * 256 + oc], msum);
            }
        }
    }
}

// ---------------------------------------------------------------------------
// Flash attention (both softmax orientations).
//   mode 0 (out_b): Q=q, K=k.  mode 1 (out_c): Q=k, K=q.
// Block: 64 queries (p), all 256 channels. 4 waves = 2 p-groups x 2 c-halves.
// Per 64-key tile: S^T = K·Q^T via 3-term split-bf16 MFMA (C-layout col = p),
// online softmax (2 shfl_xor), P->LDS bf16, V tile staged in LDS, PV MFMA.
// Writes channels 256+mode*256.. of catN (bf16 NHWC padded).
// ---------------------------------------------------------------------------
__global__ __launch_bounds__(256) void flash_attn(
    const unsigned short* __restrict__ qt_h, const unsigned short* __restrict__ qt_l,
    const unsigned short* __restrict__ kt_h, const unsigned short* __restrict__ kt_l,
    const unsigned short* __restrict__ vbf,
    unsigned short* __restrict__ catN) {
    int mode = blockIdx.y, b = blockIdx.z;
    size_t qkoff = (size_t)b * HW * 32;
    const unsigned short* Qh = (mode ? kt_h : qt_h) + qkoff;
    const unsigned short* Ql = (mode ? kt_l : qt_l) + qkoff;
    const unsigned short* Kh = (mode ? qt_h : kt_h) + qkoff;
    const unsigned short* Kl = (mode ? qt_l : kt_l) + qkoff;
    const unsigned short* V = vbf + (size_t)b * 256 * HW;
    unsigned short* out = catN + (size_t)b * PIX66 * 768;

    int t = threadIdx.x, w = t >> 6, l = t & 63, quad = l >> 4, ln = l & 15;
    int pg = w >> 1, ch = w & 1;
    int p0 = blockIdx.x * 64, pw = pg * 32;
    int cb = ch * 128;

    __shared__ unsigned short sV[256 * 72];   // V tile [c][72]
    __shared__ unsigned short sP[64 * 72];    // P tile [p][72]

    // Q fragments (fixed over the key loop): rows p, k = quad*8..+7
    short8 qbh[2], qbl[2];
#pragma unroll
    for (int pn = 0; pn < 2; ++pn) {
        size_t off = (size_t)(p0 + pw + pn * 16 + ln) * 32 + quad * 8;
        qbh[pn] = *(const short8*)(Qh + off);
        qbl[pn] = *(const short8*)(Ql + off);
    }

    float m_run[2] = {-3.0e38f, -3.0e38f};
    float l_run[2] = {0.f, 0.f};
    f32x4 accO[8][2];
#pragma unroll
    for (int cs = 0; cs < 8; ++cs)
#pragma unroll
        for (int pn = 0; pn < 2; ++pn) accO[cs][pn] = (f32x4){0.f, 0.f, 0.f, 0.f};

    for (int jb = 0; jb < HW; jb += 64) {
        // V tile -> regs (coalesced), K fragments -> regs
        short8 vreg[8];
#pragma unroll
        for (int i = 0; i < 8; ++i) {
            int idx = t + 256 * i;            // 2048 chunks of 8 bf16
            int c = idx >> 3, ck = idx & 7;
            vreg[i] = *(const short8*)(V + (size_t)c * HW + jb + ck * 8);
        }
        short8 kah[4], kal[4];
#pragma unroll
        for (int jj = 0; jj < 4; ++jj) {
            size_t off = (size_t)(jb + 16 * jj + ln) * 32 + quad * 8;
            kah[jj] = *(const short8*)(Kh + off);
            kal[jj] = *(const short8*)(Kl + off);
        }
        __syncthreads();   // previous iteration's LDS reads complete
#pragma unroll
        for (int i = 0; i < 8; ++i) {
            int idx = t + 256 * i;
            int c = idx >> 3, ck = idx & 7;
            *(short8*)(sV + (size_t)c * 72 + ck * 8) = vreg[i];
        }

        // S^T[j][p]: rows j (quad*4+r, 4 subtiles), cols p (ln)
        f32x4 sacc[2][4];
#pragma unroll
        for (int pn = 0; pn < 2; ++pn)
#pragma unroll
            for (int jj = 0; jj < 4; ++jj) sacc[pn][jj] = (f32x4){0.f, 0.f, 0.f, 0.f};
#pragma unroll
        for (int pn = 0; pn < 2; ++pn)
#pragma unroll
            for (int jj = 0; jj < 4; ++jj) {
                sacc[pn][jj] = __builtin_amdgcn_mfma_f32_16x16x32_bf16(
                    kah[jj], qbh[pn], sacc[pn][jj], 0, 0, 0);
                sacc[pn][jj] = __builtin_amdgcn_mfma_f32_16x16x32_bf16(
                    kah[jj], qbl[pn], sacc[pn][jj], 0, 0, 0);
                sacc[pn][jj] = __builtin_amdgcn_mfma_f32_16x16x32_bf16(
                    kal[jj], qbh[pn], sacc[pn][jj], 0, 0, 0);
            }

        // online softmax per query column p = ln (per pn subtile)
#pragma unroll
        for (int pn = 0; pn < 2; ++pn) {
            float tm = -3.0e38f;
#pragma unroll
            for (int jj = 0; jj < 4; ++jj)
#pragma unroll
                for (int r = 0; r < 4; ++r) tm = fmaxf(tm, sacc[pn][jj][r]);
            tm = fmaxf(tm, __shfl_xor(tm, 16));
            tm = fmaxf(tm, __shfl_xor(tm, 32));
            float mnew = fmaxf(m_run[pn], tm);
            float alpha = __expf(m_run[pn] - mnew);
            m_run[pn] = mnew;
            float ps = 0.f;
#pragma unroll
            for (int jj = 0; jj < 4; ++jj) {
                us4 pk;
#pragma unroll
                for (int r = 0; r < 4; ++r) {
                    float e = __expf(sacc[pn][jj][r] - mnew);
                    ps += e;
                    pk[r] = f2bf(e);
                }
                *(us4*)(sP + (size_t)(pw + pn * 16 + ln) * 72 + jj * 16 + quad * 4) = pk;
            }
            ps += __shfl_xor(ps, 16);
            ps += __shfl_xor(ps, 32);
            l_run[pn] = l_run[pn] * alpha + ps;
#pragma unroll
            for (int cs = 0; cs < 8; ++cs) accO[cs][pn] *= alpha;
        }
        __syncthreads();   // sV (and sP) ready

        // PV: A = V rows c, B = P rows p
        short8 pb[2][2];
#pragma unroll
        for (int pn = 0; pn < 2; ++pn)
#pragma unroll
            for (int j2 = 0; j2 < 2; ++j2)
                pb[pn][j2] = *(const short8*)(sP + (size_t)(pw + pn * 16 + ln) * 72 +
                                              j2 * 32 + quad * 8);
#pragma unroll
        for (int cs = 0; cs < 8; ++cs) {
            const unsigned short* vrow = sV + (size_t)(cb + cs * 16 + ln) * 72 + quad * 8;
            short8 va0 = *(const short8*)(vrow);
            short8 va1 = *(const short8*)(vrow + 32);
#pragma unroll
            for (int pn = 0; pn < 2; ++pn) {
                accO[cs][pn] = __builtin_amdgcn_mfma_f32_16x16x32_bf16(
                    va0, pb[pn][0], accO[cs][pn], 0, 0, 0);
                accO[cs][pn] = __builtin_amdgcn_mfma_f32_16x16x32_bf16(
                    va1, pb[pn][1], accO[cs][pn], 0, 0, 0);
            }
        }
    }

    // epilogue: O / l -> catN channels 256 + mode*256 + c
#pragma unroll
    for (int pn = 0; pn < 2; ++pn) {
        float inv = 1.f / l_run[pn];
        int p = p0 + pw + pn * 16 + ln;
        int y = p >> 6, x = p & 63;
        size_t pix = (size_t)((y + 1) * 66 + x + 1);
#pragma unroll
        for (int cs = 0; cs < 8; ++cs)
#pragma unroll
            for (int r = 0; r < 4; ++r) {
                int c = cb + cs * 16 + quad * 4 + r;
                out[pix * 768 + 256 + mode * 256 + c] = f2bf(accO[cs][pn][r] * inv);
            }
    }
}

// ---------------------------------------------------------------------------
// SE mlp + in-place scale of catN ch 0..255
// ---------------------------------------------------------------------------
__global__ __launch_bounds__(256) void se_mlp_kernel(const float* __restrict__ y,
                                                     const float* __restrict__ w1,
                                                     const float* __restrict__ w2,
                                                     float* __restrict__ sc) {
    int b = blockIdx.x, t = threadIdx.x;
    __shared__ float sy[256], sh[32];
    sy[t] = y[b * 256 + t] * (1.f / 4096.f);
    __syncthreads();
    if (t < 32) {
        float s = 0.f;
        for (int c = 0; c < 256; ++c) s = fmaf(w1[t * 256 + c], sy[c], s);
        sh[t] = fmaxf(s, 0.f);
    }
    __syncthreads();
    float s = 0.f;
#pragma unroll
    for (int h = 0; h < 32; ++h) s = fmaf(w2[t * 32 + h], sh[h], s);
    sc[b * 256 + t] = 1.f / (1.f + __expf(-s));
}

__global__ __launch_bounds__(256) void se_scale_cat(unsigned short* __restrict__ catN,
                                                    const float* __restrict__ sc) {
    int idx = blockIdx.x * 256 + threadIdx.x;   // 2*4096*256
    int c = idx & 255;
    int p = (idx >> 8) & 4095;
    int b = idx >> 20;
    int y = p >> 6, x = p & 63;
    size_t pix = (size_t)((y + 1) * 66 + x + 1);
    unsigned short* q = catN + (size_t)b * (PIX66 * 768) + pix * 768 + c;
    *q = f2bf(bf2f(*q) * sc[b * 256 + c]);
}

// ---------------------------------------------------------------------------
extern "C" void kernel_launch(void* const* d_in, const int* in_sizes, int n_in,
                              void* d_out, int out_size, void* d_ws, size_t ws_size,
                              hipStream_t stream) {
    const float* x      = (const float*)d_in[0];
    const float* mmask  = (const float*)d_in[1];
    const float* amask  = (const float*)d_in[2];
    const float* w_mp   = (const float*)d_in[3];
    const float* b_mp   = (const float*)d_in[4];
    const float* w_ap   = (const float*)d_in[5];
    const float* b_ap   = (const float*)d_in[6];
    const float* w_q    = (const float*)d_in[7];
    const float* b_q    = (const float*)d_in[8];
    const float* w_k    = (const float*)d_in[9];
    const float* b_k    = (const float*)d_in[10];
    const float* w_v    = (const float*)d_in[11];
    const float* b_v    = (const float*)d_in[12];
    const float* w_comp = (const float*)d_in[13];
    const float* b_comp = (const float*)d_in[14];
    const float* w_out  = (const float*)d_in[15];
    const float* b_out  = (const float*)d_in[16];
    const float* w_se1  = (const float*)d_in[17];
    const float* w_se2  = (const float*)d_in[18];

    unsigned short* us = (unsigned short*)d_ws;
    size_t o = 0;
    // ---- zeroed bf16 region ----
    unsigned short* xpad_hi = us + o; o += (size_t)2 * PIX66 * 256;
    unsigned short* xpad_lo = us + o; o += (size_t)2 * PIX66 * 256;
    unsigned short* mq_hi   = us + o; o += (size_t)2 * PIX66 * 32;
    unsigned short* mq_lo   = us + o; o += (size_t)2 * PIX66 * 32;
    unsigned short* ma_hi   = us + o; o += (size_t)2 * PIX66 * 32;
    unsigned short* ma_lo   = us + o; o += (size_t)2 * PIX66 * 32;
    unsigned short* ipad    = us + o; o += (size_t)2 * PIX66 * 320;
    unsigned short* catN    = us + o; o += (size_t)2 * PIX66 * 768;
    size_t zeroBytes = o * sizeof(unsigned short);
    // ---- fully-written bf16 region ----
    unsigned short* wt_mp = us + o; o += (size_t)9 * 32 * 256;
    unsigned short* wt_ap = us + o; o += (size_t)9 * 32 * 256;
    unsigned short* wt_qh = us + o; o += (size_t)9 * 32 * 288;
    unsigned short* wt_ql = us + o; o += (size_t)9 * 32 * 288;
    unsigned short* wt_kh = us + o; o += (size_t)9 * 32 * 288;
    unsigned short* wt_kl = us + o; o += (size_t)9 * 32 * 288;
    unsigned short* wt_v  = us + o; o += (size_t)9 * 256 * 256;
    unsigned short* wt_cp = us + o; o += (size_t)9 * 256 * 320;
    unsigned short* wt_ot = us + o; o += (size_t)9 * 256 * 768;
    unsigned short* qt_h  = us + o; o += (size_t)2 * HW * 32;
    unsigned short* qt_l  = us + o; o += (size_t)2 * HW * 32;
    unsigned short* kt_h  = us + o; o += (size_t)2 * HW * 32;
    unsigned short* kt_l  = us + o; o += (size_t)2 * HW * 32;
    unsigned short* vbf   = us + o; o += (size_t)2 * 256 * HW;
    // ---- fp32 region ----
    float* fp = (float*)(us + o);
    size_t fo = 0;
    float* ybuf = fp + fo; fo += 512;
    float* sbuf = fp + fo; fo += 512;
    size_t need = o * sizeof(unsigned short) + fo * sizeof(float);
    if (ws_size < need) return;

    float* outp = (float*)d_out;

    hipMemsetAsync(us, 0, zeroBytes, stream);
    hipMemsetAsync(ybuf, 0, 512 * sizeof(float), stream);

    auto wtlaunch = [&](const float* w, unsigned short* dh, unsigned short* dl, int OC,
                        int OCpad, int C0, int K0pad, int C1, int Ktot) {
        int n = 9 * OCpad * Ktot;
        k_wt<<<(n + 255) / 256, 256, 0, stream>>>(w, dh, dl, OC, OCpad, C0, K0pad, C1, Ktot);
    };
    wtlaunch(w_mp, wt_mp, (unsigned short*)0, 19, 32, 256, 256, 0, 256);
    wtlaunch(w_ap, wt_ap, (unsigned short*)0, 19, 32, 256, 256, 0, 256);
    wtlaunch(w_q,  wt_qh, wt_ql, 32, 32, 256, 256, 19, 288);
    wtlaunch(w_k,  wt_kh, wt_kl, 32, 32, 256, 256, 19, 288);
    wtlaunch(w_v,  wt_v,  (unsigned short*)0, 256, 256, 256, 256, 0, 256);
    wtlaunch(w_comp, wt_cp, (unsigned short*)0, 256, 256, 294, 320, 0, 320);
    wtlaunch(w_out,  wt_ot, (unsigned short*)0, 256, 256, 768, 768, 0, 768);

    k_build_x<<<dim3(64, 4, 2), 256, 0, stream>>>(x, xpad_hi, xpad_lo, ipad);
    k_build_mask<<<1024, 256, 0, stream>>>(mmask, mq_hi, mq_lo);
    k_build_mask<<<1024, 256, 0, stream>>>(amask, ma_hi, ma_lo);

    const unsigned short* NUS = (const unsigned short*)0;
    float* NF = (float*)0;
    unsigned short* NUSo = (unsigned short*)0;

    // mp/ap convs -> ipad ch 256 / 275 (mask-multiplied)
    conv_mfma<4, 1, 1, 0><<<dim3(32, 1, 2), 256, 0, stream>>>(
        xpad_hi, NUS, 256, NUS, NUS, 0, wt_mp, NUS, 32, b_mp,
        NF, 0, ipad, NUSo, (size_t)PIX66 * 320, 320, 256, mmask, 19, NF);
    conv_mfma<4, 1, 1, 0><<<dim3(32, 1, 2), 256, 0, stream>>>(
        xpad_hi, NUS, 256, NUS, NUS, 0, wt_ap, NUS, 32, b_ap,
        NF, 0, ipad, NUSo, (size_t)PIX66 * 320, 320, 275, amask, 19, NF);
    // q/k convs (split precision) -> qt/kt hi+lo  [p][32]
    conv_mfma<4, 1, 2, 1><<<dim3(32, 1, 2), 256, 0, stream>>>(
        xpad_hi, xpad_lo, 256, mq_hi, mq_lo, 32, wt_qh, wt_ql, 32, b_q,
        NF, 0, qt_h, qt_l, (size_t)HW * 32, 0, 0, NF, 32, NF);
    conv_mfma<4, 1, 2, 1><<<dim3(32, 1, 2), 256, 0, stream>>>(
        xpad_hi, xpad_lo, 256, ma_hi, ma_lo, 32, wt_kh, wt_kl, 32, b_k,
        NF, 0, kt_h, kt_l, (size_t)HW * 32, 0, 0, NF, 32, NF);
    // v conv -> vbf [c][4096]
    conv_mfma<2, 2, 3, 0><<<dim3(64, 4, 2), 256, 0, stream>>>(
        xpad_hi, NUS, 256, NUS, NUS, 0, wt_v, NUS, 256, b_v,
        NF, 0, vbf, NUSo, (size_t)256 * HW, 0, 0, NF, 256, NF);
    // comp conv -> catN ch 0..255 + channel sums
    conv_mfma<2, 2, 4, 0><<<dim3(64, 4, 2), 256, 0, stream>>>(
        ipad, NUS, 320, NUS, NUS, 0, wt_cp, NUS, 256, b_comp,
        NF, 0, catN, NUSo, (size_t)PIX66 * 768, 768, 0, NF, 256, ybuf);
    // SE
    se_mlp_kernel<<<2, 256, 0, stream>>>(ybuf, w_se1, w_se2, sbuf);
    se_scale_cat<<<8192, 256, 0, stream>>>(catN, sbuf);
    // flash attention: both modes, both batches, one dispatch
    flash_attn<<<dim3(64, 2, 2), 256, 0, stream>>>(qt_h, qt_l, kt_h, kt_l, vbf, catN);
    // final conv -> d_out (fp32 NCHW)
    conv_mfma<2, 2, 0, 0><<<dim3(64, 4, 2), 256, 0, stream>>>(
        catN, NUS, 768, NUS, NUS, 0, wt_ot, NUS, 256, b_out,
        outp, (size_t)256 * HW, NUSo, NUSo, 0, 0, 0, NF, 256, NF);
}

// Round 4
// 776.698 us; speedup vs baseline: 7.5112x; 1.1739x over previous
//
#include <hip/hip_runtime.h>
#include <math.h>

#define HW 4096
#define IMG 64
#define PIX66 (66 * 66)

typedef short short8 __attribute__((ext_vector_type(8)));
typedef float f32x4 __attribute__((ext_vector_type(4)));
typedef unsigned short us4 __attribute__((ext_vector_type(4)));

__device__ __forceinline__ unsigned short f2bf(float f) {
    unsigned int u = __float_as_uint(f);
    u += 0x7fff + ((u >> 16) & 1);
    return (unsigned short)(u >> 16);
}
__device__ __forceinline__ float bf2f(unsigned short h) {
    return __uint_as_float(((unsigned int)h) << 16);
}

// ---------------------------------------------------------------------------
// fused weight transforms: w fp32 [OC][C0+C1][9] -> wT bf16 [9][OCpad][Ktot]
// ---------------------------------------------------------------------------
struct WtJob {
    const float* w;
    unsigned short* dh;
    unsigned short* dl;
    int OC, OCpad, C0, K0pad, C1, Ktot;
};

__global__ __launch_bounds__(256) void k_wt_all(WtJob J0, WtJob J1, WtJob J2,
                                                WtJob J3, WtJob J4, WtJob J5,
                                                WtJob J6) {
    WtJob J;
    switch (blockIdx.y) {
        case 0: J = J0; break;
        case 1: J = J1; break;
        case 2: J = J2; break;
        case 3: J = J3; break;
        case 4: J = J4; break;
        case 5: J = J5; break;
        default: J = J6; break;
    }
    int idx = blockIdx.x * 256 + threadIdx.x;
    int n = 9 * J.OCpad * J.Ktot;
    if (idx >= n) return;
    int k = idx % J.Ktot;
    int rest = idx / J.Ktot;
    int oc = rest % J.OCpad;
    float v = 0.f;
    if (oc < J.OC) {
        int ic = -1;
        if (k < J.C0) ic = k;
        else if (k >= J.K0pad && (k - J.K0pad) < J.C1) ic = J.C0 + (k - J.K0pad);
        if (ic >= 0) {
            int tap = rest / J.OCpad;
            v = J.w[((size_t)oc * (J.C0 + J.C1) + ic) * 9 + tap];
        }
    }
    unsigned short hi = f2bf(v);
    J.dh[idx] = hi;
    if (J.dl) J.dl[idx] = f2bf(v - bf2f(hi));
}

// ---------------------------------------------------------------------------
// build NHWC-padded bf16 x (hi+lo) and ipad channels 0..255
// ---------------------------------------------------------------------------
__global__ __launch_bounds__(256) void k_build_x(const float* __restrict__ x,
                                                 unsigned short* __restrict__ xh,
                                                 unsigned short* __restrict__ xl,
                                                 unsigned short* __restrict__ ipad) {
    int b = blockIdx.z, c0 = blockIdx.y * 64, p0 = blockIdx.x * 64;
    __shared__ float s[64][65];
    int t = threadIdx.x;
    for (int i = t; i < 4096; i += 256) {
        int c = i >> 6, p = i & 63;
        s[p][c] = x[((size_t)b * 256 + c0 + c) * HW + p0 + p];
    }
    __syncthreads();
    for (int i = t; i < 4096; i += 256) {
        int c = i & 63, p = i >> 6;
        float f = s[p][c];
        unsigned short hi = f2bf(f);
        unsigned short lo = f2bf(f - bf2f(hi));
        int pp = p0 + p;
        int y = pp >> 6, xx = pp & 63;
        size_t pix = (size_t)((y + 1) * 66 + xx + 1);
        xh[(size_t)b * (PIX66 * 256) + pix * 256 + c0 + c] = hi;
        xl[(size_t)b * (PIX66 * 256) + pix * 256 + c0 + c] = lo;
        ipad[(size_t)b * (PIX66 * 320) + pix * 320 + c0 + c] = hi;
    }
}

// both masks -> NHWC bf16 hi/lo, 32-channel padded (job = blockIdx.y)
__global__ __launch_bounds__(256) void k_build_mask2(
    const float* __restrict__ m0, const float* __restrict__ m1,
    unsigned short* __restrict__ d0h, unsigned short* __restrict__ d0l,
    unsigned short* __restrict__ d1h, unsigned short* __restrict__ d1l) {
    const float* m = blockIdx.y ? m1 : m0;
    unsigned short* dh = blockIdx.y ? d1h : d0h;
    unsigned short* dl = blockIdx.y ? d1l : d0l;
    int idx = blockIdx.x * 256 + threadIdx.x;   // 2*4096*32
    int c = idx & 31;
    int p = (idx >> 5) & 4095;
    int b = idx >> 17;
    float f = (c < 19) ? m[((size_t)b * 19 + c) * HW + p] : 0.f;
    unsigned short hi = f2bf(f);
    int y = p >> 6, xx = p & 63;
    size_t pix = (size_t)((y + 1) * 66 + xx + 1);
    dh[(size_t)b * (PIX66 * 32) + pix * 32 + c] = hi;
    dl[(size_t)b * (PIX66 * 32) + pix * 32 + c] = f2bf(f - bf2f(hi));
}

// ---------------------------------------------------------------------------
// MFMA implicit-GEMM conv, 4-deep register-pipelined K-loop.
// Wave tile 32px x 32oc. Block: WPP waves (pixels) x WPO waves (oc).
// MODE 0: fp32 NCHW + bias        (out conv -> d_out)
// MODE 1: (acc+bias)*mask -> bf16 NHWC at chBase (mp/ap -> ipad)
// MODE 2: split bf16 pixel-major [p][32] hi+lo   (q/k)
// MODE 3: bf16 CHW [oc][4096]                    (v)
// MODE 4: bf16 NHWC + atomic channel-sum accum   (comp -> catN + ybuf)
// NPASS 3 = split precision (hi*Whi, hi*Wlo, lo*Whi). FUSE2: blockIdx.y=job.
// ---------------------------------------------------------------------------
struct ConvJob {
    const unsigned short* s1h;
    const unsigned short* s1l;
    const unsigned short* wth;
    const unsigned short* wtl;
    const float* bias;
    float* dstf;
    unsigned short* d1;
    unsigned short* d2;
    const float* mask;
    int chBase;
};

template <int WPP, int WPO, int MODE, int NPASS, int KS32, int FUSE2>
__global__ __launch_bounds__(WPP * WPO * 64, 2) void conv_mfma(
    const unsigned short* __restrict__ s0h, const unsigned short* __restrict__ s0l,
    int C0, int C1, int OCpad, size_t batF, size_t batB, int strideC, int OCreal,
    float* __restrict__ ybuf, ConvJob j0, ConvJob j1) {
    constexpr int Ktot = KS32 * 32;
    constexpr int ST = NPASS * 9 * KS32;
    int b = blockIdx.z;
    ConvJob J = (FUSE2 && blockIdx.y == 1) ? j1 : j0;
    int t = threadIdx.x, w = t >> 6, l = t & 63, quad = l >> 4, ln = l & 15;
    int wP = w % WPP, wO = w / WPP;
    int pBase = blockIdx.x * (WPP * 32) + wP * 32;
    int ocBase = (FUSE2 ? 0 : blockIdx.y * (WPO * 32)) + wO * 32;

    const unsigned short* S0h = s0h + (size_t)b * PIX66 * C0;
    const unsigned short* S0l = (NPASS == 3) ? (s0l + (size_t)b * PIX66 * C0)
                                             : (const unsigned short*)0;
    const unsigned short* S1h = C1 ? (J.s1h + (size_t)b * PIX66 * C1)
                                   : (const unsigned short*)0;
    const unsigned short* S1l = (C1 && NPASS == 3) ? (J.s1l + (size_t)b * PIX66 * C1)
                                                   : (const unsigned short*)0;

    long nb0[2], nb1[2];
#pragma unroll
    for (int tn = 0; tn < 2; ++tn) {
        int p = pBase + tn * 16 + ln;
        int y = p >> 6, x = p & 63;
        nb0[tn] = (long)((y + 1) * 66 + (x + 1)) * C0 + quad * 8;
        nb1[tn] = C1 ? (long)((y + 1) * 66 + (x + 1)) * C1 + quad * 8 : 0;
    }
    size_t aoff[2];
#pragma unroll
    for (int tm = 0; tm < 2; ++tm)
        aoff[tm] = (size_t)(ocBase + tm * 16 + ln) * Ktot + quad * 8;

    f32x4 acc[2][2];
#pragma unroll
    for (int i = 0; i < 2; ++i)
#pragma unroll
        for (int j = 0; j < 2; ++j) acc[i][j] = (f32x4){0.f, 0.f, 0.f, 0.f};

    // ---- pipelined K-loop ----
    int ps = 0, tap = 0, kb = 0;   // coords of the NEXT step to load
    auto adv = [&]() {
        kb += 32;
        if (kb == Ktot) { kb = 0; if (++tap == 9) { tap = 0; ++ps; } }
    };
    auto loadStep = [&](int lps, int ltap, int lkb, short8* bf, short8* af) {
        int d3 = ltap / 3;
        int doff = (d3 - 1) * 66 + (ltap - d3 * 3 - 1);
        if (lkb < C0) {
            const unsigned short* Sp = (NPASS == 3 && lps == 2) ? S0l : S0h;
            long o = (long)doff * C0 + lkb;
            bf[0] = *(const short8*)(Sp + nb0[0] + o);
            bf[1] = *(const short8*)(Sp + nb0[1] + o);
        } else {
            const unsigned short* Sp = (NPASS == 3 && lps == 2) ? S1l : S1h;
            long o = (long)doff * C1 + (lkb - C0);
            bf[0] = *(const short8*)(Sp + nb1[0] + o);
            bf[1] = *(const short8*)(Sp + nb1[1] + o);
        }
        const unsigned short* WT = ((NPASS == 3 && lps == 1) ? J.wtl : J.wth) +
                                   ((size_t)ltap * OCpad) * Ktot + lkb;
        af[0] = *(const short8*)(WT + aoff[0]);
        af[1] = *(const short8*)(WT + aoff[1]);
    };

    short8 bfr[4][2], afr[4][2];
#pragma unroll
    for (int u = 0; u < 4; ++u) { loadStep(ps, tap, kb, bfr[u], afr[u]); adv(); }

    for (int s = 0; s < ST; s += 4) {
#pragma unroll
        for (int u = 0; u < 4; ++u) {
            if (s + u < ST) {
#pragma unroll
                for (int tm = 0; tm < 2; ++tm)
#pragma unroll
                    for (int tn = 0; tn < 2; ++tn)
                        acc[tm][tn] = __builtin_amdgcn_mfma_f32_16x16x32_bf16(
                            afr[u][tm], bfr[u][tn], acc[tm][tn], 0, 0, 0);
                if (s + u + 4 < ST) { loadStep(ps, tap, kb, bfr[u], afr[u]); adv(); }
            }
        }
    }

    // ---- epilogue ----
#pragma unroll
    for (int tm = 0; tm < 2; ++tm) {
#pragma unroll
        for (int r = 0; r < 4; ++r) {
            int oc = ocBase + tm * 16 + quad * 4 + r;
            float bi = (MODE == 1) ? ((oc < OCreal) ? J.bias[oc] : 0.f) : J.bias[oc];
            float msum = 0.f;
#pragma unroll
            for (int tn = 0; tn < 2; ++tn) {
                int p = pBase + tn * 16 + ln;
                float v = acc[tm][tn][r] + bi;
                if (MODE == 0) {
                    J.dstf[(size_t)b * batF + (size_t)oc * HW + p] = v;
                } else if (MODE == 1) {
                    if (oc < OCreal) {
                        v *= J.mask[((size_t)b * OCreal + oc) * HW + p];
                        int y = p >> 6, x = p & 63;
                        J.d1[(size_t)b * batB + (size_t)((y + 1) * 66 + x + 1) * strideC +
                             J.chBase + oc] = f2bf(v);
                    }
                } else if (MODE == 2) {
                    unsigned short hi = f2bf(v);
                    J.d1[(size_t)b * batB + (size_t)p * 32 + oc] = hi;
                    J.d2[(size_t)b * batB + (size_t)p * 32 + oc] = f2bf(v - bf2f(hi));
                } else if (MODE == 3) {
                    J.d1[(size_t)b * batB + (size_t)oc * HW + p] = f2bf(v);
                } else {  // MODE 4
                    int y = p >> 6, x = p & 63;
                    J.d1[(size_t)b * batB + (size_t)((y + 1) * 66 + x + 1) * strideC +
                         J.chBase + oc] = f2bf(v);
                    msum += v;
                }
            }
            if (MODE == 4) {
#pragma unroll
                for (int off = 8; off; off >>= 1) msum += __shfl_down(msum, off, 16);
                if (ln == 0) atomicAdd(&ybuf[b * 256 + oc], msum);
            }
        }
    }
}

// ---------------------------------------------------------------------------
// Flash attention (both softmax orientations) — unchanged from round 3.
// ---------------------------------------------------------------------------
__global__ __launch_bounds__(256) void flash_attn(
    const unsigned short* __restrict__ qt_h, const unsigned short* __restrict__ qt_l,
    const unsigned short* __restrict__ kt_h, const unsigned short* __restrict__ kt_l,
    const unsigned short* __restrict__ vbf,
    unsigned short* __restrict__ catN) {
    int mode = blockIdx.y, b = blockIdx.z;
    size_t qkoff = (size_t)b * HW * 32;
    const unsigned short* Qh = (mode ? kt_h : qt_h) + qkoff;
    const unsigned short* Ql = (mode ? kt_l : qt_l) + qkoff;
    const unsigned short* Kh = (mode ? qt_h : kt_h) + qkoff;
    const unsigned short* Kl = (mode ? qt_l : kt_l) + qkoff;
    const unsigned short* V = vbf + (size_t)b * 256 * HW;
    unsigned short* out = catN + (size_t)b * PIX66 * 768;

    int t = threadIdx.x, w = t >> 6, l = t & 63, quad = l >> 4, ln = l & 15;
    int pg = w >> 1, ch = w & 1;
    int p0 = blockIdx.x * 64, pw = pg * 32;
    int cb = ch * 128;

    __shared__ unsigned short sV[256 * 72];
    __shared__ unsigned short sP[64 * 72];

    short8 qbh[2], qbl[2];
#pragma unroll
    for (int pn = 0; pn < 2; ++pn) {
        size_t off = (size_t)(p0 + pw + pn * 16 + ln) * 32 + quad * 8;
        qbh[pn] = *(const short8*)(Qh + off);
        qbl[pn] = *(const short8*)(Ql + off);
    }

    float m_run[2] = {-3.0e38f, -3.0e38f};
    float l_run[2] = {0.f, 0.f};
    f32x4 accO[8][2];
#pragma unroll
    for (int cs = 0; cs < 8; ++cs)
#pragma unroll
        for (int pn = 0; pn < 2; ++pn) accO[cs][pn] = (f32x4){0.f, 0.f, 0.f, 0.f};

    for (int jb = 0; jb < HW; jb += 64) {
        short8 vreg[8];
#pragma unroll
        for (int i = 0; i < 8; ++i) {
            int idx = t + 256 * i;
            int c = idx >> 3, ck = idx & 7;
            vreg[i] = *(const short8*)(V + (size_t)c * HW + jb + ck * 8);
        }
        short8 kah[4], kal[4];
#pragma unroll
        for (int jj = 0; jj < 4; ++jj) {
            size_t off = (size_t)(jb + 16 * jj + ln) * 32 + quad * 8;
            kah[jj] = *(const short8*)(Kh + off);
            kal[jj] = *(const short8*)(Kl + off);
        }
        __syncthreads();
#pragma unroll
        for (int i = 0; i < 8; ++i) {
            int idx = t + 256 * i;
            int c = idx >> 3, ck = idx & 7;
            *(short8*)(sV + (size_t)c * 72 + ck * 8) = vreg[i];
        }

        f32x4 sacc[2][4];
#pragma unroll
        for (int pn = 0; pn < 2; ++pn)
#pragma unroll
            for (int jj = 0; jj < 4; ++jj) sacc[pn][jj] = (f32x4){0.f, 0.f, 0.f, 0.f};
#pragma unroll
        for (int pn = 0; pn < 2; ++pn)
#pragma unroll
            for (int jj = 0; jj < 4; ++jj) {
                sacc[pn][jj] = __builtin_amdgcn_mfma_f32_16x16x32_bf16(
                    kah[jj], qbh[pn], sacc[pn][jj], 0, 0, 0);
                sacc[pn][jj] = __builtin_amdgcn_mfma_f32_16x16x32_bf16(
                    kah[jj], qbl[pn], sacc[pn][jj], 0, 0, 0);
                sacc[pn][jj] = __builtin_amdgcn_mfma_f32_16x16x32_bf16(
                    kal[jj], qbh[pn], sacc[pn][jj], 0, 0, 0);
            }

#pragma unroll
        for (int pn = 0; pn < 2; ++pn) {
            float tm = -3.0e38f;
#pragma unroll
            for (int jj = 0; jj < 4; ++jj)
#pragma unroll
                for (int r = 0; r < 4; ++r) tm = fmaxf(tm, sacc[pn][jj][r]);
            tm = fmaxf(tm, __shfl_xor(tm, 16));
            tm = fmaxf(tm, __shfl_xor(tm, 32));
            float mnew = fmaxf(m_run[pn], tm);
            float alpha = __expf(m_run[pn] - mnew);
            m_run[pn] = mnew;
            float psum = 0.f;
#pragma unroll
            for (int jj = 0; jj < 4; ++jj) {
                us4 pk;
#pragma unroll
                for (int r = 0; r < 4; ++r) {
                    float e = __expf(sacc[pn][jj][r] - mnew);
                    psum += e;
                    pk[r] = f2bf(e);
                }
                *(us4*)(sP + (size_t)(pw + pn * 16 + ln) * 72 + jj * 16 + quad * 4) = pk;
            }
            psum += __shfl_xor(psum, 16);
            psum += __shfl_xor(psum, 32);
            l_run[pn] = l_run[pn] * alpha + psum;
#pragma unroll
            for (int cs = 0; cs < 8; ++cs) accO[cs][pn] *= alpha;
        }
        __syncthreads();

        short8 pb[2][2];
#pragma unroll
        for (int pn = 0; pn < 2; ++pn)
#pragma unroll
            for (int j2 = 0; j2 < 2; ++j2)
                pb[pn][j2] = *(const short8*)(sP + (size_t)(pw + pn * 16 + ln) * 72 +
                                              j2 * 32 + quad * 8);
#pragma unroll
        for (int cs = 0; cs < 8; ++cs) {
            const unsigned short* vrow = sV + (size_t)(cb + cs * 16 + ln) * 72 + quad * 8;
            short8 va0 = *(const short8*)(vrow);
            short8 va1 = *(const short8*)(vrow + 32);
#pragma unroll
            for (int pn = 0; pn < 2; ++pn) {
                accO[cs][pn] = __builtin_amdgcn_mfma_f32_16x16x32_bf16(
                    va0, pb[pn][0], accO[cs][pn], 0, 0, 0);
                accO[cs][pn] = __builtin_amdgcn_mfma_f32_16x16x32_bf16(
                    va1, pb[pn][1], accO[cs][pn], 0, 0, 0);
            }
        }
    }

#pragma unroll
    for (int pn = 0; pn < 2; ++pn) {
        float inv = 1.f / l_run[pn];
        int p = p0 + pw + pn * 16 + ln;
        int y = p >> 6, x = p & 63;
        size_t pix = (size_t)((y + 1) * 66 + x + 1);
#pragma unroll
        for (int cs = 0; cs < 8; ++cs)
#pragma unroll
            for (int r = 0; r < 4; ++r) {
                int c = cb + cs * 16 + quad * 4 + r;
                out[pix * 768 + 256 + mode * 256 + c] = f2bf(accO[cs][pn][r] * inv);
            }
    }
}

// ---------------------------------------------------------------------------
// SE mlp + in-place scale of catN ch 0..255
// ---------------------------------------------------------------------------
__global__ __launch_bounds__(256) void se_mlp_kernel(const float* __restrict__ y,
                                                     const float* __restrict__ w1,
                                                     const float* __restrict__ w2,
                                                     float* __restrict__ sc) {
    int b = blockIdx.x, t = threadIdx.x;
    __shared__ float sy[256], sh[32];
    sy[t] = y[b * 256 + t] * (1.f / 4096.f);
    __syncthreads();
    if (t < 32) {
        float s = 0.f;
        for (int c = 0; c < 256; ++c) s = fmaf(w1[t * 256 + c], sy[c], s);
        sh[t] = fmaxf(s, 0.f);
    }
    __syncthreads();
    float s = 0.f;
#pragma unroll
    for (int h = 0; h < 32; ++h) s = fmaf(w2[t * 32 + h], sh[h], s);
    sc[b * 256 + t] = 1.f / (1.f + __expf(-s));
}

__global__ __launch_bounds__(256) void se_scale_cat(unsigned short* __restrict__ catN,
                                                    const float* __restrict__ sc) {
    int idx = blockIdx.x * 256 + threadIdx.x;   // 2*4096*256
    int c = idx & 255;
    int p = (idx >> 8) & 4095;
    int b = idx >> 20;
    int y = p >> 6, x = p & 63;
    size_t pix = (size_t)((y + 1) * 66 + x + 1);
    unsigned short* q = catN + (size_t)b * (PIX66 * 768) + pix * 768 + c;
    *q = f2bf(bf2f(*q) * sc[b * 256 + c]);
}

// ---------------------------------------------------------------------------
extern "C" void kernel_launch(void* const* d_in, const int* in_sizes, int n_in,
                              void* d_out, int out_size, void* d_ws, size_t ws_size,
                              hipStream_t stream) {
    const float* x      = (const float*)d_in[0];
    const float* mmask  = (const float*)d_in[1];
    const float* amask  = (const float*)d_in[2];
    const float* w_mp   = (const float*)d_in[3];
    const float* b_mp   = (const float*)d_in[4];
    const float* w_ap   = (const float*)d_in[5];
    const float* b_ap   = (const float*)d_in[6];
    const float* w_q    = (const float*)d_in[7];
    const float* b_q    = (const float*)d_in[8];
    const float* w_k    = (const float*)d_in[9];
    const float* b_k    = (const float*)d_in[10];
    const float* w_v    = (const float*)d_in[11];
    const float* b_v    = (const float*)d_in[12];
    const float* w_comp = (const float*)d_in[13];
    const float* b_comp = (const float*)d_in[14];
    const float* w_out  = (const float*)d_in[15];
    const float* b_out  = (const float*)d_in[16];
    const float* w_se1  = (const float*)d_in[17];
    const float* w_se2  = (const float*)d_in[18];

    unsigned short* us = (unsigned short*)d_ws;
    size_t o = 0;
    // ---- zeroed bf16 region ----
    unsigned short* xpad_hi = us + o; o += (size_t)2 * PIX66 * 256;
    unsigned short* xpad_lo = us + o; o += (size_t)2 * PIX66 * 256;
    unsigned short* mq_hi   = us + o; o += (size_t)2 * PIX66 * 32;
    unsigned short* mq_lo   = us + o; o += (size_t)2 * PIX66 * 32;
    unsigned short* ma_hi   = us + o; o += (size_t)2 * PIX66 * 32;
    unsigned short* ma_lo   = us + o; o += (size_t)2 * PIX66 * 32;
    unsigned short* ipad    = us + o; o += (size_t)2 * PIX66 * 320;
    unsigned short* catN    = us + o; o += (size_t)2 * PIX66 * 768;
    size_t zeroBytes = o * sizeof(unsigned short);
    // ---- fully-written bf16 region ----
    unsigned short* wt_mp = us + o; o += (size_t)9 * 32 * 256;
    unsigned short* wt_ap = us + o; o += (size_t)9 * 32 * 256;
    unsigned short* wt_qh = us + o; o += (size_t)9 * 32 * 288;
    unsigned short* wt_ql = us + o; o += (size_t)9 * 32 * 288;
    unsigned short* wt_kh = us + o; o += (size_t)9 * 32 * 288;
    unsigned short* wt_kl = us + o; o += (size_t)9 * 32 * 288;
    unsigned short* wt_v  = us + o; o += (size_t)9 * 256 * 256;
    unsigned short* wt_cp = us + o; o += (size_t)9 * 256 * 320;
    unsigned short* wt_ot = us + o; o += (size_t)9 * 256 * 768;
    unsigned short* qt_h  = us + o; o += (size_t)2 * HW * 32;
    unsigned short* qt_l  = us + o; o += (size_t)2 * HW * 32;
    unsigned short* kt_h  = us + o; o += (size_t)2 * HW * 32;
    unsigned short* kt_l  = us + o; o += (size_t)2 * HW * 32;
    unsigned short* vbf   = us + o; o += (size_t)2 * 256 * HW;
    // ---- fp32 region ----
    float* fp = (float*)(us + o);
    size_t fo = 0;
    float* ybuf = fp + fo; fo += 512;
    float* sbuf = fp + fo; fo += 512;
    size_t need = o * sizeof(unsigned short) + fo * sizeof(float);
    if (ws_size < need) return;

    float* outp = (float*)d_out;

    hipMemsetAsync(us, 0, zeroBytes, stream);
    hipMemsetAsync(ybuf, 0, 512 * sizeof(float), stream);

    // fused weight transforms (7 jobs); grid.x sized for the largest
    WtJob W0{w_mp,   wt_mp, (unsigned short*)0, 19, 32, 256, 256, 0, 256};
    WtJob W1{w_ap,   wt_ap, (unsigned short*)0, 19, 32, 256, 256, 0, 256};
    WtJob W2{w_q,    wt_qh, wt_ql,             32, 32, 256, 256, 19, 288};
    WtJob W3{w_k,    wt_kh, wt_kl,             32, 32, 256, 256, 19, 288};
    WtJob W4{w_v,    wt_v,  (unsigned short*)0, 256, 256, 256, 256, 0, 256};
    WtJob W5{w_comp, wt_cp, (unsigned short*)0, 256, 256, 294, 320, 0, 320};
    WtJob W6{w_out,  wt_ot, (unsigned short*)0, 256, 256, 768, 768, 0, 768};
    k_wt_all<<<dim3((9 * 256 * 768 + 255) / 256, 7), 256, 0, stream>>>(
        W0, W1, W2, W3, W4, W5, W6);

    k_build_x<<<dim3(64, 4, 2), 256, 0, stream>>>(x, xpad_hi, xpad_lo, ipad);
    k_build_mask2<<<dim3(1024, 2), 256, 0, stream>>>(mmask, amask, mq_hi, mq_lo,
                                                     ma_hi, ma_lo);

    const unsigned short* NUS = (const unsigned short*)0;
    unsigned short* NUSo = (unsigned short*)0;
    float* NF = (float*)0;

    // mp+ap fused (MODE 1) -> ipad ch 256 / 275
    ConvJob jm{NUS, NUS, wt_mp, NUS, b_mp, NF, ipad, NUSo, mmask, 256};
    ConvJob ja{NUS, NUS, wt_ap, NUS, b_ap, NF, ipad, NUSo, amask, 275};
    conv_mfma<4, 1, 1, 1, 8, 1><<<dim3(32, 2, 2), 256, 0, stream>>>(
        xpad_hi, NUS, 256, 0, 32, 0, (size_t)PIX66 * 320, 320, 19, NF, jm, ja);

    // q+k fused (MODE 2, split precision) -> qt/kt hi+lo [p][32]
    ConvJob jq{mq_hi, mq_lo, wt_qh, wt_ql, b_q, NF, qt_h, qt_l, NF, 0};
    ConvJob jk{ma_hi, ma_lo, wt_kh, wt_kl, b_k, NF, kt_h, kt_l, NF, 0};
    conv_mfma<4, 1, 2, 3, 9, 1><<<dim3(32, 2, 2), 256, 0, stream>>>(
        xpad_hi, xpad_lo, 256, 32, 32, 0, (size_t)HW * 32, 0, 32, NF, jq, jk);

    // v conv (MODE 3) -> vbf [c][4096]
    ConvJob jv{NUS, NUS, wt_v, NUS, b_v, NF, vbf, NUSo, NF, 0};
    conv_mfma<2, 2, 3, 1, 8, 0><<<dim3(64, 4, 2), 256, 0, stream>>>(
        xpad_hi, NUS, 256, 0, 256, 0, (size_t)256 * HW, 0, 256, NF, jv, jv);

    // comp conv (MODE 4) -> catN ch 0..255 + channel sums
    ConvJob jc{NUS, NUS, wt_cp, NUS, b_comp, NF, catN, NUSo, NF, 0};
    conv_mfma<2, 2, 4, 1, 10, 0><<<dim3(64, 4, 2), 256, 0, stream>>>(
        ipad, NUS, 320, 0, 256, 0, (size_t)PIX66 * 768, 768, 256, ybuf, jc, jc);

    // SE
    se_mlp_kernel<<<2, 256, 0, stream>>>(ybuf, w_se1, w_se2, sbuf);
    se_scale_cat<<<8192, 256, 0, stream>>>(catN, sbuf);

    // flash attention: both modes, both batches
    flash_attn<<<dim3(64, 2, 2), 256, 0, stream>>>(qt_h, qt_l, kt_h, kt_l, vbf, catN);

    // final conv (MODE 0) -> d_out (fp32 NCHW)
    ConvJob jo{NUS, NUS, wt_ot, NUS, b_out, outp, NUSo, NUSo, NF, 0};
    conv_mfma<2, 2, 0, 1, 24, 0><<<dim3(64, 4, 2), 256, 0, stream>>>(
        catN, NUS, 768, 0, 256, (size_t)256 * HW, 0, 0, 256, NF, jo, jo);
}

// Round 5
// 662.945 us; speedup vs baseline: 8.8000x; 1.1716x over previous
//
#include <hip/hip_runtime.h>
#include <math.h>

#define HW 4096
#define IMG 64
#define PIX66 (66 * 66)

typedef short short8 __attribute__((ext_vector_type(8)));
typedef float f32x4 __attribute__((ext_vector_type(4)));
typedef unsigned short us4 __attribute__((ext_vector_type(4)));

__device__ __forceinline__ unsigned short f2bf(float f) {
    unsigned int u = __float_as_uint(f);
    u += 0x7fff + ((u >> 16) & 1);
    return (unsigned short)(u >> 16);
}
__device__ __forceinline__ float bf2f(unsigned short h) {
    return __uint_as_float(((unsigned int)h) << 16);
}

// async global->LDS, 16B per lane
__device__ __forceinline__ void gll16(const unsigned short* g, unsigned short* l) {
    __builtin_amdgcn_global_load_lds(
        (const __attribute__((address_space(1))) unsigned int*)(g),
        (__attribute__((address_space(3))) unsigned int*)(l), 16, 0, 0);
}

// ---------------------------------------------------------------------------
// weight transform: w fp32 [OC][C0+C1][9] -> wT bf16 [9][KS][OCpad][32]
// k = kg*32+kk; ic = k (k<C0) or C0+(k-K0pad) (K0pad<=k<K0pad+C1)
// ---------------------------------------------------------------------------
struct WtJob {
    const float* w;
    unsigned short* dh;
    unsigned short* dl;
    int OC, OCpad, C0, K0pad, C1, Ktot;
};

__global__ __launch_bounds__(256) void k_wt_all(WtJob J0, WtJob J1, WtJob J2,
                                                WtJob J3, WtJob J4, WtJob J5,
                                                WtJob J6) {
    WtJob J;
    switch (blockIdx.y) {
        case 0: J = J0; break;
        case 1: J = J1; break;
        case 2: J = J2; break;
        case 3: J = J3; break;
        case 4: J = J4; break;
        case 5: J = J5; break;
        default: J = J6; break;
    }
    int idx = blockIdx.x * 256 + threadIdx.x;
    int KS = J.Ktot >> 5;
    int n = 9 * KS * J.OCpad * 32;
    if (idx >= n) return;
    int kk = idx & 31;
    int rest = idx >> 5;
    int oc = rest % J.OCpad;
    rest /= J.OCpad;
    int kg = rest % KS;
    int tap = rest / KS;
    int k = kg * 32 + kk;
    float v = 0.f;
    if (oc < J.OC) {
        int ic = -1;
        if (k < J.C0) ic = k;
        else if (k >= J.K0pad && (k - J.K0pad) < J.C1) ic = J.C0 + (k - J.K0pad);
        if (ic >= 0) v = J.w[((size_t)oc * (J.C0 + J.C1) + ic) * 9 + tap];
    }
    unsigned short hi = f2bf(v);
    J.dh[idx] = hi;
    if (J.dl) J.dl[idx] = f2bf(v - bf2f(hi));
}

// ---------------------------------------------------------------------------
// build P32 bf16 x (hi+lo) [b][8][PIX66][32] and ipad [b][10][PIX66][32]
// ---------------------------------------------------------------------------
__global__ __launch_bounds__(256) void k_build_x(const float* __restrict__ x,
                                                 unsigned short* __restrict__ xh,
                                                 unsigned short* __restrict__ xl,
                                                 unsigned short* __restrict__ ipad) {
    int b = blockIdx.z, c0 = blockIdx.y * 64, p0 = blockIdx.x * 64;
    __shared__ float s[64][65];
    int t = threadIdx.x;
    for (int i = t; i < 4096; i += 256) {
        int c = i >> 6, p = i & 63;
        s[p][c] = x[((size_t)b * 256 + c0 + c) * HW + p0 + p];
    }
    __syncthreads();
    for (int i = t; i < 4096; i += 256) {
        int c = i & 63, p = i >> 6;
        float f = s[p][c];
        unsigned short hi = f2bf(f);
        unsigned short lo = f2bf(f - bf2f(hi));
        int pp = p0 + p;
        int y = pp >> 6, xx = pp & 63;
        size_t pix = (size_t)((y + 1) * 66 + xx + 1);
        int C = c0 + c;
        size_t ix = ((size_t)(b * 8 + (C >> 5)) * PIX66 + pix) * 32 + (C & 31);
        xh[ix] = hi;
        xl[ix] = lo;
        ipad[((size_t)(b * 10 + (C >> 5)) * PIX66 + pix) * 32 + (C & 31)] = hi;
    }
}

// both masks -> P32 bf16 hi/lo [b][PIX66][32]
__global__ __launch_bounds__(256) void k_build_mask2(
    const float* __restrict__ m0, const float* __restrict__ m1,
    unsigned short* __restrict__ d0h, unsigned short* __restrict__ d0l,
    unsigned short* __restrict__ d1h, unsigned short* __restrict__ d1l) {
    const float* m = blockIdx.y ? m1 : m0;
    unsigned short* dh = blockIdx.y ? d1h : d0h;
    unsigned short* dl = blockIdx.y ? d1l : d0l;
    int idx = blockIdx.x * 256 + threadIdx.x;   // 2*4096*32
    int c = idx & 31;
    int p = (idx >> 5) & 4095;
    int b = idx >> 17;
    float f = (c < 19) ? m[((size_t)b * 19 + c) * HW + p] : 0.f;
    unsigned short hi = f2bf(f);
    int y = p >> 6, xx = p & 63;
    size_t pix = (size_t)((y + 1) * 66 + xx + 1);
    dh[(size_t)b * (PIX66 * 32) + pix * 32 + c] = hi;
    dl[(size_t)b * (PIX66 * 32) + pix * 32 + c] = f2bf(f - bf2f(hi));
}

// ---------------------------------------------------------------------------
// direct-load MFMA conv for small-M (OC=32) convs, P32 layouts.
// Block: 4 waves x 32px, one 32-oc tile. FUSE2 via blockIdx.y (job select).
// MODE 1: (acc+bias)*mask -> ipad P32 at chBase (mp/ap)
// MODE 2: split bf16 pixel-major [p][32] hi+lo   (q/k), NPASS=3
// ---------------------------------------------------------------------------
struct ConvJob {
    const unsigned short* s1h;
    const unsigned short* s1l;
    const unsigned short* wth;
    const unsigned short* wtl;
    const float* bias;
    unsigned short* d1;
    unsigned short* d2;
    const float* mask;
    int chBase;
};

template <int MODE, int NPASS, int KS0, int KS1>
__global__ __launch_bounds__(256, 2) void conv_direct(
    const unsigned short* __restrict__ s0h, const unsigned short* __restrict__ s0l,
    ConvJob j0, ConvJob j1) {
    constexpr int KS = KS0 + KS1;
    constexpr int ST = NPASS * 9 * KS;
    constexpr int OCpad = 32;
    int b = blockIdx.z;
    ConvJob J = blockIdx.y ? j1 : j0;
    int t = threadIdx.x, w = t >> 6, l = t & 63, quad = l >> 4, ln = l & 15;
    int pBase = blockIdx.x * 128 + w * 32;

    long pb[2];
    int padpix[2];
#pragma unroll
    for (int tn = 0; tn < 2; ++tn) {
        int p = pBase + tn * 16 + ln;
        padpix[tn] = ((p >> 6) + 1) * 66 + (p & 63) + 1;
        pb[tn] = (long)padpix[tn] * 32 + quad * 8;
    }
    size_t aoff[2];
#pragma unroll
    for (int tm = 0; tm < 2; ++tm) aoff[tm] = (size_t)(tm * 16 + ln) * 32 + quad * 8;

    const unsigned short* S0H = s0h + (size_t)b * KS0 * PIX66 * 32;
    const unsigned short* S0L = (NPASS == 3) ? s0l + (size_t)b * KS0 * PIX66 * 32
                                             : (const unsigned short*)0;
    const unsigned short* S1H = KS1 ? J.s1h + (size_t)b * KS1 * PIX66 * 32
                                    : (const unsigned short*)0;
    const unsigned short* S1L = (KS1 && NPASS == 3) ? J.s1l + (size_t)b * KS1 * PIX66 * 32
                                                    : (const unsigned short*)0;

    f32x4 acc[2][2];
#pragma unroll
    for (int i = 0; i < 2; ++i)
#pragma unroll
        for (int j = 0; j < 2; ++j) acc[i][j] = (f32x4){0.f, 0.f, 0.f, 0.f};

    int ps = 0, tap = 0, kg = 0;
    auto adv = [&]() {
        if (++kg == KS) { kg = 0; if (++tap == 9) { tap = 0; ++ps; } }
    };
    auto loadStep = [&](int lps, int ltap, int lkg, short8* bf, short8* af) {
        int d3 = ltap / 3;
        long doff = (long)((d3 - 1) * 66 + (ltap - d3 * 3 - 1)) * 32;
        const unsigned short* Sp;
        long plane;
        if (lkg < KS0) {
            Sp = (NPASS == 3 && lps == 2) ? S0L : S0H;
            plane = (long)lkg * PIX66 * 32;
        } else {
            Sp = (NPASS == 3 && lps == 2) ? S1L : S1H;
            plane = (long)(lkg - KS0) * PIX66 * 32;
        }
        bf[0] = *(const short8*)(Sp + plane + doff + pb[0]);
        bf[1] = *(const short8*)(Sp + plane + doff + pb[1]);
        const unsigned short* WT = ((NPASS == 3 && lps == 1) ? J.wtl : J.wth) +
                                   (size_t)(ltap * KS + lkg) * OCpad * 32;
        af[0] = *(const short8*)(WT + aoff[0]);
        af[1] = *(const short8*)(WT + aoff[1]);
    };

    short8 bfr[4][2], afr[4][2];
#pragma unroll
    for (int u = 0; u < 4; ++u) { loadStep(ps, tap, kg, bfr[u], afr[u]); adv(); }

    for (int s = 0; s < ST; s += 4) {
#pragma unroll
        for (int u = 0; u < 4; ++u) {
            if (s + u < ST) {
#pragma unroll
                for (int tm = 0; tm < 2; ++tm)
#pragma unroll
                    for (int tn = 0; tn < 2; ++tn)
                        acc[tm][tn] = __builtin_amdgcn_mfma_f32_16x16x32_bf16(
                            afr[u][tm], bfr[u][tn], acc[tm][tn], 0, 0, 0);
                if (s + u + 4 < ST) { loadStep(ps, tap, kg, bfr[u], afr[u]); adv(); }
            }
        }
    }

#pragma unroll
    for (int tm = 0; tm < 2; ++tm) {
#pragma unroll
        for (int r = 0; r < 4; ++r) {
            int oc = tm * 16 + quad * 4 + r;
#pragma unroll
            for (int tn = 0; tn < 2; ++tn) {
                int p = pBase + tn * 16 + ln;
                if (MODE == 1) {
                    if (oc < 19) {
                        float v = (acc[tm][tn][r] + J.bias[oc]) *
                                  J.mask[((size_t)b * 19 + oc) * HW + p];
                        int ch = J.chBase + oc;
                        J.d1[((size_t)(b * 10 + (ch >> 5)) * PIX66 + padpix[tn]) * 32 +
                             (ch & 31)] = f2bf(v);
                    }
                } else {  // MODE 2
                    float v = acc[tm][tn][r] + J.bias[oc];
                    unsigned short hi = f2bf(v);
                    J.d1[((size_t)b * HW + p) * 32 + oc] = hi;
                    J.d2[((size_t)b * HW + p) * 32 + oc] = f2bf(v - bf2f(hi));
                }
            }
        }
    }
}

// ---------------------------------------------------------------------------
// LDS-staged MFMA conv for OC=256 convs (v, comp, out), P32 layouts.
// Block: 128 threads = 2 waves; tile = 2 out-rows (128 px) x 64 oc.
// Per kg: stage B 264px x 32ch (16.9KB, contiguous) via global_load_lds;
// per tap: stage A 64oc x 32ch (4KB); frags via ds_read_b128; 16 MFMA/wave.
// MODE 0: fp32 NCHW (out -> d_out); MODE 3: bf16 CHW (v); MODE 4: catN P32 + ybuf
// ---------------------------------------------------------------------------
template <int KS, int MODE>
__global__ __launch_bounds__(128, 3) void conv_lds(
    const unsigned short* __restrict__ src,   // [B][KS][PIX66][32]
    const unsigned short* __restrict__ wt,    // [9][KS][256][32]
    const float* __restrict__ bias,
    float* __restrict__ dstf,
    unsigned short* __restrict__ dstb,
    float* __restrict__ ybuf) {
    int b = blockIdx.z;
    int ocBase = blockIdx.y * 64;
    int ry = blockIdx.x * 2;                  // out row pair
    int t = threadIdx.x, w = t >> 6, l = t & 63, quad = l >> 4, ln = l & 15;

    __shared__ unsigned short sB[264 * 32];
    __shared__ unsigned short sA[64 * 32];

    const unsigned short* S = src + (size_t)b * KS * PIX66 * 32;
    const size_t bStageBase = (size_t)(ry * 66) * 32;   // pad rows ry..ry+3

    f32x4 acc[4][4];
#pragma unroll
    for (int i = 0; i < 4; ++i)
#pragma unroll
        for (int j = 0; j < 4; ++j) acc[i][j] = (f32x4){0.f, 0.f, 0.f, 0.f};

    for (int kg = 0; kg < KS; ++kg) {
        const unsigned short* gB = S + (size_t)kg * PIX66 * 32 + bStageBase;
        for (int i = t; i < 1056; i += 128) gll16(gB + (size_t)i * 8, sB + (size_t)i * 8);
        for (int tap = 0; tap < 9; ++tap) {
            const unsigned short* gA =
                wt + ((size_t)(tap * KS + kg) * 256 + ocBase) * 32;
            for (int i = t; i < 256; i += 128) gll16(gA + (size_t)i * 8, sA + (size_t)i * 8);
            __syncthreads();
            int dy = tap / 3 - 1, dx = tap % 3 - 1;
            int lpBase = (1 + w + dy) * 66 + 1 + dx;
            short8 bf[4], af[4];
#pragma unroll
            for (int tn = 0; tn < 4; ++tn)
                bf[tn] = *(const short8*)(sB + (size_t)(lpBase + tn * 16 + ln) * 32 +
                                          quad * 8);
#pragma unroll
            for (int tm = 0; tm < 4; ++tm)
                af[tm] = *(const short8*)(sA + (size_t)(tm * 16 + ln) * 32 + quad * 8);
#pragma unroll
            for (int tm = 0; tm < 4; ++tm)
#pragma unroll
                for (int tn = 0; tn < 4; ++tn)
                    acc[tm][tn] = __builtin_amdgcn_mfma_f32_16x16x32_bf16(
                        af[tm], bf[tn], acc[tm][tn], 0, 0, 0);
            __syncthreads();
        }
    }

    int prow = ry + w;
#pragma unroll
    for (int tm = 0; tm < 4; ++tm) {
#pragma unroll
        for (int r = 0; r < 4; ++r) {
            int oc = ocBase + tm * 16 + quad * 4 + r;
            float bi = bias[oc];
            float msum = 0.f;
#pragma unroll
            for (int tn = 0; tn < 4; ++tn) {
                int px = tn * 16 + ln;
                float v = acc[tm][tn][r] + bi;
                if (MODE == 0) {
                    dstf[((size_t)b * 256 + oc) * HW + prow * 64 + px] = v;
                } else if (MODE == 3) {
                    dstb[((size_t)b * 256 + oc) * HW + prow * 64 + px] = f2bf(v);
                } else {  // MODE 4
                    size_t pix = (size_t)(prow + 1) * 66 + px + 1;
                    dstb[((size_t)(b * 24 + (oc >> 5)) * PIX66 + pix) * 32 + (oc & 31)] =
                        f2bf(v);
                    msum += v;
                }
            }
            if (MODE == 4) {
#pragma unroll
                for (int off = 8; off; off >>= 1) msum += __shfl_down(msum, off, 16);
                if (ln == 0) atomicAdd(&ybuf[b * 256 + oc], msum);
            }
        }
    }
}

// ---------------------------------------------------------------------------
// Flash attention (both softmax orientations); catN epilogue in P32.
// ---------------------------------------------------------------------------
__global__ __launch_bounds__(256) void flash_attn(
    const unsigned short* __restrict__ qt_h, const unsigned short* __restrict__ qt_l,
    const unsigned short* __restrict__ kt_h, const unsigned short* __restrict__ kt_l,
    const unsigned short* __restrict__ vbf,
    unsigned short* __restrict__ catN) {
    int mode = blockIdx.y, b = blockIdx.z;
    size_t qkoff = (size_t)b * HW * 32;
    const unsigned short* Qh = (mode ? kt_h : qt_h) + qkoff;
    const unsigned short* Ql = (mode ? kt_l : qt_l) + qkoff;
    const unsigned short* Kh = (mode ? qt_h : kt_h) + qkoff;
    const unsigned short* Kl = (mode ? qt_l : kt_l) + qkoff;
    const unsigned short* V = vbf + (size_t)b * 256 * HW;
    unsigned short* out = catN + (size_t)b * 24 * PIX66 * 32;

    int t = threadIdx.x, w = t >> 6, l = t & 63, quad = l >> 4, ln = l & 15;
    int pg = w >> 1, ch = w & 1;
    int p0 = blockIdx.x * 64, pw = pg * 32;
    int cb = ch * 128;

    __shared__ unsigned short sV[256 * 72];
    __shared__ unsigned short sP[64 * 72];

    short8 qbh[2], qbl[2];
#pragma unroll
    for (int pn = 0; pn < 2; ++pn) {
        size_t off = (size_t)(p0 + pw + pn * 16 + ln) * 32 + quad * 8;
        qbh[pn] = *(const short8*)(Qh + off);
        qbl[pn] = *(const short8*)(Ql + off);
    }

    float m_run[2] = {-3.0e38f, -3.0e38f};
    float l_run[2] = {0.f, 0.f};
    f32x4 accO[8][2];
#pragma unroll
    for (int cs = 0; cs < 8; ++cs)
#pragma unroll
        for (int pn = 0; pn < 2; ++pn) accO[cs][pn] = (f32x4){0.f, 0.f, 0.f, 0.f};

    for (int jb = 0; jb < HW; jb += 64) {
        short8 vreg[8];
#pragma unroll
        for (int i = 0; i < 8; ++i) {
            int idx = t + 256 * i;
            int c = idx >> 3, ck = idx & 7;
            vreg[i] = *(const short8*)(V + (size_t)c * HW + jb + ck * 8);
        }
        short8 kah[4], kal[4];
#pragma unroll
        for (int jj = 0; jj < 4; ++jj) {
            size_t off = (size_t)(jb + 16 * jj + ln) * 32 + quad * 8;
            kah[jj] = *(const short8*)(Kh + off);
            kal[jj] = *(const short8*)(Kl + off);
        }
        __syncthreads();
#pragma unroll
        for (int i = 0; i < 8; ++i) {
            int idx = t + 256 * i;
            int c = idx >> 3, ck = idx & 7;
            *(short8*)(sV + (size_t)c * 72 + ck * 8) = vreg[i];
        }

        f32x4 sacc[2][4];
#pragma unroll
        for (int pn = 0; pn < 2; ++pn)
#pragma unroll
            for (int jj = 0; jj < 4; ++jj) sacc[pn][jj] = (f32x4){0.f, 0.f, 0.f, 0.f};
#pragma unroll
        for (int pn = 0; pn < 2; ++pn)
#pragma unroll
            for (int jj = 0; jj < 4; ++jj) {
                sacc[pn][jj] = __builtin_amdgcn_mfma_f32_16x16x32_bf16(
                    kah[jj], qbh[pn], sacc[pn][jj], 0, 0, 0);
                sacc[pn][jj] = __builtin_amdgcn_mfma_f32_16x16x32_bf16(
                    kah[jj], qbl[pn], sacc[pn][jj], 0, 0, 0);
                sacc[pn][jj] = __builtin_amdgcn_mfma_f32_16x16x32_bf16(
                    kal[jj], qbh[pn], sacc[pn][jj], 0, 0, 0);
            }

#pragma unroll
        for (int pn = 0; pn < 2; ++pn) {
            float tm = -3.0e38f;
#pragma unroll
            for (int jj = 0; jj < 4; ++jj)
#pragma unroll
                for (int r = 0; r < 4; ++r) tm = fmaxf(tm, sacc[pn][jj][r]);
            tm = fmaxf(tm, __shfl_xor(tm, 16));
            tm = fmaxf(tm, __shfl_xor(tm, 32));
            float mnew = fmaxf(m_run[pn], tm);
            float alpha = __expf(m_run[pn] - mnew);
            m_run[pn] = mnew;
            float psum = 0.f;
#pragma unroll
            for (int jj = 0; jj < 4; ++jj) {
                us4 pk;
#pragma unroll
                for (int r = 0; r < 4; ++r) {
                    float e = __expf(sacc[pn][jj][r] - mnew);
                    psum += e;
                    pk[r] = f2bf(e);
                }
                *(us4*)(sP + (size_t)(pw + pn * 16 + ln) * 72 + jj * 16 + quad * 4) = pk;
            }
            psum += __shfl_xor(psum, 16);
            psum += __shfl_xor(psum, 32);
            l_run[pn] = l_run[pn] * alpha + psum;
#pragma unroll
            for (int cs = 0; cs < 8; ++cs) accO[cs][pn] *= alpha;
        }
        __syncthreads();

        short8 pb[2][2];
#pragma unroll
        for (int pn = 0; pn < 2; ++pn)
#pragma unroll
            for (int j2 = 0; j2 < 2; ++j2)
                pb[pn][j2] = *(const short8*)(sP + (size_t)(pw + pn * 16 + ln) * 72 +
                                              j2 * 32 + quad * 8);
#pragma unroll
        for (int cs = 0; cs < 8; ++cs) {
            const unsigned short* vrow = sV + (size_t)(cb + cs * 16 + ln) * 72 + quad * 8;
            short8 va0 = *(const short8*)(vrow);
            short8 va1 = *(const short8*)(vrow + 32);
#pragma unroll
            for (int pn = 0; pn < 2; ++pn) {
                accO[cs][pn] = __builtin_amdgcn_mfma_f32_16x16x32_bf16(
                    va0, pb[pn][0], accO[cs][pn], 0, 0, 0);
                accO[cs][pn] = __builtin_amdgcn_mfma_f32_16x16x32_bf16(
                    va1, pb[pn][1], accO[cs][pn], 0, 0, 0);
            }
        }
    }

#pragma unroll
    for (int pn = 0; pn < 2; ++pn) {
        float inv = 1.f / l_run[pn];
        int p = p0 + pw + pn * 16 + ln;
        int y = p >> 6, x = p & 63;
        size_t pix = (size_t)((y + 1) * 66 + x + 1);
#pragma unroll
        for (int cs = 0; cs < 8; ++cs)
#pragma unroll
            for (int r = 0; r < 4; ++r) {
                int cf = 256 + mode * 256 + cb + cs * 16 + quad * 4 + r;
                out[((size_t)(cf >> 5) * PIX66 + pix) * 32 + (cf & 31)] =
                    f2bf(accO[cs][pn][r] * inv);
            }
    }
}

// ---------------------------------------------------------------------------
// SE mlp + in-place scale of catN ch 0..255 (P32)
// ---------------------------------------------------------------------------
__global__ __launch_bounds__(256) void se_mlp_kernel(const float* __restrict__ y,
                                                     const float* __restrict__ w1,
                                                     const float* __restrict__ w2,
                                                     float* __restrict__ sc) {
    int b = blockIdx.x, t = threadIdx.x;
    __shared__ float sy[256], sh[32];
    sy[t] = y[b * 256 + t] * (1.f / 4096.f);
    __syncthreads();
    if (t < 32) {
        float s = 0.f;
        for (int c = 0; c < 256; ++c) s = fmaf(w1[t * 256 + c], sy[c], s);
        sh[t] = fmaxf(s, 0.f);
    }
    __syncthreads();
    float s = 0.f;
#pragma unroll
    for (int h = 0; h < 32; ++h) s = fmaf(w2[t * 32 + h], sh[h], s);
    sc[b * 256 + t] = 1.f / (1.f + __expf(-s));
}

__global__ __launch_bounds__(256) void se_scale_cat(unsigned short* __restrict__ catN,
                                                    const float* __restrict__ sc) {
    int idx = blockIdx.x * 256 + threadIdx.x;   // 2*4096*256
    int c = idx & 255;
    int p = (idx >> 8) & 4095;
    int b = idx >> 20;
    int y = p >> 6, x = p & 63;
    size_t pix = (size_t)((y + 1) * 66 + x + 1);
    unsigned short* q =
        catN + ((size_t)(b * 24 + (c >> 5)) * PIX66 + pix) * 32 + (c & 31);
    *q = f2bf(bf2f(*q) * sc[b * 256 + c]);
}

// ---------------------------------------------------------------------------
extern "C" void kernel_launch(void* const* d_in, const int* in_sizes, int n_in,
                              void* d_out, int out_size, void* d_ws, size_t ws_size,
                              hipStream_t stream) {
    const float* x      = (const float*)d_in[0];
    const float* mmask  = (const float*)d_in[1];
    const float* amask  = (const float*)d_in[2];
    const float* w_mp   = (const float*)d_in[3];
    const float* b_mp   = (const float*)d_in[4];
    const float* w_ap   = (const float*)d_in[5];
    const float* b_ap   = (const float*)d_in[6];
    const float* w_q    = (const float*)d_in[7];
    const float* b_q    = (const float*)d_in[8];
    const float* w_k    = (const float*)d_in[9];
    const float* b_k    = (const float*)d_in[10];
    const float* w_v    = (const float*)d_in[11];
    const float* b_v    = (const float*)d_in[12];
    const float* w_comp = (const float*)d_in[13];
    const float* b_comp = (const float*)d_in[14];
    const float* w_out  = (const float*)d_in[15];
    const float* b_out  = (const float*)d_in[16];
    const float* w_se1  = (const float*)d_in[17];
    const float* w_se2  = (const float*)d_in[18];

    unsigned short* us = (unsigned short*)d_ws;
    size_t o = 0;
    // ---- zeroed bf16 region (P32 padded buffers) ----
    unsigned short* xpad_hi = us + o; o += (size_t)2 * 8 * PIX66 * 32;
    unsigned short* xpad_lo = us + o; o += (size_t)2 * 8 * PIX66 * 32;
    unsigned short* mq_hi   = us + o; o += (size_t)2 * PIX66 * 32;
    unsigned short* mq_lo   = us + o; o += (size_t)2 * PIX66 * 32;
    unsigned short* ma_hi   = us + o; o += (size_t)2 * PIX66 * 32;
    unsigned short* ma_lo   = us + o; o += (size_t)2 * PIX66 * 32;
    unsigned short* ipad    = us + o; o += (size_t)2 * 10 * PIX66 * 32;
    unsigned short* catN    = us + o; o += (size_t)2 * 24 * PIX66 * 32;
    size_t zeroBytes = o * sizeof(unsigned short);
    // ---- fully-written bf16 region ----
    unsigned short* wt_mp = us + o; o += (size_t)9 * 8 * 32 * 32;
    unsigned short* wt_ap = us + o; o += (size_t)9 * 8 * 32 * 32;
    unsigned short* wt_qh = us + o; o += (size_t)9 * 9 * 32 * 32;
    unsigned short* wt_ql = us + o; o += (size_t)9 * 9 * 32 * 32;
    unsigned short* wt_kh = us + o; o += (size_t)9 * 9 * 32 * 32;
    unsigned short* wt_kl = us + o; o += (size_t)9 * 9 * 32 * 32;
    unsigned short* wt_v  = us + o; o += (size_t)9 * 8 * 256 * 32;
    unsigned short* wt_cp = us + o; o += (size_t)9 * 10 * 256 * 32;
    unsigned short* wt_ot = us + o; o += (size_t)9 * 24 * 256 * 32;
    unsigned short* qt_h  = us + o; o += (size_t)2 * HW * 32;
    unsigned short* qt_l  = us + o; o += (size_t)2 * HW * 32;
    unsigned short* kt_h  = us + o; o += (size_t)2 * HW * 32;
    unsigned short* kt_l  = us + o; o += (size_t)2 * HW * 32;
    unsigned short* vbf   = us + o; o += (size_t)2 * 256 * HW;
    // ---- fp32 region ----
    float* fp = (float*)(us + o);
    size_t fo = 0;
    float* ybuf = fp + fo; fo += 512;
    float* sbuf = fp + fo; fo += 512;
    size_t need = o * sizeof(unsigned short) + fo * sizeof(float);
    if (ws_size < need) return;

    float* outp = (float*)d_out;

    hipMemsetAsync(us, 0, zeroBytes, stream);
    hipMemsetAsync(ybuf, 0, 512 * sizeof(float), stream);

    // fused weight transforms
    WtJob W0{w_mp,   wt_mp, (unsigned short*)0, 19, 32, 256, 256, 0, 256};
    WtJob W1{w_ap,   wt_ap, (unsigned short*)0, 19, 32, 256, 256, 0, 256};
    WtJob W2{w_q,    wt_qh, wt_ql,             32, 32, 256, 256, 19, 288};
    WtJob W3{w_k,    wt_kh, wt_kl,             32, 32, 256, 256, 19, 288};
    WtJob W4{w_v,    wt_v,  (unsigned short*)0, 256, 256, 256, 256, 0, 256};
    WtJob W5{w_comp, wt_cp, (unsigned short*)0, 256, 256, 294, 320, 0, 320};
    WtJob W6{w_out,  wt_ot, (unsigned short*)0, 256, 256, 768, 768, 0, 768};
    k_wt_all<<<dim3((9 * 24 * 256 * 32 + 255) / 256, 7), 256, 0, stream>>>(
        W0, W1, W2, W3, W4, W5, W6);

    k_build_x<<<dim3(64, 4, 2), 256, 0, stream>>>(x, xpad_hi, xpad_lo, ipad);
    k_build_mask2<<<dim3(1024, 2), 256, 0, stream>>>(mmask, amask, mq_hi, mq_lo,
                                                     ma_hi, ma_lo);

    const unsigned short* NUS = (const unsigned short*)0;
    unsigned short* NUSo = (unsigned short*)0;
    float* NF = (float*)0;

    // mp+ap fused (MODE 1) -> ipad ch 256 / 275
    ConvJob jm{NUS, NUS, wt_mp, NUS, b_mp, ipad, NUSo, mmask, 256};
    ConvJob ja{NUS, NUS, wt_ap, NUS, b_ap, ipad, NUSo, amask, 275};
    conv_direct<1, 1, 8, 0><<<dim3(32, 2, 2), 256, 0, stream>>>(xpad_hi, NUS, jm, ja);

    // q+k fused (MODE 2, split precision) -> qt/kt hi+lo [p][32]
    ConvJob jq{mq_hi, mq_lo, wt_qh, wt_ql, b_q, qt_h, qt_l, NF, 0};
    ConvJob jk{ma_hi, ma_lo, wt_kh, wt_kl, b_k, kt_h, kt_l, NF, 0};
    conv_direct<2, 3, 8, 1><<<dim3(32, 2, 2), 256, 0, stream>>>(xpad_hi, xpad_lo, jq, jk);

    // v conv (LDS, MODE 3) -> vbf [c][4096]
    conv_lds<8, 3><<<dim3(32, 4, 2), 128, 0, stream>>>(xpad_hi, wt_v, b_v, NF, vbf, NF);

    // comp conv (LDS, MODE 4) -> catN ch 0..255 + channel sums
    conv_lds<10, 4><<<dim3(32, 4, 2), 128, 0, stream>>>(ipad, wt_cp, b_comp, NF, catN,
                                                        ybuf);

    // SE
    se_mlp_kernel<<<2, 256, 0, stream>>>(ybuf, w_se1, w_se2, sbuf);
    se_scale_cat<<<8192, 256, 0, stream>>>(catN, sbuf);

    // flash attention: both modes, both batches
    flash_attn<<<dim3(64, 2, 2), 256, 0, stream>>>(qt_h, qt_l, kt_h, kt_l, vbf, catN);

    // final conv (LDS, MODE 0) -> d_out (fp32 NCHW)
    conv_lds<24, 0><<<dim3(32, 4, 2), 128, 0, stream>>>(catN, wt_ot, b_out, outp, NUSo,
                                                        NF);
}

// Round 6
// 534.296 us; speedup vs baseline: 10.9189x; 1.2408x over previous
//
#include <hip/hip_runtime.h>
#include <math.h>

#define HW 4096
#define IMG 64
#define PIX66 (66 * 66)

typedef short short8 __attribute__((ext_vector_type(8)));
typedef float f32x4 __attribute__((ext_vector_type(4)));

__device__ __forceinline__ unsigned short f2bf(float f) {
    unsigned int u = __float_as_uint(f);
    u += 0x7fff + ((u >> 16) & 1);
    return (unsigned short)(u >> 16);
}
__device__ __forceinline__ float bf2f(unsigned short h) {
    return __uint_as_float(((unsigned int)h) << 16);
}
// pack two fp32 -> bf16 pair (round-half-up), 3 VALU ops
__device__ __forceinline__ unsigned int pkbf(float a, float b) {
    unsigned int ua = __float_as_uint(a) + 0x8000u;
    unsigned int ub = __float_as_uint(b) + 0x8000u;
    return __builtin_amdgcn_perm(ub, ua, 0x07060302u);
}

// async global->LDS, 16B per lane
__device__ __forceinline__ void gll16(const unsigned short* g, unsigned short* l) {
    __builtin_amdgcn_global_load_lds(
        (const __attribute__((address_space(1))) unsigned int*)(g),
        (__attribute__((address_space(3))) unsigned int*)(l), 16, 0, 0);
}

// ---------------------------------------------------------------------------
// weight transform: w fp32 [OC][C0+C1][9] -> wT bf16 [9][KS][OCpad][32]
// ---------------------------------------------------------------------------
struct WtJob {
    const float* w;
    unsigned short* dh;
    unsigned short* dl;
    int OC, OCpad, C0, K0pad, C1, Ktot;
};

__global__ __launch_bounds__(256) void k_wt_all(WtJob J0, WtJob J1, WtJob J2,
                                                WtJob J3, WtJob J4, WtJob J5,
                                                WtJob J6) {
    WtJob J;
    switch (blockIdx.y) {
        case 0: J = J0; break;
        case 1: J = J1; break;
        case 2: J = J2; break;
        case 3: J = J3; break;
        case 4: J = J4; break;
        case 5: J = J5; break;
        default: J = J6; break;
    }
    int idx = blockIdx.x * 256 + threadIdx.x;
    int KS = J.Ktot >> 5;
    int n = 9 * KS * J.OCpad * 32;
    if (idx >= n) return;
    int kk = idx & 31;
    int rest = idx >> 5;
    int oc = rest % J.OCpad;
    rest /= J.OCpad;
    int kg = rest % KS;
    int tap = rest / KS;
    int k = kg * 32 + kk;
    float v = 0.f;
    if (oc < J.OC) {
        int ic = -1;
        if (k < J.C0) ic = k;
        else if (k >= J.K0pad && (k - J.K0pad) < J.C1) ic = J.C0 + (k - J.K0pad);
        if (ic >= 0) v = J.w[((size_t)oc * (J.C0 + J.C1) + ic) * 9 + tap];
    }
    unsigned short hi = f2bf(v);
    J.dh[idx] = hi;
    if (J.dl) J.dl[idx] = f2bf(v - bf2f(hi));
}

// ---------------------------------------------------------------------------
// build P32 bf16 x (hi+lo) [b][8][PIX66][32] and ipad [b][10][PIX66][32]
// ---------------------------------------------------------------------------
__global__ __launch_bounds__(256) void k_build_x(const float* __restrict__ x,
                                                 unsigned short* __restrict__ xh,
                                                 unsigned short* __restrict__ xl,
                                                 unsigned short* __restrict__ ipad) {
    int b = blockIdx.z, c0 = blockIdx.y * 64, p0 = blockIdx.x * 64;
    __shared__ float s[64][65];
    int t = threadIdx.x;
    for (int i = t; i < 4096; i += 256) {
        int c = i >> 6, p = i & 63;
        s[p][c] = x[((size_t)b * 256 + c0 + c) * HW + p0 + p];
    }
    __syncthreads();
    for (int i = t; i < 4096; i += 256) {
        int c = i & 63, p = i >> 6;
        float f = s[p][c];
        unsigned short hi = f2bf(f);
        unsigned short lo = f2bf(f - bf2f(hi));
        int pp = p0 + p;
        int y = pp >> 6, xx = pp & 63;
        size_t pix = (size_t)((y + 1) * 66 + xx + 1);
        int C = c0 + c;
        size_t ix = ((size_t)(b * 8 + (C >> 5)) * PIX66 + pix) * 32 + (C & 31);
        xh[ix] = hi;
        xl[ix] = lo;
        ipad[((size_t)(b * 10 + (C >> 5)) * PIX66 + pix) * 32 + (C & 31)] = hi;
    }
}

__global__ __launch_bounds__(256) void k_build_mask2(
    const float* __restrict__ m0, const float* __restrict__ m1,
    unsigned short* __restrict__ d0h, unsigned short* __restrict__ d0l,
    unsigned short* __restrict__ d1h, unsigned short* __restrict__ d1l) {
    const float* m = blockIdx.y ? m1 : m0;
    unsigned short* dh = blockIdx.y ? d1h : d0h;
    unsigned short* dl = blockIdx.y ? d1l : d0l;
    int idx = blockIdx.x * 256 + threadIdx.x;   // 2*4096*32
    int c = idx & 31;
    int p = (idx >> 5) & 4095;
    int b = idx >> 17;
    float f = (c < 19) ? m[((size_t)b * 19 + c) * HW + p] : 0.f;
    unsigned short hi = f2bf(f);
    int y = p >> 6, xx = p & 63;
    size_t pix = (size_t)((y + 1) * 66 + xx + 1);
    dh[(size_t)b * (PIX66 * 32) + pix * 32 + c] = hi;
    dl[(size_t)b * (PIX66 * 32) + pix * 32 + c] = f2bf(f - bf2f(hi));
}

// ---------------------------------------------------------------------------
// direct-load MFMA conv for small-M (OC=32) convs, P32 layouts.
// SPLITK=1: fused 3-term split precision per step (Whi·Xhi + Wlo·Xhi + Whi·Xlo)
// MODE 1: (acc+bias)*mask -> ipad P32 at chBase (mp/ap)
// MODE 2: split bf16 pixel-major [p][32] hi+lo   (q/k)
// ---------------------------------------------------------------------------
struct ConvJob {
    const unsigned short* s1h;
    const unsigned short* s1l;
    const unsigned short* wth;
    const unsigned short* wtl;
    const float* bias;
    unsigned short* d1;
    unsigned short* d2;
    const float* mask;
    int chBase;
};

template <int MODE, int SPLITK, int KS0, int KS1>
__global__ __launch_bounds__(256, 2) void conv_direct(
    const unsigned short* __restrict__ s0h, const unsigned short* __restrict__ s0l,
    ConvJob j0, ConvJob j1) {
    constexpr int KS = KS0 + KS1;
    constexpr int ST = 9 * KS;
    constexpr int DEPTH = SPLITK ? 2 : 4;
    int b = blockIdx.z;
    ConvJob J = blockIdx.y ? j1 : j0;
    int t = threadIdx.x, w = t >> 6, l = t & 63, quad = l >> 4, ln = l & 15;
    int pBase = blockIdx.x * 128 + w * 32;

    long pb[2];
    int padpix[2];
#pragma unroll
    for (int tn = 0; tn < 2; ++tn) {
        int p = pBase + tn * 16 + ln;
        padpix[tn] = ((p >> 6) + 1) * 66 + (p & 63) + 1;
        pb[tn] = (long)padpix[tn] * 32 + quad * 8;
    }
    size_t aoff[2];
#pragma unroll
    for (int tm = 0; tm < 2; ++tm) aoff[tm] = (size_t)(tm * 16 + ln) * 32 + quad * 8;

    const unsigned short* S0H = s0h + (size_t)b * KS0 * PIX66 * 32;
    const unsigned short* S0L = SPLITK ? s0l + (size_t)b * KS0 * PIX66 * 32
                                       : (const unsigned short*)0;
    const unsigned short* S1H = KS1 ? J.s1h + (size_t)b * KS1 * PIX66 * 32
                                    : (const unsigned short*)0;
    const unsigned short* S1L = (KS1 && SPLITK) ? J.s1l + (size_t)b * KS1 * PIX66 * 32
                                                : (const unsigned short*)0;

    f32x4 acc[2][2];
#pragma unroll
    for (int i = 0; i < 2; ++i)
#pragma unroll
        for (int j = 0; j < 2; ++j) acc[i][j] = (f32x4){0.f, 0.f, 0.f, 0.f};

    int tap = 0, kg = 0;
    auto adv = [&]() { if (++kg == KS) { kg = 0; ++tap; } };
    auto loadStep = [&](int ltap, int lkg, short8* bh, short8* bl, short8* ah,
                        short8* al) {
        int d3 = ltap / 3;
        long doff = (long)((d3 - 1) * 66 + (ltap - d3 * 3 - 1)) * 32;
        const unsigned short* SpH;
        const unsigned short* SpL;
        long plane;
        if (lkg < KS0) {
            SpH = S0H; SpL = S0L; plane = (long)lkg * PIX66 * 32;
        } else {
            SpH = S1H; SpL = S1L; plane = (long)(lkg - KS0) * PIX66 * 32;
        }
        bh[0] = *(const short8*)(SpH + plane + doff + pb[0]);
        bh[1] = *(const short8*)(SpH + plane + doff + pb[1]);
        if (SPLITK) {
            bl[0] = *(const short8*)(SpL + plane + doff + pb[0]);
            bl[1] = *(const short8*)(SpL + plane + doff + pb[1]);
        }
        const unsigned short* WTh = J.wth + (size_t)(ltap * KS + lkg) * 32 * 32;
        ah[0] = *(const short8*)(WTh + aoff[0]);
        ah[1] = *(const short8*)(WTh + aoff[1]);
        if (SPLITK) {
            const unsigned short* WTl = J.wtl + (size_t)(ltap * KS + lkg) * 32 * 32;
            al[0] = *(const short8*)(WTl + aoff[0]);
            al[1] = *(const short8*)(WTl + aoff[1]);
        }
    };

    short8 BH[DEPTH][2], AH[DEPTH][2];
    short8 BL[SPLITK ? DEPTH : 1][2], AL[SPLITK ? DEPTH : 1][2];
#pragma unroll
    for (int u = 0; u < DEPTH; ++u) {
        loadStep(tap, kg, BH[u], BL[SPLITK ? u : 0], AH[u], AL[SPLITK ? u : 0]);
        adv();
    }

    for (int s = 0; s < ST; s += DEPTH) {
#pragma unroll
        for (int u = 0; u < DEPTH; ++u) {
            if (s + u < ST) {
#pragma unroll
                for (int tm = 0; tm < 2; ++tm)
#pragma unroll
                    for (int tn = 0; tn < 2; ++tn) {
                        acc[tm][tn] = __builtin_amdgcn_mfma_f32_16x16x32_bf16(
                            AH[u][tm], BH[u][tn], acc[tm][tn], 0, 0, 0);
                        if (SPLITK) {
                            acc[tm][tn] = __builtin_amdgcn_mfma_f32_16x16x32_bf16(
                                AL[u][tm], BH[u][tn], acc[tm][tn], 0, 0, 0);
                            acc[tm][tn] = __builtin_amdgcn_mfma_f32_16x16x32_bf16(
                                AH[u][tm], BL[u][tn], acc[tm][tn], 0, 0, 0);
                        }
                    }
                if (s + u + DEPTH < ST) {
                    loadStep(tap, kg, BH[u], BL[SPLITK ? u : 0], AH[u],
                             AL[SPLITK ? u : 0]);
                    adv();
                }
            }
        }
    }

#pragma unroll
    for (int tm = 0; tm < 2; ++tm) {
#pragma unroll
        for (int r = 0; r < 4; ++r) {
            int oc = tm * 16 + quad * 4 + r;
#pragma unroll
            for (int tn = 0; tn < 2; ++tn) {
                int p = pBase + tn * 16 + ln;
                if (MODE == 1) {
                    if (oc < 19) {
                        float v = (acc[tm][tn][r] + J.bias[oc]) *
                                  J.mask[((size_t)b * 19 + oc) * HW + p];
                        int ch = J.chBase + oc;
                        J.d1[((size_t)(b * 10 + (ch >> 5)) * PIX66 + padpix[tn]) * 32 +
                             (ch & 31)] = f2bf(v);
                    }
                } else {  // MODE 2
                    float v = acc[tm][tn][r] + J.bias[oc];
                    unsigned short hi = f2bf(v);
                    J.d1[((size_t)b * HW + p) * 32 + oc] = hi;
                    J.d2[((size_t)b * HW + p) * 32 + oc] = f2bf(v - bf2f(hi));
                }
            }
        }
    }
}

// ---------------------------------------------------------------------------
// LDS-staged MFMA conv (v / comp / out), runtime-job version.
// mode 3: bf16 CHW (v); mode 4: catN P32 + channel sums (comp);
// mode 5: raw fp32 K-split partial, z = seg*2+b (out conv)
// ---------------------------------------------------------------------------
struct LdsJob {
    const unsigned short* src;   // [B][KS][PIX66][32]
    const unsigned short* wt;    // [9][KS][256][32]
    const float* bias;
    float* dstf;
    unsigned short* dstb;
    int KS;
    int mode;
};

__global__ __launch_bounds__(128, 3) void conv_lds(LdsJob j0, LdsJob j1,
                                                   int ocgPerJob,
                                                   float* __restrict__ ybuf) {
    int jy = blockIdx.y;
    LdsJob J = (jy >= ocgPerJob) ? j1 : j0;
    int ocBase = ((jy >= ocgPerJob) ? jy - ocgPerJob : jy) * 64;
    int z = blockIdx.z;
    int b = (J.mode == 5) ? (z & 1) : z;
    int kgBeg = 0, kgEnd = J.KS;
    if (J.mode == 5) {
        int half = J.KS >> 1;
        kgBeg = (z >> 1) * half;
        kgEnd = kgBeg + half;
    }
    int ry = blockIdx.x * 2;
    int t = threadIdx.x, w = t >> 6, l = t & 63, quad = l >> 4, ln = l & 15;

    __shared__ unsigned short sB[264 * 32];
    __shared__ unsigned short sA[64 * 32];

    const unsigned short* S = J.src + (size_t)b * J.KS * PIX66 * 32;
    const size_t bStageBase = (size_t)(ry * 66) * 32;

    f32x4 acc[4][4];
#pragma unroll
    for (int i = 0; i < 4; ++i)
#pragma unroll
        for (int j = 0; j < 4; ++j) acc[i][j] = (f32x4){0.f, 0.f, 0.f, 0.f};

    for (int kg = kgBeg; kg < kgEnd; ++kg) {
        const unsigned short* gB = S + (size_t)kg * PIX66 * 32 + bStageBase;
        for (int i = t; i < 1056; i += 128) gll16(gB + (size_t)i * 8, sB + (size_t)i * 8);
        for (int tap = 0; tap < 9; ++tap) {
            const unsigned short* gA =
                J.wt + ((size_t)(tap * J.KS + kg) * 256 + ocBase) * 32;
            for (int i = t; i < 256; i += 128) gll16(gA + (size_t)i * 8, sA + (size_t)i * 8);
            __syncthreads();
            int dy = tap / 3 - 1, dx = tap % 3 - 1;
            int lpBase = (1 + w + dy) * 66 + 1 + dx;
            short8 bf[4], af[4];
#pragma unroll
            for (int tn = 0; tn < 4; ++tn)
                bf[tn] = *(const short8*)(sB + (size_t)(lpBase + tn * 16 + ln) * 32 +
                                          quad * 8);
#pragma unroll
            for (int tm = 0; tm < 4; ++tm)
                af[tm] = *(const short8*)(sA + (size_t)(tm * 16 + ln) * 32 + quad * 8);
#pragma unroll
            for (int tm = 0; tm < 4; ++tm)
#pragma unroll
                for (int tn = 0; tn < 4; ++tn)
                    acc[tm][tn] = __builtin_amdgcn_mfma_f32_16x16x32_bf16(
                        af[tm], bf[tn], acc[tm][tn], 0, 0, 0);
            __syncthreads();
        }
    }

    int prow = ry + w;
#pragma unroll
    for (int tm = 0; tm < 4; ++tm) {
#pragma unroll
        for (int r = 0; r < 4; ++r) {
            int oc = ocBase + tm * 16 + quad * 4 + r;
            float msum = 0.f;
#pragma unroll
            for (int tn = 0; tn < 4; ++tn) {
                int px = tn * 16 + ln;
                if (J.mode == 5) {
                    J.dstf[((size_t)z * 256 + oc) * HW + prow * 64 + px] =
                        acc[tm][tn][r];
                } else if (J.mode == 3) {
                    J.dstb[((size_t)b * 256 + oc) * HW + prow * 64 + px] =
                        f2bf(acc[tm][tn][r] + J.bias[oc]);
                } else {  // mode 4
                    float v = acc[tm][tn][r] + J.bias[oc];
                    size_t pix = (size_t)(prow + 1) * 66 + px + 1;
                    J.dstb[((size_t)(b * 24 + (oc >> 5)) * PIX66 + pix) * 32 +
                           (oc & 31)] = f2bf(v);
                    msum += v;
                }
            }
            if (J.mode == 4) {
#pragma unroll
                for (int off = 8; off; off >>= 1) msum += __shfl_down(msum, off, 16);
                if (ln == 0) atomicAdd(&ybuf[b * 256 + oc], msum);
            }
        }
    }
}

// fp32 out = seg0 + seg1 + bias  (NCHW)
__global__ __launch_bounds__(256) void out_combine(const float* __restrict__ part,
                                                   const float* __restrict__ bias,
                                                   float* __restrict__ outp) {
    int idx = blockIdx.x * 256 + threadIdx.x;   // 2*256*4096
    int p = idx & 4095;
    int oc = (idx >> 12) & 255;
    int b = idx >> 20;
    float v = part[((size_t)b * 256 + oc) * HW + p] +
              part[((size_t)(2 + b) * 256 + oc) * HW + p] + bias[oc];
    outp[((size_t)b * 256 + oc) * HW + p] = v;
}

// ---------------------------------------------------------------------------
// Flash attention, key-split NSEG=2. blockIdx.y = seg*2 + mode.
// Writes unnormalized fp32 partial O + per-query (m,l) for the segment.
// ---------------------------------------------------------------------------
__global__ __launch_bounds__(256) void flash_attn(
    const unsigned short* __restrict__ qt_h, const unsigned short* __restrict__ qt_l,
    const unsigned short* __restrict__ kt_h, const unsigned short* __restrict__ kt_l,
    const unsigned short* __restrict__ vbf,
    float* __restrict__ pO, float* __restrict__ pm, float* __restrict__ pl) {
    int seg = blockIdx.y >> 1, mode = blockIdx.y & 1, b = blockIdx.z;
    size_t qkoff = (size_t)b * HW * 32;
    const unsigned short* Qh = (mode ? kt_h : qt_h) + qkoff;
    const unsigned short* Ql = (mode ? kt_l : qt_l) + qkoff;
    const unsigned short* Kh = (mode ? qt_h : kt_h) + qkoff;
    const unsigned short* Kl = (mode ? qt_l : kt_l) + qkoff;
    const unsigned short* V = vbf + (size_t)b * 256 * HW;

    int t = threadIdx.x, w = t >> 6, l = t & 63, quad = l >> 4, ln = l & 15;
    int pg = w >> 1, ch = w & 1;
    int p0 = blockIdx.x * 64, pw = pg * 32;
    int cb = ch * 128;

    __shared__ unsigned short sV[256 * 72];
    __shared__ unsigned short sP[64 * 72];

    short8 qbh[2], qbl[2];
#pragma unroll
    for (int pn = 0; pn < 2; ++pn) {
        size_t off = (size_t)(p0 + pw + pn * 16 + ln) * 32 + quad * 8;
        qbh[pn] = *(const short8*)(Qh + off);
        qbl[pn] = *(const short8*)(Ql + off);
    }

    float m_run[2] = {-3.0e38f, -3.0e38f};
    float l_run[2] = {0.f, 0.f};
    f32x4 accO[8][2];
#pragma unroll
    for (int cs = 0; cs < 8; ++cs)
#pragma unroll
        for (int pn = 0; pn < 2; ++pn) accO[cs][pn] = (f32x4){0.f, 0.f, 0.f, 0.f};

    int jbBeg = seg * (HW / 2);
    for (int jb = jbBeg; jb < jbBeg + HW / 2; jb += 64) {
        short8 vreg[8];
#pragma unroll
        for (int i = 0; i < 8; ++i) {
            int idx = t + 256 * i;
            int c = idx >> 3, ck = idx & 7;
            vreg[i] = *(const short8*)(V + (size_t)c * HW + jb + ck * 8);
        }
        short8 kah[4], kal[4];
#pragma unroll
        for (int jj = 0; jj < 4; ++jj) {
            size_t off = (size_t)(jb + 16 * jj + ln) * 32 + quad * 8;
            kah[jj] = *(const short8*)(Kh + off);
            kal[jj] = *(const short8*)(Kl + off);
        }
        __syncthreads();
#pragma unroll
        for (int i = 0; i < 8; ++i) {
            int idx = t + 256 * i;
            int c = idx >> 3, ck = idx & 7;
            *(short8*)(sV + (size_t)c * 72 + ck * 8) = vreg[i];
        }

        f32x4 sacc[2][4];
#pragma unroll
        for (int pn = 0; pn < 2; ++pn)
#pragma unroll
            for (int jj = 0; jj < 4; ++jj) sacc[pn][jj] = (f32x4){0.f, 0.f, 0.f, 0.f};
#pragma unroll
        for (int pn = 0; pn < 2; ++pn)
#pragma unroll
            for (int jj = 0; jj < 4; ++jj) {
                sacc[pn][jj] = __builtin_amdgcn_mfma_f32_16x16x32_bf16(
                    kah[jj], qbh[pn], sacc[pn][jj], 0, 0, 0);
                sacc[pn][jj] = __builtin_amdgcn_mfma_f32_16x16x32_bf16(
                    kah[jj], qbl[pn], sacc[pn][jj], 0, 0, 0);
                sacc[pn][jj] = __builtin_amdgcn_mfma_f32_16x16x32_bf16(
                    kal[jj], qbh[pn], sacc[pn][jj], 0, 0, 0);
            }

#pragma unroll
        for (int pn = 0; pn < 2; ++pn) {
            float tm = -3.0e38f;
#pragma unroll
            for (int jj = 0; jj < 4; ++jj)
#pragma unroll
                for (int r = 0; r < 4; ++r) tm = fmaxf(tm, sacc[pn][jj][r]);
            tm = fmaxf(tm, __shfl_xor(tm, 16));
            tm = fmaxf(tm, __shfl_xor(tm, 32));
            if (__any(tm > m_run[pn])) {
                float mnew = fmaxf(m_run[pn], tm);
                float alpha = __expf(m_run[pn] - mnew);
                m_run[pn] = mnew;
                l_run[pn] *= alpha;
#pragma unroll
                for (int cs = 0; cs < 8; ++cs) accO[cs][pn] *= alpha;
            }
            float mm = m_run[pn];
            float psum = 0.f;
#pragma unroll
            for (int jj = 0; jj < 4; ++jj) {
                float e0 = __expf(sacc[pn][jj][0] - mm);
                float e1 = __expf(sacc[pn][jj][1] - mm);
                float e2 = __expf(sacc[pn][jj][2] - mm);
                float e3 = __expf(sacc[pn][jj][3] - mm);
                psum += (e0 + e1) + (e2 + e3);
                uint2 pk;
                pk.x = pkbf(e0, e1);
                pk.y = pkbf(e2, e3);
                *(uint2*)(sP + (size_t)(pw + pn * 16 + ln) * 72 + jj * 16 + quad * 4) =
                    pk;
            }
            psum += __shfl_xor(psum, 16);
            psum += __shfl_xor(psum, 32);
            l_run[pn] += psum;
        }
        __syncthreads();

        short8 pb[2][2];
#pragma unroll
        for (int pn = 0; pn < 2; ++pn)
#pragma unroll
            for (int j2 = 0; j2 < 2; ++j2)
                pb[pn][j2] = *(const short8*)(sP + (size_t)(pw + pn * 16 + ln) * 72 +
                                              j2 * 32 + quad * 8);
#pragma unroll
        for (int cs = 0; cs < 8; ++cs) {
            const unsigned short* vrow = sV + (size_t)(cb + cs * 16 + ln) * 72 + quad * 8;
            short8 va0 = *(const short8*)(vrow);
            short8 va1 = *(const short8*)(vrow + 32);
#pragma unroll
            for (int pn = 0; pn < 2; ++pn) {
                accO[cs][pn] = __builtin_amdgcn_mfma_f32_16x16x32_bf16(
                    va0, pb[pn][0], accO[cs][pn], 0, 0, 0);
                accO[cs][pn] = __builtin_amdgcn_mfma_f32_16x16x32_bf16(
                    va1, pb[pn][1], accO[cs][pn], 0, 0, 0);
            }
        }
    }

    // partial epilogue: raw O, and (m,l) once per query
    int idx4 = (seg * 2 + mode) * 2 + b;
#pragma unroll
    for (int pn = 0; pn < 2; ++pn) {
        int p = p0 + pw + pn * 16 + ln;
        if (ch == 0 && quad == 0) {
            pm[(size_t)idx4 * HW + p] = m_run[pn];
            pl[(size_t)idx4 * HW + p] = l_run[pn];
        }
#pragma unroll
        for (int cs = 0; cs < 8; ++cs)
#pragma unroll
            for (int r = 0; r < 4; ++r) {
                int c = cb + cs * 16 + quad * 4 + r;
                pO[((size_t)idx4 * 256 + c) * HW + p] = accO[cs][pn][r];
            }
    }
}

// combine two key-segments -> catN bf16 P32 channels 256+mode*256..
__global__ __launch_bounds__(256) void attn_combine(const float* __restrict__ pO,
                                                    const float* __restrict__ pm,
                                                    const float* __restrict__ pl,
                                                    unsigned short* __restrict__ catN) {
    int b = blockIdx.z, mode = blockIdx.y;
    int t = threadIdx.x;
    int p = blockIdx.x * 64 + (t & 63);
    int c0 = (t >> 6) * 64;
    int i0 = mode * 2 + b;
    int i1 = 4 + mode * 2 + b;
    float m0 = pm[(size_t)i0 * HW + p], m1 = pm[(size_t)i1 * HW + p];
    float l0 = pl[(size_t)i0 * HW + p], l1 = pl[(size_t)i1 * HW + p];
    float M = fmaxf(m0, m1);
    float e0 = __expf(m0 - M), e1 = __expf(m1 - M);
    float inv = 1.f / (l0 * e0 + l1 * e1);
    e0 *= inv;
    e1 *= inv;
    int y = p >> 6, x = p & 63;
    size_t pix = (size_t)((y + 1) * 66 + x + 1);
    for (int c = c0; c < c0 + 64; ++c) {
        float v = pO[((size_t)i0 * 256 + c) * HW + p] * e0 +
                  pO[((size_t)i1 * 256 + c) * HW + p] * e1;
        int cf = 256 + mode * 256 + c;
        catN[((size_t)(b * 24 + (cf >> 5)) * PIX66 + pix) * 32 + (cf & 31)] = f2bf(v);
    }
}

// ---------------------------------------------------------------------------
// SE mlp + in-place scale of catN ch 0..255 (P32)
// ---------------------------------------------------------------------------
__global__ __launch_bounds__(256) void se_mlp_kernel(const float* __restrict__ y,
                                                     const float* __restrict__ w1,
                                                     const float* __restrict__ w2,
                                                     float* __restrict__ sc) {
    int b = blockIdx.x, t = threadIdx.x;
    __shared__ float sy[256], sh[32];
    sy[t] = y[b * 256 + t] * (1.f / 4096.f);
    __syncthreads();
    if (t < 32) {
        float s = 0.f;
        for (int c = 0; c < 256; ++c) s = fmaf(w1[t * 256 + c], sy[c], s);
        sh[t] = fmaxf(s, 0.f);
    }
    __syncthreads();
    float s = 0.f;
#pragma unroll
    for (int h = 0; h < 32; ++h) s = fmaf(w2[t * 32 + h], sh[h], s);
    sc[b * 256 + t] = 1.f / (1.f + __expf(-s));
}

__global__ __launch_bounds__(256) void se_scale_cat(unsigned short* __restrict__ catN,
                                                    const float* __restrict__ sc) {
    int idx = blockIdx.x * 256 + threadIdx.x;   // 2*4096*256
    int c = idx & 255;
    int p = (idx >> 8) & 4095;
    int b = idx >> 20;
    int y = p >> 6, x = p & 63;
    size_t pix = (size_t)((y + 1) * 66 + x + 1);
    unsigned short* q =
        catN + ((size_t)(b * 24 + (c >> 5)) * PIX66 + pix) * 32 + (c & 31);
    *q = f2bf(bf2f(*q) * sc[b * 256 + c]);
}

// ---------------------------------------------------------------------------
extern "C" void kernel_launch(void* const* d_in, const int* in_sizes, int n_in,
                              void* d_out, int out_size, void* d_ws, size_t ws_size,
                              hipStream_t stream) {
    const float* x      = (const float*)d_in[0];
    const float* mmask  = (const float*)d_in[1];
    const float* amask  = (const float*)d_in[2];
    const float* w_mp   = (const float*)d_in[3];
    const float* b_mp   = (const float*)d_in[4];
    const float* w_ap   = (const float*)d_in[5];
    const float* b_ap   = (const float*)d_in[6];
    const float* w_q    = (const float*)d_in[7];
    const float* b_q    = (const float*)d_in[8];
    const float* w_k    = (const float*)d_in[9];
    const float* b_k    = (const float*)d_in[10];
    const float* w_v    = (const float*)d_in[11];
    const float* b_v    = (const float*)d_in[12];
    const float* w_comp = (const float*)d_in[13];
    const float* b_comp = (const float*)d_in[14];
    const float* w_out  = (const float*)d_in[15];
    const float* b_out  = (const float*)d_in[16];
    const float* w_se1  = (const float*)d_in[17];
    const float* w_se2  = (const float*)d_in[18];

    unsigned short* us = (unsigned short*)d_ws;
    size_t o = 0;
    // ---- zeroed bf16 region (P32 padded buffers) ----
    unsigned short* xpad_hi = us + o; o += (size_t)2 * 8 * PIX66 * 32;
    unsigned short* xpad_lo = us + o; o += (size_t)2 * 8 * PIX66 * 32;
    unsigned short* mq_hi   = us + o; o += (size_t)2 * PIX66 * 32;
    unsigned short* mq_lo   = us + o; o += (size_t)2 * PIX66 * 32;
    unsigned short* ma_hi   = us + o; o += (size_t)2 * PIX66 * 32;
    unsigned short* ma_lo   = us + o; o += (size_t)2 * PIX66 * 32;
    unsigned short* ipad    = us + o; o += (size_t)2 * 10 * PIX66 * 32;
    unsigned short* catN    = us + o; o += (size_t)2 * 24 * PIX66 * 32;
    size_t zeroBytes = o * sizeof(unsigned short);
    // ---- fully-written bf16 region ----
    unsigned short* wt_mp = us + o; o += (size_t)9 * 8 * 32 * 32;
    unsigned short* wt_ap = us + o; o += (size_t)9 * 8 * 32 * 32;
    unsigned short* wt_qh = us + o; o += (size_t)9 * 9 * 32 * 32;
    unsigned short* wt_ql = us + o; o += (size_t)9 * 9 * 32 * 32;
    unsigned short* wt_kh = us + o; o += (size_t)9 * 9 * 32 * 32;
    unsigned short* wt_kl = us + o; o += (size_t)9 * 9 * 32 * 32;
    unsigned short* wt_v  = us + o; o += (size_t)9 * 8 * 256 * 32;
    unsigned short* wt_cp = us + o; o += (size_t)9 * 10 * 256 * 32;
    unsigned short* wt_ot = us + o; o += (size_t)9 * 24 * 256 * 32;
    unsigned short* qt_h  = us + o; o += (size_t)2 * HW * 32;
    unsigned short* qt_l  = us + o; o += (size_t)2 * HW * 32;
    unsigned short* kt_h  = us + o; o += (size_t)2 * HW * 32;
    unsigned short* kt_l  = us + o; o += (size_t)2 * HW * 32;
    unsigned short* vbf   = us + o; o += (size_t)2 * 256 * HW;
    // ---- fp32 region (fully written before read) ----
    float* fp = (float*)(us + o);
    size_t fo = 0;
    float* pAtt = fp + fo; fo += (size_t)8 * 256 * HW;   // [seg*2+mode][b? folded][c][p]
    float* pmb  = fp + fo; fo += (size_t)8 * HW;
    float* plb  = fp + fo; fo += (size_t)8 * HW;
    float* pOut = fp + fo; fo += (size_t)4 * 256 * HW;   // [seg*2+b][oc][p]
    float* ybuf = fp + fo; fo += 512;
    float* sbuf = fp + fo; fo += 512;
    size_t need = o * sizeof(unsigned short) + fo * sizeof(float);
    if (ws_size < need) return;

    float* outp = (float*)d_out;

    hipMemsetAsync(us, 0, zeroBytes, stream);
    hipMemsetAsync(ybuf, 0, 512 * sizeof(float), stream);

    // fused weight transforms
    WtJob W0{w_mp,   wt_mp, (unsigned short*)0, 19, 32, 256, 256, 0, 256};
    WtJob W1{w_ap,   wt_ap, (unsigned short*)0, 19, 32, 256, 256, 0, 256};
    WtJob W2{w_q,    wt_qh, wt_ql,             32, 32, 256, 256, 19, 288};
    WtJob W3{w_k,    wt_kh, wt_kl,             32, 32, 256, 256, 19, 288};
    WtJob W4{w_v,    wt_v,  (unsigned short*)0, 256, 256, 256, 256, 0, 256};
    WtJob W5{w_comp, wt_cp, (unsigned short*)0, 256, 256, 294, 320, 0, 320};
    WtJob W6{w_out,  wt_ot, (unsigned short*)0, 256, 256, 768, 768, 0, 768};
    k_wt_all<<<dim3((9 * 24 * 256 * 32 + 255) / 256, 7), 256, 0, stream>>>(
        W0, W1, W2, W3, W4, W5, W6);

    k_build_x<<<dim3(64, 4, 2), 256, 0, stream>>>(x, xpad_hi, xpad_lo, ipad);
    k_build_mask2<<<dim3(1024, 2), 256, 0, stream>>>(mmask, amask, mq_hi, mq_lo,
                                                     ma_hi, ma_lo);

    const unsigned short* NUS = (const unsigned short*)0;
    unsigned short* NUSo = (unsigned short*)0;
    float* NF = (float*)0;

    // mp+ap fused (MODE 1) -> ipad ch 256 / 275
    ConvJob jm{NUS, NUS, wt_mp, NUS, b_mp, ipad, NUSo, mmask, 256};
    ConvJob ja{NUS, NUS, wt_ap, NUS, b_ap, ipad, NUSo, amask, 275};
    conv_direct<1, 0, 8, 0><<<dim3(32, 2, 2), 256, 0, stream>>>(xpad_hi, NUS, jm, ja);

    // q+k fused (MODE 2, fused split precision) -> qt/kt hi+lo [p][32]
    ConvJob jq{mq_hi, mq_lo, wt_qh, wt_ql, b_q, qt_h, qt_l, NF, 0};
    ConvJob jk{ma_hi, ma_lo, wt_kh, wt_kl, b_k, kt_h, kt_l, NF, 0};
    conv_direct<2, 1, 8, 1><<<dim3(32, 2, 2), 256, 0, stream>>>(xpad_hi, xpad_lo, jq, jk);

    // v (mode 3) + comp (mode 4) fused LDS conv
    LdsJob jv{xpad_hi, wt_v, b_v, NF, vbf, 8, 3};
    LdsJob jc{ipad, wt_cp, b_comp, NF, catN, 10, 4};
    conv_lds<<<dim3(32, 8, 2), 128, 0, stream>>>(jv, jc, 4, ybuf);

    // SE
    se_mlp_kernel<<<2, 256, 0, stream>>>(ybuf, w_se1, w_se2, sbuf);
    se_scale_cat<<<8192, 256, 0, stream>>>(catN, sbuf);

    // flash attention, key-split NSEG=2 + combine
    flash_attn<<<dim3(64, 4, 2), 256, 0, stream>>>(qt_h, qt_l, kt_h, kt_l, vbf,
                                                   pAtt, pmb, plb);
    attn_combine<<<dim3(64, 2, 2), 256, 0, stream>>>(pAtt, pmb, plb, catN);

    // final conv (mode 5, K-split into 2 segments) + combine -> d_out
    LdsJob jo{catN, wt_ot, NF, pOut, NUSo, 24, 5};
    conv_lds<<<dim3(32, 4, 4), 128, 0, stream>>>(jo, jo, 4, NF);
    out_combine<<<8192, 256, 0, stream>>>(pOut, b_out, outp);
}

// Round 7
// 498.075 us; speedup vs baseline: 11.7129x; 1.0727x over previous
//
#include <hip/hip_runtime.h>
#include <math.h>

#define HW 4096
#define IMG 64
#define PIX66 (66 * 66)

typedef short short8 __attribute__((ext_vector_type(8)));
typedef float f32x4 __attribute__((ext_vector_type(4)));

__device__ __forceinline__ unsigned short f2bf(float f) {
    unsigned int u = __float_as_uint(f);
    u += 0x7fff + ((u >> 16) & 1);
    return (unsigned short)(u >> 16);
}
__device__ __forceinline__ float bf2f(unsigned short h) {
    return __uint_as_float(((unsigned int)h) << 16);
}
// pack two fp32 -> bf16 pair (round-half-up), 3 VALU ops
__device__ __forceinline__ unsigned int pkbf(float a, float b) {
    unsigned int ua = __float_as_uint(a) + 0x8000u;
    unsigned int ub = __float_as_uint(b) + 0x8000u;
    return __builtin_amdgcn_perm(ub, ua, 0x07060302u);
}

// async global->LDS, 16B per lane
__device__ __forceinline__ void gll16(const unsigned short* g, unsigned short* l) {
    __builtin_amdgcn_global_load_lds(
        (const __attribute__((address_space(1))) unsigned int*)(g),
        (__attribute__((address_space(3))) unsigned int*)(l), 16, 0, 0);
}

// P32 plane swizzle: chunk index xor'ed per-pixel so conv_lds LDS reads are 2-way
__device__ __forceinline__ int pxor(int pix) { return (pix ^ (pix >> 2)) & 3; }
__device__ __forceinline__ int p32o(int pix, int c) {   // offset in a [PIX66][32] plane
    return pix * 32 + ((((c >> 3) ^ pxor(pix)) & 3) << 3) + (c & 7);
}

// ---------------------------------------------------------------------------
// weight transform: w fp32 [OC][C0+C1][9] -> wT bf16 [9][KS][OCpad][32]
// ---------------------------------------------------------------------------
struct WtJob {
    const float* w;
    unsigned short* dh;
    unsigned short* dl;
    int OC, OCpad, C0, K0pad, C1, Ktot;
};

__global__ __launch_bounds__(256) void k_wt_all(WtJob J0, WtJob J1, WtJob J2,
                                                WtJob J3, WtJob J4, WtJob J5,
                                                WtJob J6) {
    WtJob J;
    switch (blockIdx.y) {
        case 0: J = J0; break;
        case 1: J = J1; break;
        case 2: J = J2; break;
        case 3: J = J3; break;
        case 4: J = J4; break;
        case 5: J = J5; break;
        default: J = J6; break;
    }
    int idx = blockIdx.x * 256 + threadIdx.x;
    int KS = J.Ktot >> 5;
    int n = 9 * KS * J.OCpad * 32;
    if (idx >= n) return;
    int kk = idx & 31;
    int rest = idx >> 5;
    int oc = rest % J.OCpad;
    rest /= J.OCpad;
    int kg = rest % KS;
    int tap = rest / KS;
    int k = kg * 32 + kk;
    float v = 0.f;
    if (oc < J.OC) {
        int ic = -1;
        if (k < J.C0) ic = k;
        else if (k >= J.K0pad && (k - J.K0pad) < J.C1) ic = J.C0 + (k - J.K0pad);
        if (ic >= 0) v = J.w[((size_t)oc * (J.C0 + J.C1) + ic) * 9 + tap];
    }
    unsigned short hi = f2bf(v);
    J.dh[idx] = hi;
    if (J.dl) J.dl[idx] = f2bf(v - bf2f(hi));
}

// ---------------------------------------------------------------------------
// build swizzled P32 bf16 x (hi+lo) [b][8][PIX66][32] and ipad [b][10][PIX66][32]
// ---------------------------------------------------------------------------
__global__ __launch_bounds__(256) void k_build_x(const float* __restrict__ x,
                                                 unsigned short* __restrict__ xh,
                                                 unsigned short* __restrict__ xl,
                                                 unsigned short* __restrict__ ipad) {
    int b = blockIdx.z, c0 = blockIdx.y * 64, p0 = blockIdx.x * 64;
    __shared__ float s[64][65];
    int t = threadIdx.x;
    for (int i = t; i < 4096; i += 256) {
        int c = i >> 6, p = i & 63;
        s[p][c] = x[((size_t)b * 256 + c0 + c) * HW + p0 + p];
    }
    __syncthreads();
    for (int i = t; i < 4096; i += 256) {
        int c = i & 63, p = i >> 6;
        float f = s[p][c];
        unsigned short hi = f2bf(f);
        unsigned short lo = f2bf(f - bf2f(hi));
        int pp = p0 + p;
        int y = pp >> 6, xx = pp & 63;
        int pix = (y + 1) * 66 + xx + 1;
        int C = c0 + c;
        size_t ix = (size_t)(b * 8 + (C >> 5)) * (PIX66 * 32) + p32o(pix, C & 31);
        xh[ix] = hi;
        xl[ix] = lo;
        ipad[(size_t)(b * 10 + (C >> 5)) * (PIX66 * 32) + p32o(pix, C & 31)] = hi;
    }
}

__global__ __launch_bounds__(256) void k_build_mask2(
    const float* __restrict__ m0, const float* __restrict__ m1,
    unsigned short* __restrict__ d0h, unsigned short* __restrict__ d0l,
    unsigned short* __restrict__ d1h, unsigned short* __restrict__ d1l) {
    const float* m = blockIdx.y ? m1 : m0;
    unsigned short* dh = blockIdx.y ? d1h : d0h;
    unsigned short* dl = blockIdx.y ? d1l : d0l;
    int idx = blockIdx.x * 256 + threadIdx.x;   // 2*4096*32
    int c = idx & 31;
    int p = (idx >> 5) & 4095;
    int b = idx >> 17;
    float f = (c < 19) ? m[((size_t)b * 19 + c) * HW + p] : 0.f;
    unsigned short hi = f2bf(f);
    int y = p >> 6, xx = p & 63;
    int pix = (y + 1) * 66 + xx + 1;
    dh[(size_t)b * (PIX66 * 32) + p32o(pix, c)] = hi;
    dl[(size_t)b * (PIX66 * 32) + p32o(pix, c)] = f2bf(f - bf2f(hi));
}

// ---------------------------------------------------------------------------
// direct-load MFMA conv for small-M (OC=32) convs, swizzled P32 inputs.
// MODE 1: (acc+bias)*mask -> ipad P32 at chBase (mp/ap)
// MODE 2: split bf16 pixel-major [p][32] hi+lo (linear)   (q/k)
// ---------------------------------------------------------------------------
struct ConvJob {
    const unsigned short* s1h;
    const unsigned short* s1l;
    const unsigned short* wth;
    const unsigned short* wtl;
    const float* bias;
    unsigned short* d1;
    unsigned short* d2;
    const float* mask;
    int chBase;
};

template <int MODE, int SPLITK, int KS0, int KS1>
__global__ __launch_bounds__(256, 2) void conv_direct(
    const unsigned short* __restrict__ s0h, const unsigned short* __restrict__ s0l,
    ConvJob j0, ConvJob j1) {
    constexpr int KS = KS0 + KS1;
    constexpr int ST = 9 * KS;
    constexpr int DEPTH = SPLITK ? 2 : 4;
    int b = blockIdx.z;
    ConvJob J = blockIdx.y ? j1 : j0;
    int t = threadIdx.x, w = t >> 6, l = t & 63, quad = l >> 4, ln = l & 15;
    int pBase = blockIdx.x * 128 + w * 32;

    int padpix[2];
#pragma unroll
    for (int tn = 0; tn < 2; ++tn) {
        int p = pBase + tn * 16 + ln;
        padpix[tn] = ((p >> 6) + 1) * 66 + (p & 63) + 1;
    }
    size_t aoff[2];
#pragma unroll
    for (int tm = 0; tm < 2; ++tm) aoff[tm] = (size_t)(tm * 16 + ln) * 32 + quad * 8;

    const unsigned short* S0H = s0h + (size_t)b * KS0 * PIX66 * 32;
    const unsigned short* S0L = SPLITK ? s0l + (size_t)b * KS0 * PIX66 * 32
                                       : (const unsigned short*)0;
    const unsigned short* S1H = KS1 ? J.s1h + (size_t)b * KS1 * PIX66 * 32
                                    : (const unsigned short*)0;
    const unsigned short* S1L = (KS1 && SPLITK) ? J.s1l + (size_t)b * KS1 * PIX66 * 32
                                                : (const unsigned short*)0;

    f32x4 acc[2][2];
#pragma unroll
    for (int i = 0; i < 2; ++i)
#pragma unroll
        for (int j = 0; j < 2; ++j) acc[i][j] = (f32x4){0.f, 0.f, 0.f, 0.f};

    int tap = 0, kg = 0;
    auto adv = [&]() { if (++kg == KS) { kg = 0; ++tap; } };
    auto loadStep = [&](int ltap, int lkg, short8* bh, short8* bl, short8* ah,
                        short8* al) {
        int d3 = ltap / 3;
        int dpix = (d3 - 1) * 66 + (ltap - d3 * 3 - 1);
        const unsigned short* SpH;
        const unsigned short* SpL;
        long plane;
        if (lkg < KS0) {
            SpH = S0H; SpL = S0L; plane = (long)lkg * PIX66 * 32;
        } else {
            SpH = S1H; SpL = S1L; plane = (long)(lkg - KS0) * PIX66 * 32;
        }
#pragma unroll
        for (int tn = 0; tn < 2; ++tn) {
            int pix2 = padpix[tn] + dpix;
            long off = plane + (long)pix2 * 32 + (((quad ^ pxor(pix2)) & 3) << 3);
            bh[tn] = *(const short8*)(SpH + off);
            if (SPLITK) bl[tn] = *(const short8*)(SpL + off);
        }
        const unsigned short* WTh = J.wth + (size_t)(ltap * KS + lkg) * 32 * 32;
        ah[0] = *(const short8*)(WTh + aoff[0]);
        ah[1] = *(const short8*)(WTh + aoff[1]);
        if (SPLITK) {
            const unsigned short* WTl = J.wtl + (size_t)(ltap * KS + lkg) * 32 * 32;
            al[0] = *(const short8*)(WTl + aoff[0]);
            al[1] = *(const short8*)(WTl + aoff[1]);
        }
    };

    short8 BH[DEPTH][2], AH[DEPTH][2];
    short8 BL[SPLITK ? DEPTH : 1][2], AL[SPLITK ? DEPTH : 1][2];
#pragma unroll
    for (int u = 0; u < DEPTH; ++u) {
        loadStep(tap, kg, BH[u], BL[SPLITK ? u : 0], AH[u], AL[SPLITK ? u : 0]);
        adv();
    }

    for (int s = 0; s < ST; s += DEPTH) {
#pragma unroll
        for (int u = 0; u < DEPTH; ++u) {
            if (s + u < ST) {
#pragma unroll
                for (int tm = 0; tm < 2; ++tm)
#pragma unroll
                    for (int tn = 0; tn < 2; ++tn) {
                        acc[tm][tn] = __builtin_amdgcn_mfma_f32_16x16x32_bf16(
                            AH[u][tm], BH[u][tn], acc[tm][tn], 0, 0, 0);
                        if (SPLITK) {
                            acc[tm][tn] = __builtin_amdgcn_mfma_f32_16x16x32_bf16(
                                AL[u][tm], BH[u][tn], acc[tm][tn], 0, 0, 0);
                            acc[tm][tn] = __builtin_amdgcn_mfma_f32_16x16x32_bf16(
                                AH[u][tm], BL[u][tn], acc[tm][tn], 0, 0, 0);
                        }
                    }
                if (s + u + DEPTH < ST) {
                    loadStep(tap, kg, BH[u], BL[SPLITK ? u : 0], AH[u],
                             AL[SPLITK ? u : 0]);
                    adv();
                }
            }
        }
    }

#pragma unroll
    for (int tm = 0; tm < 2; ++tm) {
#pragma unroll
        for (int r = 0; r < 4; ++r) {
            int oc = tm * 16 + quad * 4 + r;
#pragma unroll
            for (int tn = 0; tn < 2; ++tn) {
                int p = pBase + tn * 16 + ln;
                if (MODE == 1) {
                    if (oc < 19) {
                        float v = (acc[tm][tn][r] + J.bias[oc]) *
                                  J.mask[((size_t)b * 19 + oc) * HW + p];
                        int ch = J.chBase + oc;
                        J.d1[(size_t)(b * 10 + (ch >> 5)) * (PIX66 * 32) +
                             p32o(padpix[tn], ch & 31)] = f2bf(v);
                    }
                } else {  // MODE 2
                    float v = acc[tm][tn][r] + J.bias[oc];
                    unsigned short hi = f2bf(v);
                    J.d1[((size_t)b * HW + p) * 32 + oc] = hi;
                    J.d2[((size_t)b * HW + p) * 32 + oc] = f2bf(v - bf2f(hi));
                }
            }
        }
    }
}

// ---------------------------------------------------------------------------
// LDS-staged MFMA conv (v / comp / out). B double-buffered via global_load_lds
// (1 barrier per kg); A-fragments loaded directly from global (contiguous 1KB).
// mode 3: vt key-major swizzled [b][64][256][64] (v)
// mode 4: catN P32 + channel sums (comp)
// mode 5: raw fp32 K-split partial, z = seg*2+b (out conv)
// ---------------------------------------------------------------------------
struct LdsJob {
    const unsigned short* src;   // [B][KS][PIX66][32] (swizzled P32)
    const unsigned short* wt;    // [9][KS][256][32]
    const float* bias;
    float* dstf;
    unsigned short* dstb;
    int KS;
    int mode;
};

__global__ __launch_bounds__(128, 3) void conv_lds(LdsJob j0, LdsJob j1,
                                                   int ocgPerJob,
                                                   float* __restrict__ ybuf) {
    int jy = blockIdx.y;
    LdsJob J = (jy >= ocgPerJob) ? j1 : j0;
    int ocBase = ((jy >= ocgPerJob) ? jy - ocgPerJob : jy) * 64;
    int z = blockIdx.z;
    int b = (J.mode == 5) ? (z & 1) : z;
    int kgBeg = 0, kgEnd = J.KS;
    if (J.mode == 5) {
        int half = J.KS >> 1;
        kgBeg = (z >> 1) * half;
        kgEnd = kgBeg + half;
    }
    int ry = blockIdx.x * 2;
    int t = threadIdx.x, w = t >> 6, l = t & 63, quad = l >> 4, ln = l & 15;

    __shared__ unsigned short sB[2][264 * 32];

    const unsigned short* S = J.src + (size_t)b * J.KS * PIX66 * 32;
    const size_t bStageBase = (size_t)(ry * 66) * 32;

    f32x4 acc[4][4];
#pragma unroll
    for (int i = 0; i < 4; ++i)
#pragma unroll
        for (int j = 0; j < 4; ++j) acc[i][j] = (f32x4){0.f, 0.f, 0.f, 0.f};

    {   // preload first kg into buf 0
        const unsigned short* gB = S + (size_t)kgBeg * PIX66 * 32 + bStageBase;
        for (int i = t; i < 1056; i += 128) gll16(gB + (size_t)i * 8, sB[0] + (size_t)i * 8);
    }

    for (int kg = kgBeg; kg < kgEnd; ++kg) {
        int cur = (kg - kgBeg) & 1;
        __syncthreads();   // drains own DMA (vmcnt) + everyone's reads of the other buf
        if (kg + 1 < kgEnd) {
            const unsigned short* gB = S + (size_t)(kg + 1) * PIX66 * 32 + bStageBase;
            for (int i = t; i < 1056; i += 128)
                gll16(gB + (size_t)i * 8, sB[cur ^ 1] + (size_t)i * 8);
        }
        const unsigned short* sBc = sB[cur];
#pragma unroll
        for (int tap = 0; tap < 9; ++tap) {
            const unsigned short* gA =
                J.wt + ((size_t)(tap * J.KS + kg) * 256 + ocBase) * 32;
            int dy = tap / 3 - 1, dx = tap % 3 - 1;
            int lpBase = (1 + w + dy) * 66 + 1 + dx;
            short8 bf[4], af[4];
#pragma unroll
            for (int tn = 0; tn < 4; ++tn) {
                int lp = lpBase + tn * 16 + ln;
                int P = ry * 66 + lp;
                bf[tn] = *(const short8*)(sBc + (size_t)lp * 32 +
                                          (((quad ^ pxor(P)) & 3) << 3));
            }
#pragma unroll
            for (int tm = 0; tm < 4; ++tm)
                af[tm] = *(const short8*)(gA + (size_t)(tm * 16 + ln) * 32 + quad * 8);
#pragma unroll
            for (int tm = 0; tm < 4; ++tm)
#pragma unroll
                for (int tn = 0; tn < 4; ++tn)
                    acc[tm][tn] = __builtin_amdgcn_mfma_f32_16x16x32_bf16(
                        af[tm], bf[tn], acc[tm][tn], 0, 0, 0);
        }
    }

    int prow = ry + w;
#pragma unroll
    for (int tm = 0; tm < 4; ++tm) {
#pragma unroll
        for (int r = 0; r < 4; ++r) {
            int oc = ocBase + tm * 16 + quad * 4 + r;
            float msum = 0.f;
#pragma unroll
            for (int tn = 0; tn < 4; ++tn) {
                int px = tn * 16 + ln;
                if (J.mode == 5) {
                    J.dstf[((size_t)z * 256 + oc) * HW + prow * 64 + px] =
                        acc[tm][tn][r];
                } else if (J.mode == 3) {
                    int jc = ((px >> 3) ^ (oc & 7)) & 7;
                    J.dstb[(((size_t)b * 64 + prow) * 256 + oc) * 64 + jc * 8 +
                           (px & 7)] = f2bf(acc[tm][tn][r] + J.bias[oc]);
                } else {  // mode 4
                    float v = acc[tm][tn][r] + J.bias[oc];
                    int pix = (prow + 1) * 66 + px + 1;
                    J.dstb[(size_t)(b * 24 + (oc >> 5)) * (PIX66 * 32) +
                           p32o(pix, oc & 31)] = f2bf(v);
                    msum += v;
                }
            }
            if (J.mode == 4) {
#pragma unroll
                for (int off = 8; off; off >>= 1) msum += __shfl_down(msum, off, 16);
                if (ln == 0) atomicAdd(&ybuf[b * 256 + oc], msum);
            }
        }
    }
}

// fp32 out = seg0 + seg1 + bias  (NCHW)
__global__ __launch_bounds__(256) void out_combine(const float* __restrict__ part,
                                                   const float* __restrict__ bias,
                                                   float* __restrict__ outp) {
    int idx = blockIdx.x * 256 + threadIdx.x;   // 2*256*4096
    int p = idx & 4095;
    int oc = (idx >> 12) & 255;
    int b = idx >> 20;
    float v = part[((size_t)b * 256 + oc) * HW + p] +
              part[((size_t)(2 + b) * 256 + oc) * HW + p] + bias[oc];
    outp[((size_t)b * 256 + oc) * HW + p] = v;
}

// ---------------------------------------------------------------------------
// Flash attention v3: 512 threads = 2 query-groups(32q) x 4 ch-slices(64c).
// Per query-group exactly ONE wave (soft wave) computes QK + online softmax;
// the others only do PV, reading per-tile alpha from LDS. V staged by
// global_load_lds from key-major xor-swizzled vt. Key-split NSEG=2.
// blockIdx.y = seg*2 + mode. Writes raw fp32 partial O + (m,l).
// ---------------------------------------------------------------------------
__global__ __launch_bounds__(512, 4) void flash_attn(
    const unsigned short* __restrict__ qt_h, const unsigned short* __restrict__ qt_l,
    const unsigned short* __restrict__ kt_h, const unsigned short* __restrict__ kt_l,
    const unsigned short* __restrict__ vt,
    float* __restrict__ pO, float* __restrict__ pm, float* __restrict__ pl) {
    int seg = blockIdx.y >> 1, mode = blockIdx.y & 1, b = blockIdx.z;
    size_t qkoff = (size_t)b * HW * 32;
    const unsigned short* Qh = (mode ? kt_h : qt_h) + qkoff;
    const unsigned short* Ql = (mode ? kt_l : qt_l) + qkoff;
    const unsigned short* Kh = (mode ? qt_h : kt_h) + qkoff;
    const unsigned short* Kl = (mode ? qt_l : kt_l) + qkoff;
    const unsigned short* Vt = vt + (size_t)b * 64 * 256 * 64;

    int t = threadIdx.x, w = t >> 6, l = t & 63, quad = l >> 4, ln = l & 15;
    int pg = w & 1, ch = w >> 1;
    int p0 = blockIdx.x * 64, pw = pg * 32;
    int cb = ch * 64;
    bool soft = (ch == (pg ? 3 : 0));

    __shared__ unsigned short sV[256 * 64];     // linear copy of swizzled vt slab
    __shared__ unsigned short sP[64 * 68];
    __shared__ float sAl[64];

    short8 qbh[2], qbl[2];
    if (soft) {
#pragma unroll
        for (int pn = 0; pn < 2; ++pn) {
            size_t off = (size_t)(p0 + pw + pn * 16 + ln) * 32 + quad * 8;
            qbh[pn] = *(const short8*)(Qh + off);
            qbl[pn] = *(const short8*)(Ql + off);
        }
    }

    float m_run[2] = {-3.0e38f, -3.0e38f};
    float l_run[2] = {0.f, 0.f};
    f32x4 accO[4][2];
#pragma unroll
    for (int cs = 0; cs < 4; ++cs)
#pragma unroll
        for (int pn = 0; pn < 2; ++pn) accO[cs][pn] = (f32x4){0.f, 0.f, 0.f, 0.f};

    int jbBeg = seg * (HW / 2);
    for (int jb = jbBeg; jb < jbBeg + HW / 2; jb += 64) {
        __syncthreads();   // all waves done reading sV/sP/sAl of previous tile
        {   // stage V tile: 32KB = 2048 x 16B over 512 threads
            const unsigned short* gV = Vt + (size_t)(jb >> 6) * (256 * 64);
#pragma unroll
            for (int i = 0; i < 4; ++i)
                gll16(gV + (size_t)(t + 512 * i) * 8, sV + (size_t)(t + 512 * i) * 8);
        }
        if (soft) {
            f32x4 sacc[2][4];
#pragma unroll
            for (int pn = 0; pn < 2; ++pn)
#pragma unroll
                for (int jj = 0; jj < 4; ++jj) sacc[pn][jj] = (f32x4){0.f, 0.f, 0.f, 0.f};
#pragma unroll
            for (int jj = 0; jj < 4; ++jj) {
                size_t off = (size_t)(jb + 16 * jj + ln) * 32 + quad * 8;
                short8 kh = *(const short8*)(Kh + off);
                short8 kr = *(const short8*)(Kl + off);
#pragma unroll
                for (int pn = 0; pn < 2; ++pn) {
                    sacc[pn][jj] = __builtin_amdgcn_mfma_f32_16x16x32_bf16(
                        kh, qbh[pn], sacc[pn][jj], 0, 0, 0);
                    sacc[pn][jj] = __builtin_amdgcn_mfma_f32_16x16x32_bf16(
                        kh, qbl[pn], sacc[pn][jj], 0, 0, 0);
                    sacc[pn][jj] = __builtin_amdgcn_mfma_f32_16x16x32_bf16(
                        kr, qbh[pn], sacc[pn][jj], 0, 0, 0);
                }
            }
#pragma unroll
            for (int pn = 0; pn < 2; ++pn) {
                float tmx = -3.0e38f;
#pragma unroll
                for (int jj = 0; jj < 4; ++jj)
#pragma unroll
                    for (int r = 0; r < 4; ++r) tmx = fmaxf(tmx, sacc[pn][jj][r]);
                tmx = fmaxf(tmx, __shfl_xor(tmx, 16));
                tmx = fmaxf(tmx, __shfl_xor(tmx, 32));
                float mnew = fmaxf(m_run[pn], tmx);
                float alpha = __expf(m_run[pn] - mnew);
                m_run[pn] = mnew;
                float psum = 0.f;
#pragma unroll
                for (int jj = 0; jj < 4; ++jj) {
                    float e0 = __expf(sacc[pn][jj][0] - mnew);
                    float e1 = __expf(sacc[pn][jj][1] - mnew);
                    float e2 = __expf(sacc[pn][jj][2] - mnew);
                    float e3 = __expf(sacc[pn][jj][3] - mnew);
                    psum += (e0 + e1) + (e2 + e3);
                    uint2 pk;
                    pk.x = pkbf(e0, e1);
                    pk.y = pkbf(e2, e3);
                    *(uint2*)(sP + (size_t)(pw + pn * 16 + ln) * 68 + jj * 16 +
                              quad * 4) = pk;
                }
                psum += __shfl_xor(psum, 16);
                psum += __shfl_xor(psum, 32);
                l_run[pn] = l_run[pn] * alpha + psum;
                if (quad == 0) sAl[pw + pn * 16 + ln] = alpha;
            }
        }
        __syncthreads();   // waits own DMA (vmcnt) + soft's sP/sAl writes
        float al0 = sAl[pw + ln];
        float al1 = sAl[pw + 16 + ln];
#pragma unroll
        for (int cs = 0; cs < 4; ++cs) { accO[cs][0] *= al0; accO[cs][1] *= al1; }
#pragma unroll
        for (int j2 = 0; j2 < 2; ++j2) {
            short8 pb0 = *(const short8*)(sP + (size_t)(pw + ln) * 68 + j2 * 32 +
                                          quad * 8);
            short8 pb1 = *(const short8*)(sP + (size_t)(pw + 16 + ln) * 68 + j2 * 32 +
                                          quad * 8);
#pragma unroll
            for (int cs = 0; cs < 4; ++cs) {
                int c = cb + cs * 16 + ln;
                short8 va = *(const short8*)(
                    sV + (size_t)c * 64 + ((((j2 * 4 + quad) ^ (c & 7)) & 7) << 3));
                accO[cs][0] = __builtin_amdgcn_mfma_f32_16x16x32_bf16(
                    va, pb0, accO[cs][0], 0, 0, 0);
                accO[cs][1] = __builtin_amdgcn_mfma_f32_16x16x32_bf16(
                    va, pb1, accO[cs][1], 0, 0, 0);
            }
        }
    }

    int idx4 = (seg * 2 + mode) * 2 + b;
#pragma unroll
    for (int pn = 0; pn < 2; ++pn) {
        int p = p0 + pw + pn * 16 + ln;
        if (soft && quad == 0) {
            pm[(size_t)idx4 * HW + p] = m_run[pn];
            pl[(size_t)idx4 * HW + p] = l_run[pn];
        }
#pragma unroll
        for (int cs = 0; cs < 4; ++cs)
#pragma unroll
            for (int r = 0; r < 4; ++r) {
                int c = cb + cs * 16 + quad * 4 + r;
                pO[((size_t)idx4 * 256 + c) * HW + p] = accO[cs][pn][r];
            }
    }
}

// combine two key-segments -> catN bf16 P32 channels 256+mode*256..
__global__ __launch_bounds__(256) void attn_combine(const float* __restrict__ pO,
                                                    const float* __restrict__ pm,
                                                    const float* __restrict__ pl,
                                                    unsigned short* __restrict__ catN) {
    int b = blockIdx.z, mode = blockIdx.y;
    int t = threadIdx.x;
    int p = blockIdx.x * 64 + (t & 63);
    int c0 = (t >> 6) * 64;
    int i0 = mode * 2 + b;
    int i1 = 4 + mode * 2 + b;
    float m0 = pm[(size_t)i0 * HW + p], m1 = pm[(size_t)i1 * HW + p];
    float l0 = pl[(size_t)i0 * HW + p], l1 = pl[(size_t)i1 * HW + p];
    float M = fmaxf(m0, m1);
    float e0 = __expf(m0 - M), e1 = __expf(m1 - M);
    float inv = 1.f / (l0 * e0 + l1 * e1);
    e0 *= inv;
    e1 *= inv;
    int y = p >> 6, x = p & 63;
    int pix = (y + 1) * 66 + x + 1;
    for (int c = c0; c < c0 + 64; ++c) {
        float v = pO[((size_t)i0 * 256 + c) * HW + p] * e0 +
                  pO[((size_t)i1 * 256 + c) * HW + p] * e1;
        int cf = 256 + mode * 256 + c;
        catN[(size_t)(b * 24 + (cf >> 5)) * (PIX66 * 32) + p32o(pix, cf & 31)] = f2bf(v);
    }
}

// ---------------------------------------------------------------------------
// SE mlp + in-place scale of catN ch 0..255 (P32)
// ---------------------------------------------------------------------------
__global__ __launch_bounds__(256) void se_mlp_kernel(const float* __restrict__ y,
                                                     const float* __restrict__ w1,
                                                     const float* __restrict__ w2,
                                                     float* __restrict__ sc) {
    int b = blockIdx.x, t = threadIdx.x;
    __shared__ float sy[256], sh[32];
    sy[t] = y[b * 256 + t] * (1.f / 4096.f);
    __syncthreads();
    if (t < 32) {
        float s = 0.f;
        for (int c = 0; c < 256; ++c) s = fmaf(w1[t * 256 + c], sy[c], s);
        sh[t] = fmaxf(s, 0.f);
    }
    __syncthreads();
    float s = 0.f;
#pragma unroll
    for (int h = 0; h < 32; ++h) s = fmaf(w2[t * 32 + h], sh[h], s);
    sc[b * 256 + t] = 1.f / (1.f + __expf(-s));
}

__global__ __launch_bounds__(256) void se_scale_cat(unsigned short* __restrict__ catN,
                                                    const float* __restrict__ sc) {
    int idx = blockIdx.x * 256 + threadIdx.x;   // 2*4096*256
    int c = idx & 255;
    int p = (idx >> 8) & 4095;
    int b = idx >> 20;
    int y = p >> 6, x = p & 63;
    int pix = (y + 1) * 66 + x + 1;
    unsigned short* q =
        catN + (size_t)(b * 24 + (c >> 5)) * (PIX66 * 32) + p32o(pix, c & 31);
    *q = f2bf(bf2f(*q) * sc[b * 256 + c]);
}

// ---------------------------------------------------------------------------
extern "C" void kernel_launch(void* const* d_in, const int* in_sizes, int n_in,
                              void* d_out, int out_size, void* d_ws, size_t ws_size,
                              hipStream_t stream) {
    const float* x      = (const float*)d_in[0];
    const float* mmask  = (const float*)d_in[1];
    const float* amask  = (const float*)d_in[2];
    const float* w_mp   = (const float*)d_in[3];
    const float* b_mp   = (const float*)d_in[4];
    const float* w_ap   = (const float*)d_in[5];
    const float* b_ap   = (const float*)d_in[6];
    const float* w_q    = (const float*)d_in[7];
    const float* b_q    = (const float*)d_in[8];
    const float* w_k    = (const float*)d_in[9];
    const float* b_k    = (const float*)d_in[10];
    const float* w_v    = (const float*)d_in[11];
    const float* b_v    = (const float*)d_in[12];
    const float* w_comp = (const float*)d_in[13];
    const float* b_comp = (const float*)d_in[14];
    const float* w_out  = (const float*)d_in[15];
    const float* b_out  = (const float*)d_in[16];
    const float* w_se1  = (const float*)d_in[17];
    const float* w_se2  = (const float*)d_in[18];

    unsigned short* us = (unsigned short*)d_ws;
    size_t o = 0;
    // ---- zeroed bf16 region (swizzled P32 padded buffers) ----
    unsigned short* xpad_hi = us + o; o += (size_t)2 * 8 * PIX66 * 32;
    unsigned short* xpad_lo = us + o; o += (size_t)2 * 8 * PIX66 * 32;
    unsigned short* mq_hi   = us + o; o += (size_t)2 * PIX66 * 32;
    unsigned short* mq_lo   = us + o; o += (size_t)2 * PIX66 * 32;
    unsigned short* ma_hi   = us + o; o += (size_t)2 * PIX66 * 32;
    unsigned short* ma_lo   = us + o; o += (size_t)2 * PIX66 * 32;
    unsigned short* ipad    = us + o; o += (size_t)2 * 10 * PIX66 * 32;
    unsigned short* catN    = us + o; o += (size_t)2 * 24 * PIX66 * 32;
    size_t zeroBytes = o * sizeof(unsigned short);
    // ---- fully-written bf16 region ----
    unsigned short* wt_mp = us + o; o += (size_t)9 * 8 * 32 * 32;
    unsigned short* wt_ap = us + o; o += (size_t)9 * 8 * 32 * 32;
    unsigned short* wt_qh = us + o; o += (size_t)9 * 9 * 32 * 32;
    unsigned short* wt_ql = us + o; o += (size_t)9 * 9 * 32 * 32;
    unsigned short* wt_kh = us + o; o += (size_t)9 * 9 * 32 * 32;
    unsigned short* wt_kl = us + o; o += (size_t)9 * 9 * 32 * 32;
    unsigned short* wt_v  = us + o; o += (size_t)9 * 8 * 256 * 32;
    unsigned short* wt_cp = us + o; o += (size_t)9 * 10 * 256 * 32;
    unsigned short* wt_ot = us + o; o += (size_t)9 * 24 * 256 * 32;
    unsigned short* qt_h  = us + o; o += (size_t)2 * HW * 32;
    unsigned short* qt_l  = us + o; o += (size_t)2 * HW * 32;
    unsigned short* kt_h  = us + o; o += (size_t)2 * HW * 32;
    unsigned short* kt_l  = us + o; o += (size_t)2 * HW * 32;
    unsigned short* vt    = us + o; o += (size_t)2 * 64 * 256 * 64;
    // ---- fp32 region (fully written before read) ----
    float* fp = (float*)(us + o);
    size_t fo = 0;
    float* pAtt = fp + fo; fo += (size_t)8 * 256 * HW;
    float* pmb  = fp + fo; fo += (size_t)8 * HW;
    float* plb  = fp + fo; fo += (size_t)8 * HW;
    float* pOut = fp + fo; fo += (size_t)4 * 256 * HW;
    float* ybuf = fp + fo; fo += 512;
    float* sbuf = fp + fo; fo += 512;
    size_t need = o * sizeof(unsigned short) + fo * sizeof(float);
    if (ws_size < need) return;

    float* outp = (float*)d_out;

    hipMemsetAsync(us, 0, zeroBytes, stream);
    hipMemsetAsync(ybuf, 0, 512 * sizeof(float), stream);

    // fused weight transforms
    WtJob W0{w_mp,   wt_mp, (unsigned short*)0, 19, 32, 256, 256, 0, 256};
    WtJob W1{w_ap,   wt_ap, (unsigned short*)0, 19, 32, 256, 256, 0, 256};
    WtJob W2{w_q,    wt_qh, wt_ql,             32, 32, 256, 256, 19, 288};
    WtJob W3{w_k,    wt_kh, wt_kl,             32, 32, 256, 256, 19, 288};
    WtJob W4{w_v,    wt_v,  (unsigned short*)0, 256, 256, 256, 256, 0, 256};
    WtJob W5{w_comp, wt_cp, (unsigned short*)0, 256, 256, 294, 320, 0, 320};
    WtJob W6{w_out,  wt_ot, (unsigned short*)0, 256, 256, 768, 768, 0, 768};
    k_wt_all<<<dim3((9 * 24 * 256 * 32 + 255) / 256, 7), 256, 0, stream>>>(
        W0, W1, W2, W3, W4, W5, W6);

    k_build_x<<<dim3(64, 4, 2), 256, 0, stream>>>(x, xpad_hi, xpad_lo, ipad);
    k_build_mask2<<<dim3(1024, 2), 256, 0, stream>>>(mmask, amask, mq_hi, mq_lo,
                                                     ma_hi, ma_lo);

    const unsigned short* NUS = (const unsigned short*)0;
    unsigned short* NUSo = (unsigned short*)0;
    float* NF = (float*)0;

    // mp+ap fused (MODE 1) -> ipad ch 256 / 275
    ConvJob jm{NUS, NUS, wt_mp, NUS, b_mp, ipad, NUSo, mmask, 256};
    ConvJob ja{NUS, NUS, wt_ap, NUS, b_ap, ipad, NUSo, amask, 275};
    conv_direct<1, 0, 8, 0><<<dim3(32, 2, 2), 256, 0, stream>>>(xpad_hi, NUS, jm, ja);

    // q+k fused (MODE 2, fused split precision) -> qt/kt hi+lo [p][32]
    ConvJob jq{mq_hi, mq_lo, wt_qh, wt_ql, b_q, qt_h, qt_l, NF, 0};
    ConvJob jk{ma_hi, ma_lo, wt_kh, wt_kl, b_k, kt_h, kt_l, NF, 0};
    conv_direct<2, 1, 8, 1><<<dim3(32, 2, 2), 256, 0, stream>>>(xpad_hi, xpad_lo, jq, jk);

    // v (mode 3 -> vt) + comp (mode 4 -> catN) fused LDS conv
    LdsJob jv{xpad_hi, wt_v, b_v, NF, vt, 8, 3};
    LdsJob jc{ipad, wt_cp, b_comp, NF, catN, 10, 4};
    conv_lds<<<dim3(32, 8, 2), 128, 0, stream>>>(jv, jc, 4, ybuf);

    // SE
    se_mlp_kernel<<<2, 256, 0, stream>>>(ybuf, w_se1, w_se2, sbuf);
    se_scale_cat<<<8192, 256, 0, stream>>>(catN, sbuf);

    // flash attention v3 (512-thread blocks), key-split NSEG=2 + combine
    flash_attn<<<dim3(64, 4, 2), 512, 0, stream>>>(qt_h, qt_l, kt_h, kt_l, vt,
                                                   pAtt, pmb, plb);
    attn_combine<<<dim3(64, 2, 2), 256, 0, stream>>>(pAtt, pmb, plb, catN);

    // final conv (mode 5, K-split into 2 segments) + combine -> d_out
    LdsJob jo{catN, wt_ot, NF, pOut, NUSo, 24, 5};
    conv_lds<<<dim3(32, 4, 4), 128, 0, stream>>>(jo, jo, 4, NF);
    out_combine<<<8192, 256, 0, stream>>>(pOut, b_out, outp);
}